// Round 1
// baseline (401.847 us; speedup 1.0000x reference)
//
#include <hip/hip_runtime.h>
#include <hip/hip_bf16.h>

typedef __bf16 bf16;
typedef __attribute__((ext_vector_type(8))) __bf16 bf16x8;
typedef __attribute__((ext_vector_type(4))) __bf16 bf16x4;
typedef __attribute__((ext_vector_type(4))) float f32x4;
typedef __attribute__((ext_vector_type(16))) float f32x16;

#define LSP 4096   // H*W
#define CCH 256

__device__ __forceinline__ void gl2lds16(const bf16* g, bf16* l) {
  __builtin_amdgcn_global_load_lds(
      (const __attribute__((address_space(1))) unsigned int*)g,
      (__attribute__((address_space(3))) unsigned int*)l, 16, 0, 0);
}

__device__ __forceinline__ f32x4 mfma16(bf16x8 a, bf16x8 b, f32x4 c) {
  return __builtin_amdgcn_mfma_f32_16x16x32_bf16(a, b, c, 0, 0, 0);
}
__device__ __forceinline__ f32x16 mfma32(bf16x8 a, bf16x8 b, f32x16 c) {
  return __builtin_amdgcn_mfma_f32_32x32x16_bf16(a, b, c, 0, 0, 0);
}

// ---------------------------------------------------------------------------
// Weight f32 -> bf16 conversion (Wq,Wk,Wv,Wo 65536 ea; W1 262144; W2 131072)
// ---------------------------------------------------------------------------
__global__ __launch_bounds__(256) void cvt_w_kernel(
    const float* __restrict__ wq, const float* __restrict__ wk,
    const float* __restrict__ wv, const float* __restrict__ wo,
    const float* __restrict__ w1, const float* __restrict__ w2,
    bf16* __restrict__ out) {
  int e = blockIdx.x * 256 + threadIdx.x;   // grid 2560 -> 655360 exact
  float v;
  if (e < 65536)        v = wq[e];
  else if (e < 131072)  v = wk[e - 65536];
  else if (e < 196608)  v = wv[e - 131072];
  else if (e < 262144)  v = wo[e - 196608];
  else if (e < 524288)  v = w1[e - 262144];
  else                  v = w2[e - 524288];
  out[e] = (bf16)v;
}

// ---------------------------------------------------------------------------
// LayerNorm over channels, input [b][c][l] f32, output [b][l][c] bf16
// ---------------------------------------------------------------------------
__global__ __launch_bounds__(256) void ln_chw_kernel(
    const float* __restrict__ x, const float* __restrict__ gam,
    const float* __restrict__ bet, bf16* __restrict__ out) {
  int p = blockIdx.x * 256 + threadIdx.x;        // grid 256: 65536 positions
  int b = p >> 12, l = p & 4095;
  const float* px = x + (size_t)b * CCH * LSP + l;
  float s = 0.f, s2 = 0.f;
  #pragma unroll 16
  for (int c = 0; c < CCH; ++c) {
    float v = px[(size_t)c * LSP];
    s += v; s2 += v * v;
  }
  float mean = s * (1.f / 256.f);
  float var  = s2 * (1.f / 256.f) - mean * mean;
  float rs   = rsqrtf(var + 1e-5f);
  bf16* po = out + (size_t)p * CCH;
  #pragma unroll 8
  for (int c0 = 0; c0 < CCH; c0 += 4) {
    bf16x4 o;
    #pragma unroll
    for (int i = 0; i < 4; ++i) {
      float v = px[(size_t)(c0 + i) * LSP];
      o[i] = (bf16)((v - mean) * rs * gam[c0 + i] + bet[c0 + i]);
    }
    *(bf16x4*)&po[c0] = o;
  }
}

// ---------------------------------------------------------------------------
// LayerNorm over channels, input [b][l][c] f32 (contiguous), output bf16 same
// ---------------------------------------------------------------------------
__global__ __launch_bounds__(256) void ln_lc_kernel(
    const float* __restrict__ x, const float* __restrict__ gam,
    const float* __restrict__ bet, bf16* __restrict__ out) {
  int p = blockIdx.x * 256 + threadIdx.x;
  const float* px = x + (size_t)p * CCH;
  float s = 0.f, s2 = 0.f;
  #pragma unroll 8
  for (int c0 = 0; c0 < CCH; c0 += 4) {
    f32x4 v = *(const f32x4*)&px[c0];
    #pragma unroll
    for (int i = 0; i < 4; ++i) { s += v[i]; s2 += v[i] * v[i]; }
  }
  float mean = s * (1.f / 256.f);
  float var  = s2 * (1.f / 256.f) - mean * mean;
  float rs   = rsqrtf(var + 1e-5f);
  bf16* po = out + (size_t)p * CCH;
  #pragma unroll 8
  for (int c0 = 0; c0 < CCH; c0 += 4) {
    f32x4 v = *(const f32x4*)&px[c0];
    bf16x4 o;
    #pragma unroll
    for (int i = 0; i < 4; ++i)
      o[i] = (bf16)((v[i] - mean) * rs * gam[c0 + i] + bet[c0 + i]);
    *(bf16x4*)&po[c0] = o;
  }
}

// ---------------------------------------------------------------------------
// GEMM: out[m][l] = sum_k W[m][k] * X[b][l][k]   (per batch b)
// W bf16 [M][K] row-major, X bf16 [B][L][K].
// 128x128 tile, BK=32, 4 waves, mfma_f32_16x16x32_bf16, dbuf LDS +
// global_load_lds(16B).
// MODE 0: out bf16 [b][256][L]                      (q, k)
// MODE 1: out bf16 [b][L][256]                      (v)
// MODE 2: out f32  [b][L][256] = acc + res[b][c][l] (x = optical + Wo@attn)
// MODE 3: dual-A SimpleGate: g=(A@X+b1[m])*(A2@X+b1[m+512]), bf16 [b][L][512]
// MODE 4: out f32  [b][256][L] = acc + bias[m] + res[b][l][c]  (final)
// ---------------------------------------------------------------------------
template <int MODE>
__global__ __launch_bounds__(256) void gemm_k(
    const bf16* __restrict__ Aw, const bf16* __restrict__ Bx,
    void* __restrict__ outp, const float* __restrict__ res,
    const float* __restrict__ bias, int K) {
  const int tid = threadIdx.x;
  const int lane = tid & 63;
  const int wave = tid >> 6;
  const int wr = wave >> 1, wc = wave & 1;
  const int l0 = blockIdx.x * 128;
  const int m0 = blockIdx.y * 128;
  const int b  = blockIdx.z;

  constexpr int NB = 4096;  // 128*32 elements per tile buffer
  __shared__ bf16 smem[(MODE == 3 ? 6 : 4) * NB];
  bf16* As  = smem;             // [2][NB]
  bf16* Bs  = smem + 2 * NB;    // [2][NB]
  bf16* As2 = smem + 4 * NB;    // [2][NB] (MODE 3)

  const bf16* Ag  = Aw + (size_t)m0 * K;
  const bf16* Ag2 = Aw + (size_t)(m0 + 512) * K;   // only read for MODE 3
  const bf16* Bg  = Bx + ((size_t)b * LSP + l0) * K;

  auto stage = [&](int buf, int k0) {
    #pragma unroll
    for (int i = 0; i < 2; ++i) {
      int ch = i * 256 + tid;            // 0..511 16B chunks
      int r  = ch >> 2;
      int c8 = (ch & 3) * 8;
      gl2lds16(Ag + (size_t)r * K + k0 + c8, As + buf * NB + ch * 8);
      gl2lds16(Bg + (size_t)r * K + k0 + c8, Bs + buf * NB + ch * 8);
      if constexpr (MODE == 3)
        gl2lds16(Ag2 + (size_t)r * K + k0 + c8, As2 + buf * NB + ch * 8);
    }
  };

  f32x4 acc[4][4];
  f32x4 acc2[4][4];
  #pragma unroll
  for (int mi = 0; mi < 4; ++mi)
    #pragma unroll
    for (int ni = 0; ni < 4; ++ni)
      #pragma unroll
      for (int r = 0; r < 4; ++r) {
        acc[mi][ni][r] = 0.f;
        if constexpr (MODE == 3) acc2[mi][ni][r] = 0.f;
      }

  const int nk = K >> 5;
  stage(0, 0);
  for (int kt = 0; kt < nk; ++kt) {
    __syncthreads();                       // stage(kt) landed; prev reads done
    if (kt + 1 < nk) stage((kt + 1) & 1, (kt + 1) * 32);
    const bf16* Ab  = As  + (kt & 1) * NB;
    const bf16* Bb  = Bs  + (kt & 1) * NB;
    const bf16* Ab2 = As2 + (kt & 1) * NB;
    bf16x8 af[4], bfr[4], af2[4];
    #pragma unroll
    for (int mi = 0; mi < 4; ++mi)
      af[mi] = *(const bf16x8*)&Ab[(wr * 64 + mi * 16 + (lane & 15)) * 32 +
                                   (lane >> 4) * 8];
    #pragma unroll
    for (int ni = 0; ni < 4; ++ni)
      bfr[ni] = *(const bf16x8*)&Bb[(wc * 64 + ni * 16 + (lane & 15)) * 32 +
                                    (lane >> 4) * 8];
    if constexpr (MODE == 3) {
      #pragma unroll
      for (int mi = 0; mi < 4; ++mi)
        af2[mi] = *(const bf16x8*)&Ab2[(wr * 64 + mi * 16 + (lane & 15)) * 32 +
                                       (lane >> 4) * 8];
    }
    #pragma unroll
    for (int mi = 0; mi < 4; ++mi)
      #pragma unroll
      for (int ni = 0; ni < 4; ++ni) {
        acc[mi][ni] = mfma16(af[mi], bfr[ni], acc[mi][ni]);
        if constexpr (MODE == 3)
          acc2[mi][ni] = mfma16(af2[mi], bfr[ni], acc2[mi][ni]);
      }
  }

  // epilogue: m = m0 + wr*64 + mi*16 + (lane>>4)*4 + r ; l = l0 + wc*64 + ni*16 + (lane&15)
  const int mq = m0 + wr * 64 + (lane >> 4) * 4;
  const int lq = l0 + wc * 64 + (lane & 15);

  if constexpr (MODE == 0) {
    bf16* out = (bf16*)outp;
    #pragma unroll
    for (int mi = 0; mi < 4; ++mi)
      #pragma unroll
      for (int ni = 0; ni < 4; ++ni) {
        int l = lq + ni * 16, mb = mq + mi * 16;
        #pragma unroll
        for (int r = 0; r < 4; ++r)
          out[((size_t)b * CCH + mb + r) * LSP + l] = (bf16)acc[mi][ni][r];
      }
  } else if constexpr (MODE == 1) {
    bf16* out = (bf16*)outp;
    #pragma unroll
    for (int mi = 0; mi < 4; ++mi)
      #pragma unroll
      for (int ni = 0; ni < 4; ++ni) {
        int l = lq + ni * 16, mb = mq + mi * 16;
        bf16x4 o;
        #pragma unroll
        for (int r = 0; r < 4; ++r) o[r] = (bf16)acc[mi][ni][r];
        *(bf16x4*)&out[((size_t)b * LSP + l) * CCH + mb] = o;
      }
  } else if constexpr (MODE == 2) {
    float* out = (float*)outp;
    #pragma unroll
    for (int mi = 0; mi < 4; ++mi)
      #pragma unroll
      for (int ni = 0; ni < 4; ++ni) {
        int l = lq + ni * 16, mb = mq + mi * 16;
        f32x4 o;
        #pragma unroll
        for (int r = 0; r < 4; ++r)
          o[r] = acc[mi][ni][r] + res[((size_t)b * CCH + mb + r) * LSP + l];
        *(f32x4*)&out[((size_t)b * LSP + l) * CCH + mb] = o;
      }
  } else if constexpr (MODE == 3) {
    bf16* out = (bf16*)outp;
    #pragma unroll
    for (int mi = 0; mi < 4; ++mi)
      #pragma unroll
      for (int ni = 0; ni < 4; ++ni) {
        int l = lq + ni * 16, mb = mq + mi * 16;
        bf16x4 o;
        #pragma unroll
        for (int r = 0; r < 4; ++r) {
          float h1 = acc[mi][ni][r]  + bias[mb + r];
          float h2 = acc2[mi][ni][r] + bias[512 + mb + r];
          o[r] = (bf16)(h1 * h2);
        }
        *(bf16x4*)&out[((size_t)b * LSP + l) * 512 + mb] = o;
      }
  } else {  // MODE 4
    float* out = (float*)outp;
    #pragma unroll
    for (int mi = 0; mi < 4; ++mi)
      #pragma unroll
      for (int ni = 0; ni < 4; ++ni) {
        int l = lq + ni * 16, mb = mq + mi * 16;
        f32x4 xr = *(const f32x4*)&res[((size_t)b * LSP + l) * CCH + mb];
        #pragma unroll
        for (int r = 0; r < 4; ++r)
          out[((size_t)b * CCH + mb + r) * LSP + l] =
              acc[mi][ni][r] + bias[mb + r] + xr[r];
      }
  }
}

// ---------------------------------------------------------------------------
// Channel attention per (b, head): S = (q k^T)*scale (32x32, contract L=4096),
// softmax rows, attn = P v. q,k: bf16 [b][256][L]; v: bf16 [b][L][256];
// attn out: bf16 [b][L][256]. 1 block / (b,h), 4 waves, each owns 1024 l's.
// ---------------------------------------------------------------------------
__global__ __launch_bounds__(256) void attn_kernel(
    const bf16* __restrict__ q, const bf16* __restrict__ k,
    const bf16* __restrict__ v, bf16* __restrict__ attn) {
  const int b = blockIdx.x >> 3;
  const int h = blockIdx.x & 7;
  const int tid = threadIdx.x, lane = tid & 63, w = tid >> 6;

  __shared__ float S[4][1024];
  __shared__ float rowm[32], rowinv[32];
  __shared__ bf16 Pb[1024];

  // --- QK^T partial over this wave's l range ---
  f32x16 accS;
  #pragma unroll
  for (int r = 0; r < 16; ++r) accS[r] = 0.f;
  const bf16* qrow = q + ((size_t)b * CCH + h * 32 + (lane & 31)) * LSP;
  const bf16* krow = k + ((size_t)b * CCH + h * 32 + (lane & 31)) * LSP;
  const int loff = w * 1024 + (lane >> 5) * 8;
  #pragma unroll 4
  for (int ls = 0; ls < 1024; ls += 16) {
    bf16x8 aq = *(const bf16x8*)&qrow[loff + ls];
    bf16x8 bk = *(const bf16x8*)&krow[loff + ls];
    accS = mfma32(aq, bk, accS);
  }
  #pragma unroll
  for (int r = 0; r < 16; ++r) {
    int row = (r & 3) + 8 * (r >> 2) + 4 * (lane >> 5);
    S[w][row * 32 + (lane & 31)] = accS[r];
  }
  __syncthreads();

  // --- reduce partials + scale ---
  const float scale = 0.17677669529663687f;  // 1/sqrt(32)
  #pragma unroll
  for (int i = 0; i < 4; ++i) {
    int e = tid + 256 * i;
    S[0][e] = (S[0][e] + S[1][e] + S[2][e] + S[3][e]) * scale;
  }
  __syncthreads();

  // --- row max / sum ---
  if (tid < 32) {
    float m = -1e30f;
    for (int d = 0; d < 32; ++d) m = fmaxf(m, S[0][tid * 32 + d]);
    float sum = 0.f;
    for (int d = 0; d < 32; ++d) sum += __expf(S[0][tid * 32 + d] - m);
    rowm[tid] = m;
    rowinv[tid] = 1.f / sum;
  }
  __syncthreads();

  // --- P bf16 ---
  #pragma unroll
  for (int i = 0; i < 4; ++i) {
    int e = tid + 256 * i;
    int c = e >> 5;
    Pb[e] = (bf16)(__expf(S[0][e] - rowm[c]) * rowinv[c]);
  }
  __syncthreads();

  // --- PV over this wave's l range ---
  bf16x8 a0 = *(const bf16x8*)&Pb[(lane & 31) * 32 + (lane >> 5) * 8];
  bf16x8 a1 = *(const bf16x8*)&Pb[(lane & 31) * 32 + 16 + (lane >> 5) * 8];
  const bf16* vbase = v + (size_t)b * LSP * CCH + h * 32;
  for (int lt = w * 1024; lt < w * 1024 + 1024; lt += 32) {
    bf16x8 b0 =
        *(const bf16x8*)&vbase[(size_t)(lt + (lane & 31)) * CCH + (lane >> 5) * 8];
    bf16x8 b1 = *(const bf16x8*)&vbase[(size_t)(lt + (lane & 31)) * CCH + 16 +
                                       (lane >> 5) * 8];
    f32x16 acc;
    #pragma unroll
    for (int r = 0; r < 16; ++r) acc[r] = 0.f;
    acc = mfma32(a0, b0, acc);
    acc = mfma32(a1, b1, acc);
    bf16* ob = attn + ((size_t)b * LSP + lt + (lane & 31)) * CCH + h * 32;
    #pragma unroll
    for (int rg = 0; rg < 4; ++rg) {
      int c0 = rg * 8 + 4 * (lane >> 5);
      bf16x4 o;
      #pragma unroll
      for (int r = 0; r < 4; ++r) o[r] = (bf16)acc[rg * 4 + r];
      *(bf16x4*)&ob[c0] = o;
    }
  }
}

// ---------------------------------------------------------------------------
extern "C" void kernel_launch(void* const* d_in, const int* in_sizes, int n_in,
                              void* d_out, int out_size, void* d_ws,
                              size_t ws_size, hipStream_t stream) {
  const float* optical = (const float*)d_in[0];
  const float* sar     = (const float*)d_in[1];
  const float* g_opt   = (const float*)d_in[2];
  const float* b_opt   = (const float*)d_in[3];
  const float* g_sar   = (const float*)d_in[4];
  const float* b_sar   = (const float*)d_in[5];
  const float* Wq      = (const float*)d_in[6];
  const float* Wk      = (const float*)d_in[7];
  const float* Wv      = (const float*)d_in[8];
  const float* Wo      = (const float*)d_in[9];
  const float* g_ffn   = (const float*)d_in[10];
  const float* b_ffn   = (const float*)d_in[11];
  const float* W1      = (const float*)d_in[12];
  const float* b1      = (const float*)d_in[13];
  const float* W2      = (const float*)d_in[14];
  const float* b2      = (const float*)d_in[15];

  char* ws = (char*)d_ws;
  bf16* wbf = (bf16*)ws;
  bf16* Wqb = wbf;
  bf16* Wkb = wbf + 65536;
  bf16* Wvb = wbf + 131072;
  bf16* Wob = wbf + 196608;
  bf16* W1b = wbf + 262144;
  bf16* W2b = wbf + 524288;

  size_t off = 2ull * 1024 * 1024;
  const size_t T16 = 16ull * LSP * CCH * 2;  // 33.5 MB bf16 tensor
  bf16* opt_n = (bf16*)(ws + off); off += T16;   // later reused as hn
  bf16* sar_n = (bf16*)(ws + off); off += T16;   // later reused as attn
  bf16* qb    = (bf16*)(ws + off); off += T16;   // later g (low half)
  bf16* kb    = (bf16*)(ws + off); off += T16;   // later g (high half)
  bf16* vb    = (bf16*)(ws + off); off += T16;
  float* xbuf = (float*)(ws + off); off += 2 * T16;  // 64 MB f32
  bf16* hn    = opt_n;
  bf16* attnb = sar_n;
  bf16* gbuf  = qb;  // 64 MB contiguous across qb+kb

  dim3 blk(256);
  cvt_w_kernel<<<2560, blk, 0, stream>>>(Wq, Wk, Wv, Wo, W1, W2, wbf);
  ln_chw_kernel<<<256, blk, 0, stream>>>(optical, g_opt, b_opt, opt_n);
  ln_chw_kernel<<<256, blk, 0, stream>>>(sar, g_sar, b_sar, sar_n);
  gemm_k<0><<<dim3(32, 2, 16), blk, 0, stream>>>(Wqb, opt_n, qb, nullptr, nullptr, 256);
  gemm_k<0><<<dim3(32, 2, 16), blk, 0, stream>>>(Wkb, sar_n, kb, nullptr, nullptr, 256);
  gemm_k<1><<<dim3(32, 2, 16), blk, 0, stream>>>(Wvb, sar_n, vb, nullptr, nullptr, 256);
  attn_kernel<<<128, blk, 0, stream>>>(qb, kb, vb, attnb);
  gemm_k<2><<<dim3(32, 2, 16), blk, 0, stream>>>(Wob, attnb, xbuf, optical, nullptr, 256);
  ln_lc_kernel<<<256, blk, 0, stream>>>(xbuf, g_ffn, b_ffn, hn);
  gemm_k<3><<<dim3(32, 4, 16), blk, 0, stream>>>(W1b, hn, gbuf, nullptr, b1, 256);
  gemm_k<4><<<dim3(32, 2, 16), blk, 0, stream>>>(W2b, gbuf, (float*)d_out, xbuf, b2, 512);
}

// Round 2
// 339.660 us; speedup vs baseline: 1.1831x; 1.1831x over previous
//
#include <hip/hip_runtime.h>
#include <hip/hip_bf16.h>

typedef __bf16 bf16;
typedef __attribute__((ext_vector_type(8))) __bf16 bf16x8;
typedef __attribute__((ext_vector_type(4))) __bf16 bf16x4;
typedef __attribute__((ext_vector_type(4))) float f32x4;
typedef __attribute__((ext_vector_type(16))) float f32x16;

#define LSP 4096   // H*W
#define CCH 256

__device__ __forceinline__ void gl2lds16(const bf16* g, bf16* l) {
  __builtin_amdgcn_global_load_lds(
      (const __attribute__((address_space(1))) unsigned int*)g,
      (__attribute__((address_space(3))) unsigned int*)l, 16, 0, 0);
}

__device__ __forceinline__ f32x4 mfma16(bf16x8 a, bf16x8 b, f32x4 c) {
  return __builtin_amdgcn_mfma_f32_16x16x32_bf16(a, b, c, 0, 0, 0);
}
__device__ __forceinline__ f32x16 mfma32(bf16x8 a, bf16x8 b, f32x16 c) {
  return __builtin_amdgcn_mfma_f32_32x32x16_bf16(a, b, c, 0, 0, 0);
}

// ---------------------------------------------------------------------------
// Weight f32 -> bf16. Wq,Wk,Wo direct; Wv written TRANSPOSED (WvT[cin][och]);
// W1, W2 direct.
// ---------------------------------------------------------------------------
__global__ __launch_bounds__(256) void cvt_w_kernel(
    const float* __restrict__ wq, const float* __restrict__ wk,
    const float* __restrict__ wv, const float* __restrict__ wo,
    const float* __restrict__ w1, const float* __restrict__ w2,
    bf16* __restrict__ out) {
  int e = blockIdx.x * 256 + threadIdx.x;   // grid 2560 -> 655360 exact
  if (e < 65536)        { out[e] = (bf16)wq[e]; }
  else if (e < 131072)  { out[e] = (bf16)wk[e - 65536]; }
  else if (e < 196608)  {
    int e2 = e - 131072;            // e2 = och*256 + cin
    int och = e2 >> 8, cin = e2 & 255;
    out[131072 + cin * 256 + och] = (bf16)wv[e2];   // WvT
  }
  else if (e < 262144)  { out[e] = (bf16)wo[e - 196608]; }
  else if (e < 524288)  { out[e] = (bf16)w1[e - 262144]; }
  else                  { out[e] = (bf16)w2[e - 524288]; }
}

// ---------------------------------------------------------------------------
// LayerNorm over channels, input [b][c][l] f32, output [b][l][c] bf16
// ---------------------------------------------------------------------------
__global__ __launch_bounds__(256) void ln_chw_kernel(
    const float* __restrict__ x, const float* __restrict__ gam,
    const float* __restrict__ bet, bf16* __restrict__ out) {
  int p = blockIdx.x * 256 + threadIdx.x;        // grid 256: 65536 positions
  int b = p >> 12, l = p & 4095;
  const float* px = x + (size_t)b * CCH * LSP + l;
  float s = 0.f, s2 = 0.f;
  #pragma unroll 16
  for (int c = 0; c < CCH; ++c) {
    float v = px[(size_t)c * LSP];
    s += v; s2 += v * v;
  }
  float mean = s * (1.f / 256.f);
  float var  = s2 * (1.f / 256.f) - mean * mean;
  float rs   = rsqrtf(var + 1e-5f);
  bf16* po = out + (size_t)p * CCH;
  #pragma unroll 8
  for (int c0 = 0; c0 < CCH; c0 += 4) {
    bf16x4 o;
    #pragma unroll
    for (int i = 0; i < 4; ++i) {
      float v = px[(size_t)(c0 + i) * LSP];
      o[i] = (bf16)((v - mean) * rs * gam[c0 + i] + bet[c0 + i]);
    }
    *(bf16x4*)&po[c0] = o;
  }
}

// ---------------------------------------------------------------------------
// LayerNorm over channels, input [b][l][c] f32 (contiguous), output bf16 same
// ---------------------------------------------------------------------------
__global__ __launch_bounds__(256) void ln_lc_kernel(
    const float* __restrict__ x, const float* __restrict__ gam,
    const float* __restrict__ bet, bf16* __restrict__ out) {
  int p = blockIdx.x * 256 + threadIdx.x;
  const float* px = x + (size_t)p * CCH;
  float s = 0.f, s2 = 0.f;
  #pragma unroll 8
  for (int c0 = 0; c0 < CCH; c0 += 4) {
    f32x4 v = *(const f32x4*)&px[c0];
    #pragma unroll
    for (int i = 0; i < 4; ++i) { s += v[i]; s2 += v[i] * v[i]; }
  }
  float mean = s * (1.f / 256.f);
  float var  = s2 * (1.f / 256.f) - mean * mean;
  float rs   = rsqrtf(var + 1e-5f);
  bf16* po = out + (size_t)p * CCH;
  #pragma unroll 8
  for (int c0 = 0; c0 < CCH; c0 += 4) {
    f32x4 v = *(const f32x4*)&px[c0];
    bf16x4 o;
    #pragma unroll
    for (int i = 0; i < 4; ++i)
      o[i] = (bf16)((v[i] - mean) * rs * gam[c0 + i] + bet[c0 + i]);
    *(bf16x4*)&po[c0] = o;
  }
}

// ---------------------------------------------------------------------------
// GEMM: out[m][l] = sum_k W[m][k] * X[b][l][k]   (per batch b)
// W bf16 [M][K] row-major (optionally per-batch via aw_bstride), X bf16
// [B][Lp][K]. 128x128 tile, BK=32, 4 waves, dbuf LDS + global_load_lds(16B).
// MODE 0: out bf16 [b][256][Lp]                      (q, k, Wfold)
// MODE 2: out f32  [b][Lp][256] = acc + res[b][c][l] (x = optical + Wf@sar_n)
// MODE 3: dual-A SimpleGate: g=(A@X+b1[m])*(A2@X+b1[m+512]), bf16 [b][Lp][512]
// MODE 4: out f32  [b][256][Lp] = acc + bias[m] + res[b][l][c]  (final)
// ---------------------------------------------------------------------------
template <int MODE>
__global__ __launch_bounds__(256) void gemm_k(
    const bf16* __restrict__ Aw, const bf16* __restrict__ Bx,
    void* __restrict__ outp, const float* __restrict__ res,
    const float* __restrict__ bias, int K, int Lp, long aw_bstride) {
  const int tid = threadIdx.x;
  const int lane = tid & 63;
  const int wave = tid >> 6;
  const int wr = wave >> 1, wc = wave & 1;
  const int l0 = blockIdx.x * 128;
  const int m0 = blockIdx.y * 128;
  const int b  = blockIdx.z;

  constexpr int NB = 4096;  // 128*32 elements per tile buffer
  __shared__ bf16 smem[(MODE == 3 ? 6 : 4) * NB];
  bf16* As  = smem;             // [2][NB]
  bf16* Bs  = smem + 2 * NB;    // [2][NB]
  bf16* As2 = smem + 4 * NB;    // [2][NB] (MODE 3)

  const bf16* Ag  = Aw + (size_t)b * aw_bstride + (size_t)m0 * K;
  const bf16* Ag2 = Aw + (size_t)(m0 + 512) * K;   // only read for MODE 3
  const bf16* Bg  = Bx + ((size_t)b * Lp + l0) * K;

  auto stage = [&](int buf, int k0) {
    #pragma unroll
    for (int i = 0; i < 2; ++i) {
      int ch = i * 256 + tid;            // 0..511 16B chunks
      int r  = ch >> 2;
      int c8 = (ch & 3) * 8;
      gl2lds16(Ag + (size_t)r * K + k0 + c8, As + buf * NB + ch * 8);
      gl2lds16(Bg + (size_t)r * K + k0 + c8, Bs + buf * NB + ch * 8);
      if constexpr (MODE == 3)
        gl2lds16(Ag2 + (size_t)r * K + k0 + c8, As2 + buf * NB + ch * 8);
    }
  };

  f32x4 acc[4][4];
  f32x4 acc2[4][4];
  #pragma unroll
  for (int mi = 0; mi < 4; ++mi)
    #pragma unroll
    for (int ni = 0; ni < 4; ++ni)
      #pragma unroll
      for (int r = 0; r < 4; ++r) {
        acc[mi][ni][r] = 0.f;
        if constexpr (MODE == 3) acc2[mi][ni][r] = 0.f;
      }

  const int nk = K >> 5;
  stage(0, 0);
  for (int kt = 0; kt < nk; ++kt) {
    __syncthreads();                       // stage(kt) landed; prev reads done
    if (kt + 1 < nk) stage((kt + 1) & 1, (kt + 1) * 32);
    const bf16* Ab  = As  + (kt & 1) * NB;
    const bf16* Bb  = Bs  + (kt & 1) * NB;
    const bf16* Ab2 = As2 + (kt & 1) * NB;
    bf16x8 af[4], bfr[4], af2[4];
    #pragma unroll
    for (int mi = 0; mi < 4; ++mi)
      af[mi] = *(const bf16x8*)&Ab[(wr * 64 + mi * 16 + (lane & 15)) * 32 +
                                   (lane >> 4) * 8];
    #pragma unroll
    for (int ni = 0; ni < 4; ++ni)
      bfr[ni] = *(const bf16x8*)&Bb[(wc * 64 + ni * 16 + (lane & 15)) * 32 +
                                    (lane >> 4) * 8];
    if constexpr (MODE == 3) {
      #pragma unroll
      for (int mi = 0; mi < 4; ++mi)
        af2[mi] = *(const bf16x8*)&Ab2[(wr * 64 + mi * 16 + (lane & 15)) * 32 +
                                       (lane >> 4) * 8];
    }
    #pragma unroll
    for (int mi = 0; mi < 4; ++mi)
      #pragma unroll
      for (int ni = 0; ni < 4; ++ni) {
        acc[mi][ni] = mfma16(af[mi], bfr[ni], acc[mi][ni]);
        if constexpr (MODE == 3)
          acc2[mi][ni] = mfma16(af2[mi], bfr[ni], acc2[mi][ni]);
      }
  }

  // epilogue: m = m0 + wr*64 + mi*16 + (lane>>4)*4 + r ; l = l0 + wc*64 + ni*16 + (lane&15)
  const int mq = m0 + wr * 64 + (lane >> 4) * 4;
  const int lq = l0 + wc * 64 + (lane & 15);

  if constexpr (MODE == 0) {
    bf16* out = (bf16*)outp;
    #pragma unroll
    for (int mi = 0; mi < 4; ++mi)
      #pragma unroll
      for (int ni = 0; ni < 4; ++ni) {
        int l = lq + ni * 16, mb = mq + mi * 16;
        #pragma unroll
        for (int r = 0; r < 4; ++r)
          out[((size_t)b * CCH + mb + r) * Lp + l] = (bf16)acc[mi][ni][r];
      }
  } else if constexpr (MODE == 2) {
    float* out = (float*)outp;
    #pragma unroll
    for (int mi = 0; mi < 4; ++mi)
      #pragma unroll
      for (int ni = 0; ni < 4; ++ni) {
        int l = lq + ni * 16, mb = mq + mi * 16;
        f32x4 o;
        #pragma unroll
        for (int r = 0; r < 4; ++r)
          o[r] = acc[mi][ni][r] + res[((size_t)b * CCH + mb + r) * Lp + l];
        *(f32x4*)&out[((size_t)b * Lp + l) * CCH + mb] = o;
      }
  } else if constexpr (MODE == 3) {
    bf16* out = (bf16*)outp;
    #pragma unroll
    for (int mi = 0; mi < 4; ++mi)
      #pragma unroll
      for (int ni = 0; ni < 4; ++ni) {
        int l = lq + ni * 16, mb = mq + mi * 16;
        bf16x4 o;
        #pragma unroll
        for (int r = 0; r < 4; ++r) {
          float h1 = acc[mi][ni][r]  + bias[mb + r];
          float h2 = acc2[mi][ni][r] + bias[512 + mb + r];
          o[r] = (bf16)(h1 * h2);
        }
        *(bf16x4*)&out[((size_t)b * Lp + l) * 512 + mb] = o;
      }
  } else {  // MODE 4
    float* out = (float*)outp;
    #pragma unroll
    for (int mi = 0; mi < 4; ++mi)
      #pragma unroll
      for (int ni = 0; ni < 4; ++ni) {
        int l = lq + ni * 16, mb = mq + mi * 16;
        f32x4 xr = *(const f32x4*)&res[((size_t)b * Lp + l) * CCH + mb];
        #pragma unroll
        for (int r = 0; r < 4; ++r)
          out[((size_t)b * CCH + mb + r) * Lp + l] =
              acc[mi][ni][r] + bias[mb + r] + xr[r];
      }
  }
}

// ---------------------------------------------------------------------------
// Split-K QK^T partials: grid (8 l-chunks, 128 bh). Each block computes the
// 32x32 partial S over 512 l's (4 waves x 128 l) and writes f32 partials.
// q,k: bf16 [b][256][L] (l contiguous).
// ---------------------------------------------------------------------------
__global__ __launch_bounds__(256) void s_partial_kernel(
    const bf16* __restrict__ q, const bf16* __restrict__ k,
    float* __restrict__ Spart) {
  const int chunk = blockIdx.x;       // 8
  const int bh = blockIdx.y;          // 128
  const int b = bh >> 3, h = bh & 7;
  const int tid = threadIdx.x, lane = tid & 63, w = tid >> 6;
  __shared__ float S[4][1024];
  f32x16 accS;
  #pragma unroll
  for (int r = 0; r < 16; ++r) accS[r] = 0.f;
  const bf16* qrow = q + ((size_t)b * CCH + h * 32 + (lane & 31)) * LSP;
  const bf16* krow = k + ((size_t)b * CCH + h * 32 + (lane & 31)) * LSP;
  const int loff = chunk * 512 + w * 128 + (lane >> 5) * 8;
  #pragma unroll
  for (int ls = 0; ls < 128; ls += 16) {
    bf16x8 aq = *(const bf16x8*)&qrow[loff + ls];
    bf16x8 bk = *(const bf16x8*)&krow[loff + ls];
    accS = mfma32(aq, bk, accS);
  }
  #pragma unroll
  for (int r = 0; r < 16; ++r) {
    int row = (r & 3) + 8 * (r >> 2) + 4 * (lane >> 5);
    S[w][row * 32 + (lane & 31)] = accS[r];
  }
  __syncthreads();
  float* out = Spart + ((size_t)chunk * 128 + bh) * 1024;
  #pragma unroll
  for (int i = 0; i < 4; ++i) {
    int e = tid + 256 * i;
    out[e] = S[0][e] + S[1][e] + S[2][e] + S[3][e];
  }
}

// ---------------------------------------------------------------------------
// Fold: per (b,h): reduce S partials -> softmax -> P (32x32 bf16, LDS) ->
// UT[b][cin][h*32+c] = sum_d WvT[cin][h*32+d] * P[c][d]   (bf16 out, global)
// grid 128 (b,h), 256 threads (4 waves split cin in 64-chunks).
// ---------------------------------------------------------------------------
__global__ __launch_bounds__(256) void attn_fold_kernel(
    const float* __restrict__ Spart, const bf16* __restrict__ WvT,
    bf16* __restrict__ UT) {
  const int bh = blockIdx.x;   // 128
  const int b = bh >> 3, h = bh & 7;
  const int tid = threadIdx.x, lane = tid & 63, w = tid >> 6;
  __shared__ float S[1024];
  __shared__ bf16 P[32 * 32];
  #pragma unroll
  for (int i = 0; i < 4; ++i) {
    int e = tid + 256 * i;
    float s = 0.f;
    #pragma unroll
    for (int c = 0; c < 8; ++c) s += Spart[((size_t)c * 128 + bh) * 1024 + e];
    S[e] = s * 0.17677669529663687f;   // * 1/sqrt(32)
  }
  __syncthreads();
  if (tid < 32) {
    float m = -1e30f;
    #pragma unroll
    for (int d = 0; d < 32; ++d) m = fmaxf(m, S[tid * 32 + d]);
    float sum = 0.f;
    float ex[32];
    #pragma unroll
    for (int d = 0; d < 32; ++d) {
      ex[d] = __expf(S[tid * 32 + d] - m);
      sum += ex[d];
    }
    float inv = 1.f / sum;
    #pragma unroll
    for (int d = 0; d < 32; ++d) P[tid * 32 + d] = (bf16)(ex[d] * inv);
  }
  __syncthreads();
  // MFMA: A = WvT rows (cin), K = d (32); B = P[c][d]
  bf16x8 bfrag[2];
  #pragma unroll
  for (int ct = 0; ct < 2; ++ct)
    bfrag[ct] =
        *(const bf16x8*)&P[(ct * 16 + (lane & 15)) * 32 + (lane >> 4) * 8];
  bf16* outb = UT + (size_t)b * 65536 + h * 32;
  #pragma unroll
  for (int t = 0; t < 4; ++t) {
    int cin16 = w * 64 + t * 16;
    bf16x8 afrag = *(const bf16x8*)&WvT[(size_t)(cin16 + (lane & 15)) * 256 +
                                        h * 32 + (lane >> 4) * 8];
    #pragma unroll
    for (int ct = 0; ct < 2; ++ct) {
      f32x4 acc = {0.f, 0.f, 0.f, 0.f};
      acc = mfma16(afrag, bfrag[ct], acc);
      int c = ct * 16 + (lane & 15);
      int cinr = cin16 + (lane >> 4) * 4;
      #pragma unroll
      for (int r = 0; r < 4; ++r)
        outb[(size_t)(cinr + r) * 256 + c] = (bf16)acc[r];
    }
  }
}

// ---------------------------------------------------------------------------
extern "C" void kernel_launch(void* const* d_in, const int* in_sizes, int n_in,
                              void* d_out, int out_size, void* d_ws,
                              size_t ws_size, hipStream_t stream) {
  const float* optical = (const float*)d_in[0];
  const float* sar     = (const float*)d_in[1];
  const float* g_opt   = (const float*)d_in[2];
  const float* b_opt   = (const float*)d_in[3];
  const float* g_sar   = (const float*)d_in[4];
  const float* b_sar   = (const float*)d_in[5];
  const float* Wq      = (const float*)d_in[6];
  const float* Wk      = (const float*)d_in[7];
  const float* Wv      = (const float*)d_in[8];
  const float* Wo      = (const float*)d_in[9];
  const float* g_ffn   = (const float*)d_in[10];
  const float* b_ffn   = (const float*)d_in[11];
  const float* W1      = (const float*)d_in[12];
  const float* b1      = (const float*)d_in[13];
  const float* W2      = (const float*)d_in[14];
  const float* b2      = (const float*)d_in[15];

  char* ws = (char*)d_ws;
  bf16* wbf  = (bf16*)ws;
  bf16* Wqb  = wbf;
  bf16* Wkb  = wbf + 65536;
  bf16* WvTb = wbf + 131072;
  bf16* Wob  = wbf + 196608;
  bf16* W1b  = wbf + 262144;
  bf16* W2b  = wbf + 524288;

  size_t off = 2ull * 1024 * 1024;
  const size_t T16 = 16ull * LSP * CCH * 2;  // 33.5 MB bf16 tensor
  bf16* opt_n = (bf16*)(ws + off); off += T16;   // later reused as hn
  bf16* sar_n = (bf16*)(ws + off); off += T16;
  bf16* qb    = (bf16*)(ws + off); off += T16;   // later g (low half)
  bf16* kb    = (bf16*)(ws + off); off += T16;   // later g (high half)
  float* xbuf = (float*)(ws + off); off += 2 * T16;           // 67 MB f32
  float* Spart = (float*)(ws + off); off += 4ull * 1024 * 1024;   // 4 MB
  bf16* UTb    = (bf16*)(ws + off); off += 2ull * 1024 * 1024;    // 2 MB
  bf16* Wfoldb = (bf16*)(ws + off); off += 2ull * 1024 * 1024;    // 2 MB
  bf16* hn   = opt_n;
  bf16* gbuf = qb;  // 67 MB contiguous across qb+kb

  dim3 blk(256);
  cvt_w_kernel<<<2560, blk, 0, stream>>>(Wq, Wk, Wv, Wo, W1, W2, wbf);
  ln_chw_kernel<<<256, blk, 0, stream>>>(optical, g_opt, b_opt, opt_n);
  ln_chw_kernel<<<256, blk, 0, stream>>>(sar, g_sar, b_sar, sar_n);
  gemm_k<0><<<dim3(32, 2, 16), blk, 0, stream>>>(Wqb, opt_n, qb, nullptr,
                                                 nullptr, 256, 4096, 0);
  gemm_k<0><<<dim3(32, 2, 16), blk, 0, stream>>>(Wkb, sar_n, kb, nullptr,
                                                 nullptr, 256, 4096, 0);
  s_partial_kernel<<<dim3(8, 128), blk, 0, stream>>>(qb, kb, Spart);
  attn_fold_kernel<<<128, blk, 0, stream>>>(Spart, WvTb, UTb);
  gemm_k<0><<<dim3(2, 2, 16), blk, 0, stream>>>(Wob, UTb, Wfoldb, nullptr,
                                                nullptr, 256, 256, 0);
  gemm_k<2><<<dim3(32, 2, 16), blk, 0, stream>>>(Wfoldb, sar_n, xbuf, optical,
                                                 nullptr, 256, 4096, 65536);
  ln_lc_kernel<<<256, blk, 0, stream>>>(xbuf, g_ffn, b_ffn, hn);
  gemm_k<3><<<dim3(32, 4, 16), blk, 0, stream>>>(W1b, hn, gbuf, nullptr, b1,
                                                 256, 4096, 0);
  gemm_k<4><<<dim3(32, 2, 16), blk, 0, stream>>>(W2b, gbuf, (float*)d_out,
                                                 xbuf, b2, 512, 4096, 0);
}

// Round 4
// 331.510 us; speedup vs baseline: 1.2122x; 1.0246x over previous
//
#include <hip/hip_runtime.h>
#include <hip/hip_bf16.h>

typedef __bf16 bf16;
typedef __attribute__((ext_vector_type(8))) __bf16 bf16x8;
typedef __attribute__((ext_vector_type(4))) __bf16 bf16x4;
typedef __attribute__((ext_vector_type(4))) float f32x4;
typedef __attribute__((ext_vector_type(16))) float f32x16;

#define LSP 4096   // H*W
#define CCH 256

__device__ __forceinline__ void gl2lds16(const bf16* g, bf16* l) {
  __builtin_amdgcn_global_load_lds(
      (const __attribute__((address_space(1))) unsigned int*)g,
      (__attribute__((address_space(3))) unsigned int*)l, 16, 0, 0);
}

__device__ __forceinline__ f32x4 mfma16(bf16x8 a, bf16x8 b, f32x4 c) {
  return __builtin_amdgcn_mfma_f32_16x16x32_bf16(a, b, c, 0, 0, 0);
}
__device__ __forceinline__ f32x16 mfma32(bf16x8 a, bf16x8 b, f32x16 c) {
  return __builtin_amdgcn_mfma_f32_32x32x16_bf16(a, b, c, 0, 0, 0);
}

// ---------------------------------------------------------------------------
// Weight f32 -> bf16. Wq,Wk,Wo direct; Wv written TRANSPOSED (WvT[cin][och]);
// W1, W2 direct.
// ---------------------------------------------------------------------------
__global__ __launch_bounds__(256) void cvt_w_kernel(
    const float* __restrict__ wq, const float* __restrict__ wk,
    const float* __restrict__ wv, const float* __restrict__ wo,
    const float* __restrict__ w1, const float* __restrict__ w2,
    bf16* __restrict__ out) {
  int e = blockIdx.x * 256 + threadIdx.x;   // grid 2560 -> 655360 exact
  if (e < 65536)        { out[e] = (bf16)wq[e]; }
  else if (e < 131072)  { out[e] = (bf16)wk[e - 65536]; }
  else if (e < 196608)  {
    int e2 = e - 131072;            // e2 = och*256 + cin
    int och = e2 >> 8, cin = e2 & 255;
    out[131072 + cin * 256 + och] = (bf16)wv[e2];   // WvT
  }
  else if (e < 262144)  { out[e] = (bf16)wo[e - 196608]; }
  else if (e < 524288)  { out[e] = (bf16)w1[e - 262144]; }
  else                  { out[e] = (bf16)w2[e - 524288]; }
}

// ---------------------------------------------------------------------------
// LayerNorm over channels, input [b][c][l] f32, output [b][c][l] bf16 (same
// layout, l-contiguous) -- feeds the Gram kernel.
// ---------------------------------------------------------------------------
__global__ __launch_bounds__(256) void ln_cl_kernel(
    const float* __restrict__ x, const float* __restrict__ gam,
    const float* __restrict__ bet, bf16* __restrict__ out_cl) {
  int p = blockIdx.x * 256 + threadIdx.x;        // grid 256: 65536 positions
  int b = p >> 12, l = p & 4095;
  const float* px = x + (size_t)b * CCH * LSP + l;
  float s = 0.f, s2 = 0.f;
  #pragma unroll 16
  for (int c = 0; c < CCH; ++c) {
    float v = px[(size_t)c * LSP];
    s += v; s2 += v * v;
  }
  float mean = s * (1.f / 256.f);
  float var  = s2 * (1.f / 256.f) - mean * mean;
  float rs   = rsqrtf(var + 1e-5f);
  bf16* po = out_cl + (size_t)b * CCH * LSP + l;
  #pragma unroll 16
  for (int c = 0; c < CCH; ++c) {
    float v = px[(size_t)c * LSP];
    po[(size_t)c * LSP] = (bf16)((v - mean) * rs * gam[c] + bet[c]);
  }
}

// ---------------------------------------------------------------------------
// LayerNorm (sar): writes BOTH [b][c][l] (for gram) and [b][l][c] (for xgemm)
// ---------------------------------------------------------------------------
__global__ __launch_bounds__(256) void ln_dual_kernel(
    const float* __restrict__ x, const float* __restrict__ gam,
    const float* __restrict__ bet, bf16* __restrict__ out_cl,
    bf16* __restrict__ out_lc) {
  int p = blockIdx.x * 256 + threadIdx.x;
  int b = p >> 12, l = p & 4095;
  const float* px = x + (size_t)b * CCH * LSP + l;
  float s = 0.f, s2 = 0.f;
  #pragma unroll 16
  for (int c = 0; c < CCH; ++c) {
    float v = px[(size_t)c * LSP];
    s += v; s2 += v * v;
  }
  float mean = s * (1.f / 256.f);
  float var  = s2 * (1.f / 256.f) - mean * mean;
  float rs   = rsqrtf(var + 1e-5f);
  bf16* pcl = out_cl + (size_t)b * CCH * LSP + l;
  bf16* plc = out_lc + (size_t)p * CCH;
  #pragma unroll 8
  for (int c0 = 0; c0 < CCH; c0 += 4) {
    bf16x4 o;
    #pragma unroll
    for (int i = 0; i < 4; ++i) {
      float v = px[(size_t)(c0 + i) * LSP];
      bf16 r = (bf16)((v - mean) * rs * gam[c0 + i] + bet[c0 + i]);
      o[i] = r;
      pcl[(size_t)(c0 + i) * LSP] = r;
    }
    *(bf16x4*)&plc[c0] = o;
  }
}

// ---------------------------------------------------------------------------
// Gram: G2part[chunk][b][j][i] = sum_{l in chunk} sar_cl[b][j][l]*opt_cl[b][i][l]
// grid (4 tiles(2j x 2i), 4 chunks, 16 b), 4 waves (2x2), mfma32, frags
// direct from global (l-contiguous).
// ---------------------------------------------------------------------------
__global__ __launch_bounds__(256) void gram_kernel(
    const bf16* __restrict__ sar_cl, const bf16* __restrict__ opt_cl,
    float* __restrict__ part) {
  const int tile = blockIdx.x, chunk = blockIdx.y, b = blockIdx.z;
  const int tid = threadIdx.x, lane = tid & 63, w = tid >> 6;
  const int j0 = (tile >> 1) * 128 + (w >> 1) * 64;
  const int i0 = (tile & 1) * 128 + (w & 1) * 64;
  const int l0 = chunk * 1024;
  const bf16* sj = sar_cl + ((size_t)b * CCH + j0 + (lane & 31)) * LSP + l0;
  const bf16* oi = opt_cl + ((size_t)b * CCH + i0 + (lane & 31)) * LSP + l0;
  f32x16 acc[2][2];
  #pragma unroll
  for (int mt = 0; mt < 2; ++mt)
    #pragma unroll
    for (int nt = 0; nt < 2; ++nt)
      #pragma unroll
      for (int r = 0; r < 16; ++r) acc[mt][nt][r] = 0.f;
  #pragma unroll 4
  for (int ks = 0; ks < 64; ++ks) {
    int lofs = ks * 16 + (lane >> 5) * 8;
    bf16x8 a0 = *(const bf16x8*)&sj[lofs];
    bf16x8 a1 = *(const bf16x8*)&sj[32 * LSP + lofs];
    bf16x8 b0 = *(const bf16x8*)&oi[lofs];
    bf16x8 b1 = *(const bf16x8*)&oi[32 * LSP + lofs];
    acc[0][0] = mfma32(a0, b0, acc[0][0]);
    acc[0][1] = mfma32(a0, b1, acc[0][1]);
    acc[1][0] = mfma32(a1, b0, acc[1][0]);
    acc[1][1] = mfma32(a1, b1, acc[1][1]);
  }
  float* op = part + ((size_t)chunk * 16 + b) * 65536;
  #pragma unroll
  for (int mt = 0; mt < 2; ++mt)
    #pragma unroll
    for (int nt = 0; nt < 2; ++nt)
      #pragma unroll
      for (int r = 0; r < 16; ++r) {
        int row = j0 + mt * 32 + (r & 3) + 8 * (r >> 2) + 4 * (lane >> 5);
        int col = i0 + nt * 32 + (lane & 31);
        op[(size_t)row * 256 + col] = acc[mt][nt][r];
      }
}

// ---------------------------------------------------------------------------
// Reduce Gram partials (4 chunks) -> G2 bf16 [b][j][i]
// ---------------------------------------------------------------------------
__global__ __launch_bounds__(256) void greduce_kernel(
    const float* __restrict__ part, bf16* __restrict__ G2) {
  size_t e = ((size_t)blockIdx.x * 256 + threadIdx.x) * 8;  // grid 512
  float a[8];
  #pragma unroll
  for (int i = 0; i < 8; ++i) a[i] = 0.f;
  #pragma unroll
  for (int ch = 0; ch < 4; ++ch) {
    f32x4 p0 = *(const f32x4*)&part[ch * 1048576ull + e];
    f32x4 p1 = *(const f32x4*)&part[ch * 1048576ull + e + 4];
    #pragma unroll
    for (int i = 0; i < 4; ++i) { a[i] += p0[i]; a[4 + i] += p1[i]; }
  }
  bf16x8 o;
  #pragma unroll
  for (int i = 0; i < 8; ++i) o[i] = (bf16)a[i];
  *(bf16x8*)&G2[e] = o;
}

// ---------------------------------------------------------------------------
// Fold: per (b,h): M1[c][j] = sum_i Wq_h[c][i]*G2[j][i],
// S[c][d] = sum_j M1[c][j]*Wk_h[d][j], softmax rows -> P,
// UT[b][cin][h*32+c] = sum_d WvT[cin][h*32+d]*P[c][d].
// grid 128 (b,h), 4 waves.
// ---------------------------------------------------------------------------
__global__ __launch_bounds__(256) void fold2_kernel(
    const bf16* __restrict__ G2, const bf16* __restrict__ Wq,
    const bf16* __restrict__ Wk, const bf16* __restrict__ WvT,
    bf16* __restrict__ UT) {
  const int bh = blockIdx.x;
  const int b = bh >> 3, h = bh & 7;
  const int tid = threadIdx.x, lane = tid & 63, w = tid >> 6;
  __shared__ bf16 M1[32 * 256];
  __shared__ float Sp[4][1024];
  __shared__ float S[1024];
  __shared__ bf16 P[1024];

  // phase 1: M1[c][j], wave w owns j in [w*64, w*64+64)
  const bf16* gq = Wq + (size_t)(h * 32) * 256;
  const bf16* g2b = G2 + (size_t)b * 65536;
  #pragma unroll
  for (int mt = 0; mt < 2; ++mt)
    #pragma unroll
    for (int nt = 0; nt < 4; ++nt) {
      f32x4 acc = {0.f, 0.f, 0.f, 0.f};
      #pragma unroll
      for (int ks = 0; ks < 8; ++ks) {
        bf16x8 a = *(const bf16x8*)&gq[(size_t)(mt * 16 + (lane & 15)) * 256 +
                                       ks * 32 + (lane >> 4) * 8];
        bf16x8 bb = *(const bf16x8*)&g2b[
            (size_t)(w * 64 + nt * 16 + (lane & 15)) * 256 + ks * 32 +
            (lane >> 4) * 8];
        acc = mfma16(a, bb, acc);
      }
      #pragma unroll
      for (int r = 0; r < 4; ++r)
        M1[(mt * 16 + (lane >> 4) * 4 + r) * 256 + w * 64 + nt * 16 +
           (lane & 15)] = (bf16)acc[r];
    }
  __syncthreads();

  // phase 2: S partials, wave w covers j-range [w*64, w*64+64)
  const bf16* gk = Wk + (size_t)(h * 32) * 256;
  #pragma unroll
  for (int mt = 0; mt < 2; ++mt)
    #pragma unroll
    for (int dt = 0; dt < 2; ++dt) {
      f32x4 acc = {0.f, 0.f, 0.f, 0.f};
      #pragma unroll
      for (int kk = 0; kk < 2; ++kk) {
        bf16x8 a = *(const bf16x8*)&M1[(mt * 16 + (lane & 15)) * 256 + w * 64 +
                                       kk * 32 + (lane >> 4) * 8];
        bf16x8 bb = *(const bf16x8*)&gk[(size_t)(dt * 16 + (lane & 15)) * 256 +
                                        w * 64 + kk * 32 + (lane >> 4) * 8];
        acc = mfma16(a, bb, acc);
      }
      #pragma unroll
      for (int r = 0; r < 4; ++r)
        Sp[w][(mt * 16 + (lane >> 4) * 4 + r) * 32 + dt * 16 + (lane & 15)] =
            acc[r];
    }
  __syncthreads();
  #pragma unroll
  for (int i = 0; i < 4; ++i) {
    int e = tid + 256 * i;
    S[e] = (Sp[0][e] + Sp[1][e] + Sp[2][e] + Sp[3][e]) * 0.17677669529663687f;
  }
  __syncthreads();
  if (tid < 32) {
    float m = -1e30f;
    #pragma unroll
    for (int d = 0; d < 32; ++d) m = fmaxf(m, S[tid * 32 + d]);
    float sum = 0.f;
    float ex[32];
    #pragma unroll
    for (int d = 0; d < 32; ++d) {
      ex[d] = __expf(S[tid * 32 + d] - m);
      sum += ex[d];
    }
    float inv = 1.f / sum;
    #pragma unroll
    for (int d = 0; d < 32; ++d) P[tid * 32 + d] = (bf16)(ex[d] * inv);
  }
  __syncthreads();

  // phase 3: UT
  bf16x8 bfrag[2];
  #pragma unroll
  for (int ct = 0; ct < 2; ++ct)
    bfrag[ct] =
        *(const bf16x8*)&P[(ct * 16 + (lane & 15)) * 32 + (lane >> 4) * 8];
  bf16* outb = UT + (size_t)b * 65536 + h * 32;
  #pragma unroll
  for (int t = 0; t < 4; ++t) {
    int cin16 = w * 64 + t * 16;
    bf16x8 afrag = *(const bf16x8*)&WvT[(size_t)(cin16 + (lane & 15)) * 256 +
                                        h * 32 + (lane >> 4) * 8];
    #pragma unroll
    for (int ct = 0; ct < 2; ++ct) {
      f32x4 acc = {0.f, 0.f, 0.f, 0.f};
      acc = mfma16(afrag, bfrag[ct], acc);
      int c = ct * 16 + (lane & 15);
      int cinr = cin16 + (lane >> 4) * 4;
      #pragma unroll
      for (int r = 0; r < 4; ++r)
        outb[(size_t)(cinr + r) * 256 + c] = (bf16)acc[r];
    }
  }
}

// ---------------------------------------------------------------------------
// GEMM: out[m][l] = sum_k W[m][k] * X[b][l][k]   (per batch b)
// MODE 0: out bf16 [b][256][Lp]                      (Wfold)
// MODE 3: dual-A SimpleGate: g=(A@X+b1[m])*(A2@X+b1[m+512]), bf16 [b][Lp][512]
// MODE 4: out f32  [b][256][Lp] = acc + bias[m] + res[b][l][c]  (final)
// ---------------------------------------------------------------------------
template <int MODE>
__global__ __launch_bounds__(256) void gemm_k(
    const bf16* __restrict__ Aw, const bf16* __restrict__ Bx,
    void* __restrict__ outp, const float* __restrict__ res,
    const float* __restrict__ bias, int K, int Lp, long aw_bstride) {
  const int tid = threadIdx.x;
  const int lane = tid & 63;
  const int wave = tid >> 6;
  const int wr = wave >> 1, wc = wave & 1;
  const int l0 = blockIdx.x * 128;
  const int m0 = blockIdx.y * 128;
  const int b  = blockIdx.z;

  constexpr int NB = 4096;  // 128*32 elements per tile buffer
  __shared__ bf16 smem[(MODE == 3 ? 6 : 4) * NB];
  bf16* As  = smem;             // [2][NB]
  bf16* Bs  = smem + 2 * NB;    // [2][NB]
  bf16* As2 = smem + 4 * NB;    // [2][NB] (MODE 3)

  const bf16* Ag  = Aw + (size_t)b * aw_bstride + (size_t)m0 * K;
  const bf16* Ag2 = Aw + (size_t)(m0 + 512) * K;   // only read for MODE 3
  const bf16* Bg  = Bx + ((size_t)b * Lp + l0) * K;

  auto stage = [&](int buf, int k0) {
    #pragma unroll
    for (int i = 0; i < 2; ++i) {
      int ch = i * 256 + tid;            // 0..511 16B chunks
      int r  = ch >> 2;
      int c8 = (ch & 3) * 8;
      gl2lds16(Ag + (size_t)r * K + k0 + c8, As + buf * NB + ch * 8);
      gl2lds16(Bg + (size_t)r * K + k0 + c8, Bs + buf * NB + ch * 8);
      if constexpr (MODE == 3)
        gl2lds16(Ag2 + (size_t)r * K + k0 + c8, As2 + buf * NB + ch * 8);
    }
  };

  f32x4 acc[4][4];
  f32x4 acc2[4][4];
  #pragma unroll
  for (int mi = 0; mi < 4; ++mi)
    #pragma unroll
    for (int ni = 0; ni < 4; ++ni)
      #pragma unroll
      for (int r = 0; r < 4; ++r) {
        acc[mi][ni][r] = 0.f;
        if constexpr (MODE == 3) acc2[mi][ni][r] = 0.f;
      }

  const int nk = K >> 5;
  stage(0, 0);
  for (int kt = 0; kt < nk; ++kt) {
    __syncthreads();                       // stage(kt) landed; prev reads done
    if (kt + 1 < nk) stage((kt + 1) & 1, (kt + 1) * 32);
    const bf16* Ab  = As  + (kt & 1) * NB;
    const bf16* Bb  = Bs  + (kt & 1) * NB;
    const bf16* Ab2 = As2 + (kt & 1) * NB;
    bf16x8 af[4], bfr[4], af2[4];
    #pragma unroll
    for (int mi = 0; mi < 4; ++mi)
      af[mi] = *(const bf16x8*)&Ab[(wr * 64 + mi * 16 + (lane & 15)) * 32 +
                                   (lane >> 4) * 8];
    #pragma unroll
    for (int ni = 0; ni < 4; ++ni)
      bfr[ni] = *(const bf16x8*)&Bb[(wc * 64 + ni * 16 + (lane & 15)) * 32 +
                                    (lane >> 4) * 8];
    if constexpr (MODE == 3) {
      #pragma unroll
      for (int mi = 0; mi < 4; ++mi)
        af2[mi] = *(const bf16x8*)&Ab2[(wr * 64 + mi * 16 + (lane & 15)) * 32 +
                                       (lane >> 4) * 8];
    }
    #pragma unroll
    for (int mi = 0; mi < 4; ++mi)
      #pragma unroll
      for (int ni = 0; ni < 4; ++ni) {
        acc[mi][ni] = mfma16(af[mi], bfr[ni], acc[mi][ni]);
        if constexpr (MODE == 3)
          acc2[mi][ni] = mfma16(af2[mi], bfr[ni], acc2[mi][ni]);
      }
  }

  const int mq = m0 + wr * 64 + (lane >> 4) * 4;
  const int lq = l0 + wc * 64 + (lane & 15);

  if constexpr (MODE == 0) {
    bf16* out = (bf16*)outp;
    #pragma unroll
    for (int mi = 0; mi < 4; ++mi)
      #pragma unroll
      for (int ni = 0; ni < 4; ++ni) {
        int l = lq + ni * 16, mb = mq + mi * 16;
        #pragma unroll
        for (int r = 0; r < 4; ++r)
          out[((size_t)b * CCH + mb + r) * Lp + l] = (bf16)acc[mi][ni][r];
      }
  } else if constexpr (MODE == 3) {
    bf16* out = (bf16*)outp;
    #pragma unroll
    for (int mi = 0; mi < 4; ++mi)
      #pragma unroll
      for (int ni = 0; ni < 4; ++ni) {
        int l = lq + ni * 16, mb = mq + mi * 16;
        bf16x4 o;
        #pragma unroll
        for (int r = 0; r < 4; ++r) {
          float h1 = acc[mi][ni][r]  + bias[mb + r];
          float h2 = acc2[mi][ni][r] + bias[512 + mb + r];
          o[r] = (bf16)(h1 * h2);
        }
        *(bf16x4*)&out[((size_t)b * Lp + l) * 512 + mb] = o;
      }
  } else {  // MODE 4
    float* out = (float*)outp;
    #pragma unroll
    for (int mi = 0; mi < 4; ++mi)
      #pragma unroll
      for (int ni = 0; ni < 4; ++ni) {
        int l = lq + ni * 16, mb = mq + mi * 16;
        f32x4 xr = *(const f32x4*)&res[((size_t)b * Lp + l) * CCH + mb];
        #pragma unroll
        for (int r = 0; r < 4; ++r)
          out[((size_t)b * CCH + mb + r) * Lp + l] =
              acc[mi][ni][r] + bias[mb + r] + xr[r];
      }
  }
}

// ---------------------------------------------------------------------------
// Fused x-GEMM + residual + FFN LayerNorm.
// x[c][l] = sum_k Wfold[b][c][k]*sar_lc[b][l][k] + optical[b][c][l]
// writes xbuf f32 [b][l][c]  AND  hn bf16 [b][l][c] = LN_c(x)*g+b.
// Tile: M=256 (all channels), N=64 l. grid (64, 16), 4 waves (wave w owns
// m-range w*64).
// ---------------------------------------------------------------------------
__global__ __launch_bounds__(256) void xgemm_ln_kernel(
    const bf16* __restrict__ Wfold, const bf16* __restrict__ sar_lc,
    const float* __restrict__ optical, const float* __restrict__ gff,
    const float* __restrict__ bff, float* __restrict__ xbuf,
    bf16* __restrict__ hn) {
  const int tid = threadIdx.x, lane = tid & 63, w = tid >> 6;
  const int l0 = blockIdx.x * 64;
  const int b  = blockIdx.y;
  __shared__ bf16 As[2][256 * 32];
  __shared__ bf16 Bs[2][64 * 32];
  __shared__ float red[2][4][64];

  const bf16* Ag = Wfold + (size_t)b * 65536;
  const bf16* Bg = sar_lc + ((size_t)b * LSP + l0) * CCH;

  auto stage = [&](int buf, int k0) {
    // As: 256 rows x 32 k = 1024 x 16B chunks
    #pragma unroll
    for (int i = 0; i < 4; ++i) {
      int ch = i * 256 + tid;
      int r = ch >> 2, c8 = (ch & 3) * 8;
      gl2lds16(Ag + (size_t)r * 256 + k0 + c8, &As[buf][ch * 8]);
    }
    // Bs: 64 rows x 32 k = 256 x 16B chunks, one per thread
    {
      int r = tid >> 2, c8 = (tid & 3) * 8;
      gl2lds16(Bg + (size_t)r * 256 + k0 + c8, &Bs[buf][tid * 8]);
    }
  };

  f32x4 acc[4][4];
  #pragma unroll
  for (int mi = 0; mi < 4; ++mi)
    #pragma unroll
    for (int ni = 0; ni < 4; ++ni)
      #pragma unroll
      for (int r = 0; r < 4; ++r) acc[mi][ni][r] = 0.f;

  stage(0, 0);
  for (int kt = 0; kt < 8; ++kt) {
    __syncthreads();
    if (kt < 7) stage((kt + 1) & 1, (kt + 1) * 32);
    const bf16* Ab = As[kt & 1];
    const bf16* Bb = Bs[kt & 1];
    bf16x8 af[4], bfr[4];
    #pragma unroll
    for (int mi = 0; mi < 4; ++mi)
      af[mi] = *(const bf16x8*)&Ab[(w * 64 + mi * 16 + (lane & 15)) * 32 +
                                   (lane >> 4) * 8];
    #pragma unroll
    for (int ni = 0; ni < 4; ++ni)
      bfr[ni] = *(const bf16x8*)&Bb[(ni * 16 + (lane & 15)) * 32 +
                                    (lane >> 4) * 8];
    #pragma unroll
    for (int mi = 0; mi < 4; ++mi)
      #pragma unroll
      for (int ni = 0; ni < 4; ++ni)
        acc[mi][ni] = mfma16(af[mi], bfr[ni], acc[mi][ni]);
  }

  // epilogue: c = w*64 + mi*16 + (lane>>4)*4 + r ; l = l0 + ni*16 + (lane&15)
  const int cb = w * 64 + (lane >> 4) * 4;
  const int lb = l0 + (lane & 15);
  float s[4], q[4];
  #pragma unroll
  for (int ni = 0; ni < 4; ++ni) { s[ni] = 0.f; q[ni] = 0.f; }
  #pragma unroll
  for (int mi = 0; mi < 4; ++mi)
    #pragma unroll
    for (int ni = 0; ni < 4; ++ni) {
      int c = cb + mi * 16, l = lb + ni * 16;
      #pragma unroll
      for (int r = 0; r < 4; ++r) {
        float v = acc[mi][ni][r] + optical[((size_t)b * CCH + c + r) * LSP + l];
        acc[mi][ni][r] = v;
        s[ni] += v; q[ni] += v * v;
      }
    }
  #pragma unroll
  for (int ni = 0; ni < 4; ++ni) {
    s[ni] += __shfl_xor(s[ni], 16);
    s[ni] += __shfl_xor(s[ni], 32);
    q[ni] += __shfl_xor(q[ni], 16);
    q[ni] += __shfl_xor(q[ni], 32);
  }
  if ((lane >> 4) == 0) {
    #pragma unroll
    for (int ni = 0; ni < 4; ++ni) {
      red[0][w][ni * 16 + (lane & 15)] = s[ni];
      red[1][w][ni * 16 + (lane & 15)] = q[ni];
    }
  }
  __syncthreads();
  float mu[4], rsg[4];
  #pragma unroll
  for (int ni = 0; ni < 4; ++ni) {
    int ll = ni * 16 + (lane & 15);
    float S4 = red[0][0][ll] + red[0][1][ll] + red[0][2][ll] + red[0][3][ll];
    float Q4 = red[1][0][ll] + red[1][1][ll] + red[1][2][ll] + red[1][3][ll];
    float m = S4 * (1.f / 256.f);
    mu[ni] = m;
    rsg[ni] = rsqrtf(Q4 * (1.f / 256.f) - m * m + 1e-5f);
  }
  #pragma unroll
  for (int mi = 0; mi < 4; ++mi) {
    int c = cb + mi * 16;
    f32x4 g4 = *(const f32x4*)&gff[c];
    f32x4 b4 = *(const f32x4*)&bff[c];
    #pragma unroll
    for (int ni = 0; ni < 4; ++ni) {
      int l = lb + ni * 16;
      f32x4 xv = acc[mi][ni];
      *(f32x4*)&xbuf[((size_t)b * LSP + l) * CCH + c] = xv;
      bf16x4 o;
      #pragma unroll
      for (int r = 0; r < 4; ++r)
        o[r] = (bf16)((xv[r] - mu[ni]) * rsg[ni] * g4[r] + b4[r]);
      *(bf16x4*)&hn[((size_t)b * LSP + l) * CCH + c] = o;
    }
  }
}

// ---------------------------------------------------------------------------
extern "C" void kernel_launch(void* const* d_in, const int* in_sizes, int n_in,
                              void* d_out, int out_size, void* d_ws,
                              size_t ws_size, hipStream_t stream) {
  const float* optical = (const float*)d_in[0];
  const float* sar     = (const float*)d_in[1];
  const float* g_opt   = (const float*)d_in[2];
  const float* b_opt   = (const float*)d_in[3];
  const float* g_sar   = (const float*)d_in[4];
  const float* b_sar   = (const float*)d_in[5];
  const float* Wq      = (const float*)d_in[6];
  const float* Wk      = (const float*)d_in[7];
  const float* Wv      = (const float*)d_in[8];
  const float* Wo      = (const float*)d_in[9];
  const float* g_ffn   = (const float*)d_in[10];
  const float* b_ffn   = (const float*)d_in[11];
  const float* W1      = (const float*)d_in[12];
  const float* b1      = (const float*)d_in[13];
  const float* W2      = (const float*)d_in[14];
  const float* b2      = (const float*)d_in[15];

  char* ws = (char*)d_ws;
  bf16* wbf  = (bf16*)ws;
  bf16* Wqb  = wbf;
  bf16* Wkb  = wbf + 65536;
  bf16* WvTb = wbf + 131072;
  bf16* Wob  = wbf + 196608;
  bf16* W1b  = wbf + 262144;
  bf16* W2b  = wbf + 524288;

  size_t off = 2ull * 1024 * 1024;
  const size_t T16 = 16ull * LSP * CCH * 2;  // 33.5 MB bf16 tensor
  bf16* opt_ncl = (bf16*)(ws + off); off += T16;
  bf16* sar_ncl = (bf16*)(ws + off); off += T16;
  bf16* sar_nlc = (bf16*)(ws + off); off += T16;
  bf16* hn      = (bf16*)(ws + off); off += T16;
  float* xbuf   = (float*)(ws + off); off += 2 * T16;              // 67 MB
  float* Gpart  = (float*)(ws + off); off += 16ull * 1024 * 1024;  // 16 MB
  bf16* G2b     = (bf16*)(ws + off); off += 4ull * 1024 * 1024;
  bf16* UTb     = (bf16*)(ws + off); off += 2ull * 1024 * 1024;
  bf16* Wfoldb  = (bf16*)(ws + off); off += 2ull * 1024 * 1024;
  bf16* gbuf = opt_ncl;  // 67 MB overlay (opt_ncl+sar_ncl dead after gram)

  dim3 blk(256);
  cvt_w_kernel<<<2560, blk, 0, stream>>>(Wq, Wk, Wv, Wo, W1, W2, wbf);
  ln_cl_kernel<<<256, blk, 0, stream>>>(optical, g_opt, b_opt, opt_ncl);
  ln_dual_kernel<<<256, blk, 0, stream>>>(sar, g_sar, b_sar, sar_ncl, sar_nlc);
  gram_kernel<<<dim3(4, 4, 16), blk, 0, stream>>>(sar_ncl, opt_ncl, Gpart);
  greduce_kernel<<<512, blk, 0, stream>>>(Gpart, G2b);
  fold2_kernel<<<128, blk, 0, stream>>>(G2b, Wqb, Wkb, WvTb, UTb);
  gemm_k<0><<<dim3(2, 2, 16), blk, 0, stream>>>(Wob, UTb, Wfoldb, nullptr,
                                                nullptr, 256, 256, 0);
  xgemm_ln_kernel<<<dim3(64, 16), blk, 0, stream>>>(Wfoldb, sar_nlc, optical,
                                                    g_ffn, b_ffn, xbuf, hn);
  gemm_k<3><<<dim3(32, 4, 16), blk, 0, stream>>>(W1b, hn, gbuf, nullptr, b1,
                                                 256, 4096, 0);
  gemm_k<4><<<dim3(32, 2, 16), blk, 0, stream>>>(W2b, gbuf, (float*)d_out,
                                                 xbuf, b2, 512, 4096, 0);
}

// Round 5
// 310.185 us; speedup vs baseline: 1.2955x; 1.0687x over previous
//
#include <hip/hip_runtime.h>
#include <hip/hip_bf16.h>

typedef __bf16 bf16;
typedef __attribute__((ext_vector_type(8))) __bf16 bf16x8;
typedef __attribute__((ext_vector_type(4))) __bf16 bf16x4;
typedef __attribute__((ext_vector_type(4))) float f32x4;
typedef __attribute__((ext_vector_type(16))) float f32x16;

#define LSP 4096   // H*W
#define CCH 256

__device__ __forceinline__ void gl2lds16(const bf16* g, bf16* l) {
  __builtin_amdgcn_global_load_lds(
      (const __attribute__((address_space(1))) unsigned int*)g,
      (__attribute__((address_space(3))) unsigned int*)l, 16, 0, 0);
}

__device__ __forceinline__ f32x4 mfma16(bf16x8 a, bf16x8 b, f32x4 c) {
  return __builtin_amdgcn_mfma_f32_16x16x32_bf16(a, b, c, 0, 0, 0);
}
__device__ __forceinline__ f32x16 mfma32(bf16x8 a, bf16x8 b, f32x16 c) {
  return __builtin_amdgcn_mfma_f32_32x32x16_bf16(a, b, c, 0, 0, 0);
}

// ---------------------------------------------------------------------------
// Weight f32 -> bf16. Wq,Wk direct; Wv TRANSPOSED (WvT[cin][och]); Wo direct;
// W1 INTERLEAVED (row 2a = W1[a], row 2a+1 = W1[a+512]) for in-register gate
// pairing; W2 direct.
// ---------------------------------------------------------------------------
__global__ __launch_bounds__(256) void cvt_w_kernel(
    const float* __restrict__ wq, const float* __restrict__ wk,
    const float* __restrict__ wv, const float* __restrict__ wo,
    const float* __restrict__ w1, const float* __restrict__ w2,
    bf16* __restrict__ out) {
  int e = blockIdx.x * 256 + threadIdx.x;   // grid 2560 -> 655360 exact
  if (e < 65536)        { out[e] = (bf16)wq[e]; }
  else if (e < 131072)  { out[e] = (bf16)wk[e - 65536]; }
  else if (e < 196608)  {
    int e2 = e - 131072;            // e2 = och*256 + cin
    int och = e2 >> 8, cin = e2 & 255;
    out[131072 + cin * 256 + och] = (bf16)wv[e2];   // WvT
  }
  else if (e < 262144)  { out[e] = (bf16)wo[e - 196608]; }
  else if (e < 524288)  {
    int e2 = e - 262144;            // m*256 + k, m in [0,1024)
    int m = e2 >> 8, k = e2 & 255;
    int mp = (m < 512) ? (2 * m) : (2 * (m - 512) + 1);
    out[262144 + mp * 256 + k] = (bf16)w1[e2];      // W1 interleaved
  }
  else                  { out[e] = (bf16)w2[e - 524288]; }
}

// ---------------------------------------------------------------------------
// LayerNorm over channels, input [b][c][l] f32, output [b][c][l] bf16
// ---------------------------------------------------------------------------
__global__ __launch_bounds__(256) void ln_cl_kernel(
    const float* __restrict__ x, const float* __restrict__ gam,
    const float* __restrict__ bet, bf16* __restrict__ out_cl) {
  int p = blockIdx.x * 256 + threadIdx.x;        // grid 256: 65536 positions
  int b = p >> 12, l = p & 4095;
  const float* px = x + (size_t)b * CCH * LSP + l;
  float s = 0.f, s2 = 0.f;
  #pragma unroll 16
  for (int c = 0; c < CCH; ++c) {
    float v = px[(size_t)c * LSP];
    s += v; s2 += v * v;
  }
  float mean = s * (1.f / 256.f);
  float var  = s2 * (1.f / 256.f) - mean * mean;
  float rs   = rsqrtf(var + 1e-5f);
  bf16* po = out_cl + (size_t)b * CCH * LSP + l;
  #pragma unroll 16
  for (int c = 0; c < CCH; ++c) {
    float v = px[(size_t)c * LSP];
    po[(size_t)c * LSP] = (bf16)((v - mean) * rs * gam[c] + bet[c]);
  }
}

// ---------------------------------------------------------------------------
// LayerNorm (sar): writes BOTH [b][c][l] (for gram) and [b][l][c] (for xgemm)
// ---------------------------------------------------------------------------
__global__ __launch_bounds__(256) void ln_dual_kernel(
    const float* __restrict__ x, const float* __restrict__ gam,
    const float* __restrict__ bet, bf16* __restrict__ out_cl,
    bf16* __restrict__ out_lc) {
  int p = blockIdx.x * 256 + threadIdx.x;
  int b = p >> 12, l = p & 4095;
  const float* px = x + (size_t)b * CCH * LSP + l;
  float s = 0.f, s2 = 0.f;
  #pragma unroll 16
  for (int c = 0; c < CCH; ++c) {
    float v = px[(size_t)c * LSP];
    s += v; s2 += v * v;
  }
  float mean = s * (1.f / 256.f);
  float var  = s2 * (1.f / 256.f) - mean * mean;
  float rs   = rsqrtf(var + 1e-5f);
  bf16* pcl = out_cl + (size_t)b * CCH * LSP + l;
  bf16* plc = out_lc + (size_t)p * CCH;
  #pragma unroll 8
  for (int c0 = 0; c0 < CCH; c0 += 4) {
    bf16x4 o;
    #pragma unroll
    for (int i = 0; i < 4; ++i) {
      float v = px[(size_t)(c0 + i) * LSP];
      bf16 r = (bf16)((v - mean) * rs * gam[c0 + i] + bet[c0 + i]);
      o[i] = r;
      pcl[(size_t)(c0 + i) * LSP] = r;
    }
    *(bf16x4*)&plc[c0] = o;
  }
}

// ---------------------------------------------------------------------------
// Gram: G2part[chunk][b][j][i] = sum_{l in chunk} sar_cl[b][j][l]*opt_cl[b][i][l]
// ---------------------------------------------------------------------------
__global__ __launch_bounds__(256) void gram_kernel(
    const bf16* __restrict__ sar_cl, const bf16* __restrict__ opt_cl,
    float* __restrict__ part) {
  const int tile = blockIdx.x, chunk = blockIdx.y, b = blockIdx.z;
  const int tid = threadIdx.x, lane = tid & 63, w = tid >> 6;
  const int j0 = (tile >> 1) * 128 + (w >> 1) * 64;
  const int i0 = (tile & 1) * 128 + (w & 1) * 64;
  const int l0 = chunk * 1024;
  const bf16* sj = sar_cl + ((size_t)b * CCH + j0 + (lane & 31)) * LSP + l0;
  const bf16* oi = opt_cl + ((size_t)b * CCH + i0 + (lane & 31)) * LSP + l0;
  f32x16 acc[2][2];
  #pragma unroll
  for (int mt = 0; mt < 2; ++mt)
    #pragma unroll
    for (int nt = 0; nt < 2; ++nt)
      #pragma unroll
      for (int r = 0; r < 16; ++r) acc[mt][nt][r] = 0.f;
  #pragma unroll 4
  for (int ks = 0; ks < 64; ++ks) {
    int lofs = ks * 16 + (lane >> 5) * 8;
    bf16x8 a0 = *(const bf16x8*)&sj[lofs];
    bf16x8 a1 = *(const bf16x8*)&sj[32 * LSP + lofs];
    bf16x8 b0 = *(const bf16x8*)&oi[lofs];
    bf16x8 b1 = *(const bf16x8*)&oi[32 * LSP + lofs];
    acc[0][0] = mfma32(a0, b0, acc[0][0]);
    acc[0][1] = mfma32(a0, b1, acc[0][1]);
    acc[1][0] = mfma32(a1, b0, acc[1][0]);
    acc[1][1] = mfma32(a1, b1, acc[1][1]);
  }
  float* op = part + ((size_t)chunk * 16 + b) * 65536;
  #pragma unroll
  for (int mt = 0; mt < 2; ++mt)
    #pragma unroll
    for (int nt = 0; nt < 2; ++nt)
      #pragma unroll
      for (int r = 0; r < 16; ++r) {
        int row = j0 + mt * 32 + (r & 3) + 8 * (r >> 2) + 4 * (lane >> 5);
        int col = i0 + nt * 32 + (lane & 31);
        op[(size_t)row * 256 + col] = acc[mt][nt][r];
      }
}

// ---------------------------------------------------------------------------
// Reduce Gram partials (4 chunks) -> G2 bf16 [b][j][i]
// ---------------------------------------------------------------------------
__global__ __launch_bounds__(256) void greduce_kernel(
    const float* __restrict__ part, bf16* __restrict__ G2) {
  size_t e = ((size_t)blockIdx.x * 256 + threadIdx.x) * 8;  // grid 512
  float a[8];
  #pragma unroll
  for (int i = 0; i < 8; ++i) a[i] = 0.f;
  #pragma unroll
  for (int ch = 0; ch < 4; ++ch) {
    f32x4 p0 = *(const f32x4*)&part[ch * 1048576ull + e];
    f32x4 p1 = *(const f32x4*)&part[ch * 1048576ull + e + 4];
    #pragma unroll
    for (int i = 0; i < 4; ++i) { a[i] += p0[i]; a[4 + i] += p1[i]; }
  }
  bf16x8 o;
  #pragma unroll
  for (int i = 0; i < 8; ++i) o[i] = (bf16)a[i];
  *(bf16x8*)&G2[e] = o;
}

// ---------------------------------------------------------------------------
// Fold: per (b,h): M1[c][j] = sum_i Wq_h[c][i]*G2[j][i],
// S[c][d] = sum_j M1[c][j]*Wk_h[d][j], softmax rows -> P,
// UT[b][cin][h*32+c] = sum_d WvT[cin][h*32+d]*P[c][d].
// ---------------------------------------------------------------------------
__global__ __launch_bounds__(256) void fold2_kernel(
    const bf16* __restrict__ G2, const bf16* __restrict__ Wq,
    const bf16* __restrict__ Wk, const bf16* __restrict__ WvT,
    bf16* __restrict__ UT) {
  const int bh = blockIdx.x;
  const int b = bh >> 3, h = bh & 7;
  const int tid = threadIdx.x, lane = tid & 63, w = tid >> 6;
  __shared__ bf16 M1[32 * 256];
  __shared__ float Sp[4][1024];
  __shared__ float S[1024];
  __shared__ bf16 P[1024];

  const bf16* gq = Wq + (size_t)(h * 32) * 256;
  const bf16* g2b = G2 + (size_t)b * 65536;
  #pragma unroll
  for (int mt = 0; mt < 2; ++mt)
    #pragma unroll
    for (int nt = 0; nt < 4; ++nt) {
      f32x4 acc = {0.f, 0.f, 0.f, 0.f};
      #pragma unroll
      for (int ks = 0; ks < 8; ++ks) {
        bf16x8 a = *(const bf16x8*)&gq[(size_t)(mt * 16 + (lane & 15)) * 256 +
                                       ks * 32 + (lane >> 4) * 8];
        bf16x8 bb = *(const bf16x8*)&g2b[
            (size_t)(w * 64 + nt * 16 + (lane & 15)) * 256 + ks * 32 +
            (lane >> 4) * 8];
        acc = mfma16(a, bb, acc);
      }
      #pragma unroll
      for (int r = 0; r < 4; ++r)
        M1[(mt * 16 + (lane >> 4) * 4 + r) * 256 + w * 64 + nt * 16 +
           (lane & 15)] = (bf16)acc[r];
    }
  __syncthreads();

  const bf16* gk = Wk + (size_t)(h * 32) * 256;
  #pragma unroll
  for (int mt = 0; mt < 2; ++mt)
    #pragma unroll
    for (int dt = 0; dt < 2; ++dt) {
      f32x4 acc = {0.f, 0.f, 0.f, 0.f};
      #pragma unroll
      for (int kk = 0; kk < 2; ++kk) {
        bf16x8 a = *(const bf16x8*)&M1[(mt * 16 + (lane & 15)) * 256 + w * 64 +
                                       kk * 32 + (lane >> 4) * 8];
        bf16x8 bb = *(const bf16x8*)&gk[(size_t)(dt * 16 + (lane & 15)) * 256 +
                                        w * 64 + kk * 32 + (lane >> 4) * 8];
        acc = mfma16(a, bb, acc);
      }
      #pragma unroll
      for (int r = 0; r < 4; ++r)
        Sp[w][(mt * 16 + (lane >> 4) * 4 + r) * 32 + dt * 16 + (lane & 15)] =
            acc[r];
    }
  __syncthreads();
  #pragma unroll
  for (int i = 0; i < 4; ++i) {
    int e = tid + 256 * i;
    S[e] = (Sp[0][e] + Sp[1][e] + Sp[2][e] + Sp[3][e]) * 0.17677669529663687f;
  }
  __syncthreads();
  if (tid < 32) {
    float m = -1e30f;
    #pragma unroll
    for (int d = 0; d < 32; ++d) m = fmaxf(m, S[tid * 32 + d]);
    float sum = 0.f;
    float ex[32];
    #pragma unroll
    for (int d = 0; d < 32; ++d) {
      ex[d] = __expf(S[tid * 32 + d] - m);
      sum += ex[d];
    }
    float inv = 1.f / sum;
    #pragma unroll
    for (int d = 0; d < 32; ++d) P[tid * 32 + d] = (bf16)(ex[d] * inv);
  }
  __syncthreads();

  bf16x8 bfrag[2];
  #pragma unroll
  for (int ct = 0; ct < 2; ++ct)
    bfrag[ct] =
        *(const bf16x8*)&P[(ct * 16 + (lane & 15)) * 32 + (lane >> 4) * 8];
  bf16* outb = UT + (size_t)b * 65536 + h * 32;
  #pragma unroll
  for (int t = 0; t < 4; ++t) {
    int cin16 = w * 64 + t * 16;
    bf16x8 afrag = *(const bf16x8*)&WvT[(size_t)(cin16 + (lane & 15)) * 256 +
                                        h * 32 + (lane >> 4) * 8];
    #pragma unroll
    for (int ct = 0; ct < 2; ++ct) {
      f32x4 acc = {0.f, 0.f, 0.f, 0.f};
      acc = mfma16(afrag, bfrag[ct], acc);
      int c = ct * 16 + (lane & 15);
      int cinr = cin16 + (lane >> 4) * 4;
      #pragma unroll
      for (int r = 0; r < 4; ++r)
        outb[(size_t)(cinr + r) * 256 + c] = (bf16)acc[r];
    }
  }
}

// ---------------------------------------------------------------------------
// Small GEMM for Wfold: out bf16 [b][256][256] = Wo @ UT   (128x128 tiles)
// ---------------------------------------------------------------------------
__global__ __launch_bounds__(256) void wfold_kernel(
    const bf16* __restrict__ Aw, const bf16* __restrict__ Bx,
    bf16* __restrict__ outp) {
  const int tid = threadIdx.x;
  const int lane = tid & 63;
  const int wave = tid >> 6;
  const int wr = wave >> 1, wc = wave & 1;
  const int l0 = blockIdx.x * 128;
  const int m0 = blockIdx.y * 128;
  const int b  = blockIdx.z;
  constexpr int NB = 4096;
  __shared__ bf16 smem[4 * NB];
  bf16* As = smem;
  bf16* Bs = smem + 2 * NB;
  const bf16* Ag = Aw + (size_t)m0 * 256;
  const bf16* Bg = Bx + ((size_t)b * 256 + l0) * 256;
  auto stage = [&](int buf, int k0) {
    #pragma unroll
    for (int i = 0; i < 2; ++i) {
      int ch = i * 256 + tid;
      int r  = ch >> 2;
      int c8 = (ch & 3) * 8;
      gl2lds16(Ag + (size_t)r * 256 + k0 + c8, As + buf * NB + ch * 8);
      gl2lds16(Bg + (size_t)r * 256 + k0 + c8, Bs + buf * NB + ch * 8);
    }
  };
  f32x4 acc[4][4];
  #pragma unroll
  for (int mi = 0; mi < 4; ++mi)
    #pragma unroll
    for (int ni = 0; ni < 4; ++ni)
      #pragma unroll
      for (int r = 0; r < 4; ++r) acc[mi][ni][r] = 0.f;
  stage(0, 0);
  for (int kt = 0; kt < 8; ++kt) {
    __syncthreads();
    if (kt + 1 < 8) stage((kt + 1) & 1, (kt + 1) * 32);
    const bf16* Ab = As + (kt & 1) * NB;
    const bf16* Bb = Bs + (kt & 1) * NB;
    bf16x8 af[4], bfr[4];
    #pragma unroll
    for (int mi = 0; mi < 4; ++mi)
      af[mi] = *(const bf16x8*)&Ab[(wr * 64 + mi * 16 + (lane & 15)) * 32 +
                                   (lane >> 4) * 8];
    #pragma unroll
    for (int ni = 0; ni < 4; ++ni)
      bfr[ni] = *(const bf16x8*)&Bb[(wc * 64 + ni * 16 + (lane & 15)) * 32 +
                                    (lane >> 4) * 8];
    #pragma unroll
    for (int mi = 0; mi < 4; ++mi)
      #pragma unroll
      for (int ni = 0; ni < 4; ++ni)
        acc[mi][ni] = mfma16(af[mi], bfr[ni], acc[mi][ni]);
  }
  const int mq = m0 + wr * 64 + (lane >> 4) * 4;
  const int lq = l0 + wc * 64 + (lane & 15);
  #pragma unroll
  for (int mi = 0; mi < 4; ++mi)
    #pragma unroll
    for (int ni = 0; ni < 4; ++ni) {
      int l = lq + ni * 16, mb = mq + mi * 16;
      #pragma unroll
      for (int r = 0; r < 4; ++r)
        outp[((size_t)b * 256 + mb + r) * 256 + l] = (bf16)acc[mi][ni][r];
    }
}

// ---------------------------------------------------------------------------
// Fused x-GEMM + residual + FFN LayerNorm (M=256, N=64, K=256).
// ---------------------------------------------------------------------------
__global__ __launch_bounds__(256) void xgemm_ln_kernel(
    const bf16* __restrict__ Wfold, const bf16* __restrict__ sar_lc,
    const float* __restrict__ optical, const float* __restrict__ gff,
    const float* __restrict__ bff, float* __restrict__ xbuf,
    bf16* __restrict__ hn) {
  const int tid = threadIdx.x, lane = tid & 63, w = tid >> 6;
  const int l0 = blockIdx.x * 64;
  const int b  = blockIdx.y;
  __shared__ bf16 As[2][256 * 32];
  __shared__ bf16 Bs[2][64 * 32];
  __shared__ float red[2][4][64];

  const bf16* Ag = Wfold + (size_t)b * 65536;
  const bf16* Bg = sar_lc + ((size_t)b * LSP + l0) * CCH;

  auto stage = [&](int buf, int k0) {
    #pragma unroll
    for (int i = 0; i < 4; ++i) {
      int ch = i * 256 + tid;
      int r = ch >> 2, c8 = (ch & 3) * 8;
      gl2lds16(Ag + (size_t)r * 256 + k0 + c8, &As[buf][ch * 8]);
    }
    {
      int r = tid >> 2, c8 = (tid & 3) * 8;
      gl2lds16(Bg + (size_t)r * 256 + k0 + c8, &Bs[buf][tid * 8]);
    }
  };

  f32x4 acc[4][4];
  #pragma unroll
  for (int mi = 0; mi < 4; ++mi)
    #pragma unroll
    for (int ni = 0; ni < 4; ++ni)
      #pragma unroll
      for (int r = 0; r < 4; ++r) acc[mi][ni][r] = 0.f;

  stage(0, 0);
  for (int kt = 0; kt < 8; ++kt) {
    __syncthreads();
    if (kt < 7) stage((kt + 1) & 1, (kt + 1) * 32);
    const bf16* Ab = As[kt & 1];
    const bf16* Bb = Bs[kt & 1];
    bf16x8 af[4], bfr[4];
    #pragma unroll
    for (int mi = 0; mi < 4; ++mi)
      af[mi] = *(const bf16x8*)&Ab[(w * 64 + mi * 16 + (lane & 15)) * 32 +
                                   (lane >> 4) * 8];
    #pragma unroll
    for (int ni = 0; ni < 4; ++ni)
      bfr[ni] = *(const bf16x8*)&Bb[(ni * 16 + (lane & 15)) * 32 +
                                    (lane >> 4) * 8];
    #pragma unroll
    for (int mi = 0; mi < 4; ++mi)
      #pragma unroll
      for (int ni = 0; ni < 4; ++ni)
        acc[mi][ni] = mfma16(af[mi], bfr[ni], acc[mi][ni]);
  }

  const int cb = w * 64 + (lane >> 4) * 4;
  const int lb = l0 + (lane & 15);
  float s[4], q[4];
  #pragma unroll
  for (int ni = 0; ni < 4; ++ni) { s[ni] = 0.f; q[ni] = 0.f; }
  #pragma unroll
  for (int mi = 0; mi < 4; ++mi)
    #pragma unroll
    for (int ni = 0; ni < 4; ++ni) {
      int c = cb + mi * 16, l = lb + ni * 16;
      #pragma unroll
      for (int r = 0; r < 4; ++r) {
        float v = acc[mi][ni][r] + optical[((size_t)b * CCH + c + r) * LSP + l];
        acc[mi][ni][r] = v;
        s[ni] += v; q[ni] += v * v;
      }
    }
  #pragma unroll
  for (int ni = 0; ni < 4; ++ni) {
    s[ni] += __shfl_xor(s[ni], 16);
    s[ni] += __shfl_xor(s[ni], 32);
    q[ni] += __shfl_xor(q[ni], 16);
    q[ni] += __shfl_xor(q[ni], 32);
  }
  if ((lane >> 4) == 0) {
    #pragma unroll
    for (int ni = 0; ni < 4; ++ni) {
      red[0][w][ni * 16 + (lane & 15)] = s[ni];
      red[1][w][ni * 16 + (lane & 15)] = q[ni];
    }
  }
  __syncthreads();
  float mu[4], rsg[4];
  #pragma unroll
  for (int ni = 0; ni < 4; ++ni) {
    int ll = ni * 16 + (lane & 15);
    float S4 = red[0][0][ll] + red[0][1][ll] + red[0][2][ll] + red[0][3][ll];
    float Q4 = red[1][0][ll] + red[1][1][ll] + red[1][2][ll] + red[1][3][ll];
    float m = S4 * (1.f / 256.f);
    mu[ni] = m;
    rsg[ni] = rsqrtf(Q4 * (1.f / 256.f) - m * m + 1e-5f);
  }
  #pragma unroll
  for (int mi = 0; mi < 4; ++mi) {
    int c = cb + mi * 16;
    f32x4 g4 = *(const f32x4*)&gff[c];
    f32x4 b4 = *(const f32x4*)&bff[c];
    #pragma unroll
    for (int ni = 0; ni < 4; ++ni) {
      int l = lb + ni * 16;
      f32x4 xv = acc[mi][ni];
      *(f32x4*)&xbuf[((size_t)b * LSP + l) * CCH + c] = xv;
      bf16x4 o;
      #pragma unroll
      for (int r = 0; r < 4; ++r)
        o[r] = (bf16)((xv[r] - mu[ni]) * rsg[ni] * g4[r] + b4[r]);
      *(bf16x4*)&hn[((size_t)b * LSP + l) * CCH + c] = o;
    }
  }
}

// ---------------------------------------------------------------------------
// 256x256-tile 8-phase GEMM (T2 swizzle + T3/T4 counted vmcnt + T5 setprio).
// out[m][l] = sum_k A[m][k] * B[b][l][k], 512 threads = 8 waves (2M x 4N),
// BK=64, per-phase: vmcnt(6); barrier; 12x ds_read; 1 half-tile stage
// (2x global_load_lds); lgkmcnt(0); 16 MFMA.
// LDS slots: {A,B} x {buf0,buf1} x {even,odd 16-row-group parity}; staged in
// ring order one phase after each slot's last reader; all stage->read edges
// are >=4 phases and vmcnt(6) at phase start forces exactly those.
// Swizzle: lds_byte ^= ((row&7)<<4) on reads; staging keeps LINEAR dest and
// pre-swizzles the global source column (same involution).
// MODE 0 (KEL=256): A = W1 interleaved; epilogue pairs even/odd rows ->
//   SimpleGate g, writes bf16 [b][l][512] via LDS transpose.
// MODE 1 (KEL=512): A = W2; epilogue adds b2 + res[b][l][c], writes f32
//   d_out [b][c][l] via LDS transpose (coalesced 1KB row runs).
// ---------------------------------------------------------------------------
template <int KEL, int MODE>
__global__ __launch_bounds__(512, 2) void ffn_gemm_kernel(
    const bf16* __restrict__ Aw, const bf16* __restrict__ Bx,
    void* __restrict__ outp, const float* __restrict__ res,
    const float* __restrict__ bias) {
  constexpr int LDSB = (MODE == 1) ? 135168 : 131072;
  __shared__ __align__(16) char smem_raw[LDSB];
  const int tid = threadIdx.x;
  const int lane = tid & 63;
  const int wave = tid >> 6;
  const int wr = wave >> 2;        // 0..1  (m half: 128 rows)
  const int wc = wave & 3;         // 0..3  (n quarter: 64 cols)
  const int l0 = blockIdx.x * 256;
  const int m0 = blockIdx.y * 256;
  const int b  = blockIdx.z;

  char* ldsA0 = smem_raw;                  // A tile buf0: 256x64 bf16 = 32KB
  char* ldsB0 = smem_raw + 32768;
  char* ldsA1 = smem_raw + 65536;
  char* ldsB1 = smem_raw + 98304;

  const bf16* Ag = Aw + (size_t)m0 * KEL;
  const bf16* Bg = Bx + ((size_t)b * LSP + l0) * KEL;

  // Stage one half-tile (128 rows of given 16-row-group parity) of one tensor.
  auto STAGE = [&](const bf16* gsrc, char* ldst, int par, int kt) {
    #pragma unroll
    for (int i = 0; i < 2; ++i) {
      int qi = i * 512 + tid;                       // 0..1023 chunk-in-half
      int r  = ((qi >> 7) << 5) + (par << 4) + ((qi >> 3) & 15);
      int cl = (qi & 7) ^ ((qi >> 3) & 7);          // pre-swizzled source col
      int p  = ((qi >> 7) << 8) + (par << 7) + (qi & 127);  // linear dest
      gl2lds16(gsrc + (size_t)r * KEL + kt * 64 + cl * 8,
               (bf16*)(ldst + p * 16));
    }
  };

  f32x4 acc[8][4];
  #pragma unroll
  for (int mi = 0; mi < 8; ++mi)
    #pragma unroll
    for (int ni = 0; ni < 4; ++ni)
      #pragma unroll
      for (int r = 0; r < 4; ++r) acc[mi][ni][r] = 0.f;

  bf16x8 af[4][2], bf[2][2];
  const int col0 = (((lane >> 4) << 4)) ^ ((lane & 7) << 4);
  const int col1 = col0 ^ 64;
  const int arow_off = (lane & 15) * 128;

#define LOAD_FRAGS(BUFA, BUFB, MP, NP)                                        \
  {                                                                           \
    const char* Ab_ = (BUFA);                                                 \
    const char* Bb_ = (BUFB);                                                 \
    _Pragma("unroll") for (int j = 0; j < 4; ++j) {                           \
      int rb = (wr * 128 + ((MP) + 2 * j) * 16) * 128 + arow_off;             \
      af[j][0] = *(const bf16x8*)(Ab_ + rb + col0);                           \
      af[j][1] = *(const bf16x8*)(Ab_ + rb + col1);                           \
    }                                                                         \
    _Pragma("unroll") for (int i = 0; i < 2; ++i) {                           \
      int rb = (wc * 64 + ((NP) + 2 * i) * 16) * 128 + arow_off;              \
      bf[i][0] = *(const bf16x8*)(Bb_ + rb + col0);                           \
      bf[i][1] = *(const bf16x8*)(Bb_ + rb + col1);                           \
    }                                                                         \
  }

#define DO_MFMA(MP, NP)                                                       \
  _Pragma("unroll") for (int j = 0; j < 4; ++j)                               \
  _Pragma("unroll") for (int i = 0; i < 2; ++i) {                             \
    acc[(MP) + 2 * j][(NP) + 2 * i] =                                         \
        mfma16(af[j][0], bf[i][0], acc[(MP) + 2 * j][(NP) + 2 * i]);          \
    acc[(MP) + 2 * j][(NP) + 2 * i] =                                         \
        mfma16(af[j][1], bf[i][1], acc[(MP) + 2 * j][(NP) + 2 * i]);          \
  }

#define PHASE(BUFA, BUFB, MP, NP, STG)                                        \
  asm volatile("s_waitcnt vmcnt(6)" ::: "memory");                            \
  __builtin_amdgcn_s_barrier();                                               \
  __builtin_amdgcn_sched_barrier(0);                                          \
  LOAD_FRAGS(BUFA, BUFB, MP, NP);                                             \
  STG;                                                                        \
  asm volatile("s_waitcnt lgkmcnt(0)" ::: "memory");                          \
  __builtin_amdgcn_sched_barrier(0);                                          \
  __builtin_amdgcn_s_setprio(1);                                              \
  DO_MFMA(MP, NP);                                                            \
  __builtin_amdgcn_s_setprio(0);

  // Prologue: kt0 full (4 halves) + kt1 even halves. 12 loads.
  STAGE(Ag, ldsA0, 0, 0);
  STAGE(Ag, ldsA0, 1, 0);
  STAGE(Bg, ldsB0, 0, 0);
  STAGE(Bg, ldsB0, 1, 0);
  STAGE(Ag, ldsA1, 0, 1);
  STAGE(Bg, ldsB1, 0, 1);

  constexpr int NITER = KEL / 128;
  for (int t = 0; t < NITER; ++t) {
    const int kt1 = 2 * t + 1;
    PHASE(ldsA0, ldsB0, 0, 0, STAGE(Ag, ldsA1, 1, kt1));      // ph1
    PHASE(ldsA0, ldsB0, 0, 1, STAGE(Bg, ldsB1, 1, kt1));      // ph2
    PHASE(ldsA0, ldsB0, 1, 0, STAGE(Ag, ldsA0, 0, kt1 + 1));  // ph3
    PHASE(ldsA0, ldsB0, 1, 1, STAGE(Bg, ldsB0, 0, kt1 + 1));  // ph4
    PHASE(ldsA1, ldsB1, 0, 0, STAGE(Ag, ldsA0, 1, kt1 + 1));  // ph5
    PHASE(ldsA1, ldsB1, 0, 1, STAGE(Bg, ldsB0, 1, kt1 + 1));  // ph6
    PHASE(ldsA1, ldsB1, 1, 0, STAGE(Ag, ldsA1, 0, kt1 + 2));  // ph7
    PHASE(ldsA1, ldsB1, 1, 1, STAGE(Bg, ldsB1, 0, kt1 + 2));  // ph8
  }
#undef PHASE
#undef DO_MFMA
#undef LOAD_FRAGS

  asm volatile("s_waitcnt vmcnt(0)" ::: "memory");
  __syncthreads();

  if constexpr (MODE == 0) {
    // SimpleGate epilogue: pair even/odd W1p rows -> g, LDS transpose, write.
    bf16* g_lds = (bf16*)smem_raw;           // [256 l][136 pad] bf16 = 68KB
    const int lq = wc * 64 + (lane & 15);
    const int qq = (lane >> 4);
    #pragma unroll
    for (int mi = 0; mi < 8; ++mi) {
      int a0 = wr * 64 + mi * 8 + qq * 2;    // local gate row (0..127)
      int ag = (m0 >> 1) + a0;               // global gate row (0..511)
      float b10 = bias[ag], b1h0 = bias[ag + 512];
      float b11 = bias[ag + 1], b1h1 = bias[ag + 1 + 512];
      #pragma unroll
      for (int ni = 0; ni < 4; ++ni) {
        int l = lq + ni * 16;
        float g0 = (acc[mi][ni][0] + b10) * (acc[mi][ni][1] + b1h0);
        float g1 = (acc[mi][ni][2] + b11) * (acc[mi][ni][3] + b1h1);
        bf16 gv0 = (bf16)g0, gv1 = (bf16)g1;
        unsigned u = ((unsigned)*(unsigned short*)&gv1 << 16) |
                     (unsigned)*(unsigned short*)&gv0;
        *(unsigned*)&g_lds[l * 136 + a0] = u;
      }
    }
    __syncthreads();
    bf16* out = (bf16*)outp;
    const int gy = blockIdx.y * 128;
    #pragma unroll
    for (int it = 0; it < 8; ++it) {
      int cid = it * 512 + tid;              // 4096 chunks of 16B
      int l = cid >> 4, ch = cid & 15;
      bf16x8 v = *(const bf16x8*)&g_lds[l * 136 + ch * 8];
      *(bf16x8*)&out[((size_t)b * LSP + l0 + l) * 512 + gy + ch * 8] = v;
    }
  } else {
    // Final epilogue: acc + b2 + res -> f32 d_out [b][c][l], LDS transpose.
    float* lds_f = (float*)smem_raw;         // [128 c][260 pad] f32 = 133KB
    float* out = (float*)outp;
    const int lq = wc * 64 + (lane & 15);
    const int qq = (lane >> 4);
    #pragma unroll
    for (int round = 0; round < 2; ++round) {
      if (wr == round) {
        #pragma unroll
        for (int mi = 0; mi < 8; ++mi) {
          int c0 = mi * 16 + qq * 4;         // local c (0..127)
          f32x4 b4 = *(const f32x4*)&bias[round * 128 + c0];
          #pragma unroll
          for (int ni = 0; ni < 4; ++ni) {
            int l = lq + ni * 16;
            f32x4 xr = *(const f32x4*)&res[((size_t)b * LSP + l0 + l) * CCH +
                                           round * 128 + c0];
            #pragma unroll
            for (int r = 0; r < 4; ++r)
              lds_f[(c0 + r) * 260 + l] = acc[mi][ni][r] + b4[r] + xr[r];
          }
        }
      }
      __syncthreads();
      #pragma unroll
      for (int it = 0; it < 16; ++it) {
        int cid = it * 512 + tid;            // 8192 chunks of 16B
        int c = cid >> 6, lch = cid & 63;
        f32x4 v = *(const f32x4*)&lds_f[c * 260 + lch * 4];
        *(f32x4*)&out[((size_t)b * CCH + round * 128 + c) * LSP + l0 +
                      lch * 4] = v;
      }
      __syncthreads();
    }
  }
}

// ---------------------------------------------------------------------------
extern "C" void kernel_launch(void* const* d_in, const int* in_sizes, int n_in,
                              void* d_out, int out_size, void* d_ws,
                              size_t ws_size, hipStream_t stream) {
  const float* optical = (const float*)d_in[0];
  const float* sar     = (const float*)d_in[1];
  const float* g_opt   = (const float*)d_in[2];
  const float* b_opt   = (const float*)d_in[3];
  const float* g_sar   = (const float*)d_in[4];
  const float* b_sar   = (const float*)d_in[5];
  const float* Wq      = (const float*)d_in[6];
  const float* Wk      = (const float*)d_in[7];
  const float* Wv      = (const float*)d_in[8];
  const float* Wo      = (const float*)d_in[9];
  const float* g_ffn   = (const float*)d_in[10];
  const float* b_ffn   = (const float*)d_in[11];
  const float* W1      = (const float*)d_in[12];
  const float* b1      = (const float*)d_in[13];
  const float* W2      = (const float*)d_in[14];
  const float* b2      = (const float*)d_in[15];

  char* ws = (char*)d_ws;
  bf16* wbf  = (bf16*)ws;
  bf16* Wqb  = wbf;
  bf16* Wkb  = wbf + 65536;
  bf16* WvTb = wbf + 131072;
  bf16* Wob  = wbf + 196608;
  bf16* W1b  = wbf + 262144;   // interleaved
  bf16* W2b  = wbf + 524288;

  size_t off = 2ull * 1024 * 1024;
  const size_t T16 = 16ull * LSP * CCH * 2;  // 33.5 MB bf16 tensor
  bf16* opt_ncl = (bf16*)(ws + off); off += T16;
  bf16* sar_ncl = (bf16*)(ws + off); off += T16;
  bf16* sar_nlc = (bf16*)(ws + off); off += T16;
  bf16* hn      = (bf16*)(ws + off); off += T16;
  float* xbuf   = (float*)(ws + off); off += 2 * T16;              // 67 MB
  float* Gpart  = (float*)(ws + off); off += 16ull * 1024 * 1024;  // 16 MB
  bf16* G2b     = (bf16*)(ws + off); off += 4ull * 1024 * 1024;
  bf16* UTb     = (bf16*)(ws + off); off += 2ull * 1024 * 1024;
  bf16* Wfoldb  = (bf16*)(ws + off); off += 2ull * 1024 * 1024;
  bf16* gbuf = opt_ncl;  // 67 MB overlay (opt_ncl+sar_ncl dead after gram)

  dim3 blk(256);
  cvt_w_kernel<<<2560, blk, 0, stream>>>(Wq, Wk, Wv, Wo, W1, W2, wbf);
  ln_cl_kernel<<<256, blk, 0, stream>>>(optical, g_opt, b_opt, opt_ncl);
  ln_dual_kernel<<<256, blk, 0, stream>>>(sar, g_sar, b_sar, sar_ncl, sar_nlc);
  gram_kernel<<<dim3(4, 4, 16), blk, 0, stream>>>(sar_ncl, opt_ncl, Gpart);
  greduce_kernel<<<512, blk, 0, stream>>>(Gpart, G2b);
  fold2_kernel<<<128, blk, 0, stream>>>(G2b, Wqb, Wkb, WvTb, UTb);
  wfold_kernel<<<dim3(2, 2, 16), blk, 0, stream>>>(Wob, UTb, Wfoldb);
  xgemm_ln_kernel<<<dim3(64, 16), blk, 0, stream>>>(Wfoldb, sar_nlc, optical,
                                                    g_ffn, b_ffn, xbuf, hn);
  ffn_gemm_kernel<256, 0><<<dim3(16, 4, 16), dim3(512), 0, stream>>>(
      W1b, hn, gbuf, nullptr, b1);
  ffn_gemm_kernel<512, 1><<<dim3(16, 1, 16), dim3(512), 0, stream>>>(
      W2b, gbuf, (float*)d_out, xbuf, b2);
}

// Round 6
// 281.683 us; speedup vs baseline: 1.4266x; 1.1012x over previous
//
#include <hip/hip_runtime.h>
#include <hip/hip_bf16.h>

typedef __bf16 bf16;
typedef __attribute__((ext_vector_type(8))) __bf16 bf16x8;
typedef __attribute__((ext_vector_type(4))) __bf16 bf16x4;
typedef __attribute__((ext_vector_type(4))) float f32x4;
typedef __attribute__((ext_vector_type(16))) float f32x16;

#define LSP 4096   // H*W
#define CCH 256

__device__ __forceinline__ void gl2lds16(const bf16* g, bf16* l) {
  __builtin_amdgcn_global_load_lds(
      (const __attribute__((address_space(1))) unsigned int*)g,
      (__attribute__((address_space(3))) unsigned int*)l, 16, 0, 0);
}

__device__ __forceinline__ f32x4 mfma16(bf16x8 a, bf16x8 b, f32x4 c) {
  return __builtin_amdgcn_mfma_f32_16x16x32_bf16(a, b, c, 0, 0, 0);
}
__device__ __forceinline__ f32x16 mfma32(bf16x8 a, bf16x8 b, f32x16 c) {
  return __builtin_amdgcn_mfma_f32_32x32x16_bf16(a, b, c, 0, 0, 0);
}

// ---------------------------------------------------------------------------
// Weight f32 -> bf16. Wq,Wk direct; Wv TRANSPOSED (WvT[cin][och]); Wo direct;
// W1 INTERLEAVED (row 2a = W1[a], row 2a+1 = W1[a+512]); W2 direct.
// ---------------------------------------------------------------------------
__global__ __launch_bounds__(256) void cvt_w_kernel(
    const float* __restrict__ wq, const float* __restrict__ wk,
    const float* __restrict__ wv, const float* __restrict__ wo,
    const float* __restrict__ w1, const float* __restrict__ w2,
    bf16* __restrict__ out) {
  int e = blockIdx.x * 256 + threadIdx.x;   // grid 2560 -> 655360 exact
  if (e < 65536)        { out[e] = (bf16)wq[e]; }
  else if (e < 131072)  { out[e] = (bf16)wk[e - 65536]; }
  else if (e < 196608)  {
    int e2 = e - 131072;            // e2 = och*256 + cin
    int och = e2 >> 8, cin = e2 & 255;
    out[131072 + cin * 256 + och] = (bf16)wv[e2];   // WvT
  }
  else if (e < 262144)  { out[e] = (bf16)wo[e - 196608]; }
  else if (e < 524288)  {
    int e2 = e - 262144;            // m*256 + k, m in [0,1024)
    int m = e2 >> 8, k = e2 & 255;
    int mp = (m < 512) ? (2 * m) : (2 * (m - 512) + 1);
    out[262144 + mp * 256 + k] = (bf16)w1[e2];      // W1 interleaved
  }
  else                  { out[e] = (bf16)w2[e - 524288]; }
}

// ---------------------------------------------------------------------------
// Tiled LayerNorm over channels. Input f32 [b][c][l]. Tile = 256c x 64l,
// grid (64 l-tiles, 16 b), 256 threads. Single global read pass (sums
// accumulated in registers during staging); tile held in LDS as bf16 with
// XOR swizzle (col ^= ((c>>3)&7)<<3) so the c-major transpose read is <=4-way.
// Outputs: [c][l] bf16 always; [l][c] bf16 when DUAL (both fully vectorized,
// coalesced).
// ---------------------------------------------------------------------------
template <int DUAL>
__global__ __launch_bounds__(256) void ln_tile_kernel(
    const float* __restrict__ x, const float* __restrict__ gam,
    const float* __restrict__ bet, bf16* __restrict__ out_cl,
    bf16* __restrict__ out_lc) {
  const int l0 = blockIdx.x * 64;
  const int b  = blockIdx.y;
  const int tid = threadIdx.x;
  __shared__ bf16 Tt[256 * 64];          // 32 KB, swizzled
  __shared__ float red[2][16][64];       // 8 KB
  __shared__ float mu_s[64], rs_s[64];

  const float* px = x + (size_t)b * CCH * LSP + l0;
  const int colq = (tid & 15) * 4;       // this thread's fixed 4-l column
  f32x4 s = {0.f, 0.f, 0.f, 0.f}, q = {0.f, 0.f, 0.f, 0.f};
  #pragma unroll
  for (int it = 0; it < 16; ++it) {
    int c = it * 16 + (tid >> 4);
    f32x4 v = *(const f32x4*)&px[(size_t)c * LSP + colq];
    s += v;
    q += v * v;
    bf16x4 h;
    #pragma unroll
    for (int j = 0; j < 4; ++j) h[j] = (bf16)v[j];
    int colp = colq ^ (((c >> 3) & 7) << 3);
    *(bf16x4*)&Tt[c * 64 + colp] = h;
  }
  #pragma unroll
  for (int j = 0; j < 4; ++j) {
    red[0][tid >> 4][colq + j] = s[j];
    red[1][tid >> 4][colq + j] = q[j];
  }
  __syncthreads();
  if (tid < 64) {
    float S = 0.f, Q = 0.f;
    #pragma unroll
    for (int k = 0; k < 16; ++k) { S += red[0][k][tid]; Q += red[1][k][tid]; }
    float m = S * (1.f / 256.f);
    mu_s[tid] = m;
    rs_s[tid] = rsqrtf(Q * (1.f / 256.f) - m * m + 1e-5f);
  }
  __syncthreads();

  // [c][l] output: bf16x8, 128B runs per 8 lanes
  #pragma unroll
  for (int it = 0; it < 8; ++it) {
    int ch = it * 256 + tid;
    int c = ch >> 3, col8 = (ch & 7) * 8;
    int colp = col8 ^ (((c >> 3) & 7) << 3);
    bf16x8 h = *(const bf16x8*)&Tt[c * 64 + colp];
    f32x4 m0 = *(const f32x4*)&mu_s[col8];
    f32x4 m1 = *(const f32x4*)&mu_s[col8 + 4];
    f32x4 r0 = *(const f32x4*)&rs_s[col8];
    f32x4 r1 = *(const f32x4*)&rs_s[col8 + 4];
    float g = gam[c], be = bet[c];
    bf16x8 o;
    #pragma unroll
    for (int j = 0; j < 4; ++j) {
      o[j]     = (bf16)(((float)h[j] - m0[j]) * r0[j] * g + be);
      o[4 + j] = (bf16)(((float)h[4 + j] - m1[j]) * r1[j] * g + be);
    }
    *(bf16x8*)&out_cl[((size_t)b * CCH + c) * LSP + l0 + col8] = o;
  }

  if constexpr (DUAL) {
    // [l][c] output: transpose read from LDS (swizzled), coalesced write
    #pragma unroll
    for (int it = 0; it < 8; ++it) {
      int ch = it * 256 + tid;
      int l = ch >> 5, cch = ch & 31;
      int c0 = cch * 8;
      int lp = l ^ ((cch & 7) << 3);
      float mu = mu_s[l], rs = rs_s[l];
      f32x4 g0 = *(const f32x4*)&gam[c0];
      f32x4 g1 = *(const f32x4*)&gam[c0 + 4];
      f32x4 b0 = *(const f32x4*)&bet[c0];
      f32x4 b1 = *(const f32x4*)&bet[c0 + 4];
      bf16x8 o;
      #pragma unroll
      for (int j = 0; j < 4; ++j) {
        float h0 = (float)Tt[(c0 + j) * 64 + lp];
        float h1 = (float)Tt[(c0 + 4 + j) * 64 + lp];
        o[j]     = (bf16)((h0 - mu) * rs * g0[j] + b0[j]);
        o[4 + j] = (bf16)((h1 - mu) * rs * g1[j] + b1[j]);
      }
      *(bf16x8*)&out_lc[((size_t)b * LSP + l0 + l) * CCH + c0] = o;
    }
  }
}

// ---------------------------------------------------------------------------
// Gram: G2part[chunk][b][j][i] = sum_{l in chunk} sar_cl[b][j][l]*opt_cl[b][i][l]
// ---------------------------------------------------------------------------
__global__ __launch_bounds__(256) void gram_kernel(
    const bf16* __restrict__ sar_cl, const bf16* __restrict__ opt_cl,
    float* __restrict__ part) {
  const int tile = blockIdx.x, chunk = blockIdx.y, b = blockIdx.z;
  const int tid = threadIdx.x, lane = tid & 63, w = tid >> 6;
  const int j0 = (tile >> 1) * 128 + (w >> 1) * 64;
  const int i0 = (tile & 1) * 128 + (w & 1) * 64;
  const int l0 = chunk * 1024;
  const bf16* sj = sar_cl + ((size_t)b * CCH + j0 + (lane & 31)) * LSP + l0;
  const bf16* oi = opt_cl + ((size_t)b * CCH + i0 + (lane & 31)) * LSP + l0;
  f32x16 acc[2][2];
  #pragma unroll
  for (int mt = 0; mt < 2; ++mt)
    #pragma unroll
    for (int nt = 0; nt < 2; ++nt)
      #pragma unroll
      for (int r = 0; r < 16; ++r) acc[mt][nt][r] = 0.f;
  #pragma unroll 4
  for (int ks = 0; ks < 64; ++ks) {
    int lofs = ks * 16 + (lane >> 5) * 8;
    bf16x8 a0 = *(const bf16x8*)&sj[lofs];
    bf16x8 a1 = *(const bf16x8*)&sj[32 * LSP + lofs];
    bf16x8 b0 = *(const bf16x8*)&oi[lofs];
    bf16x8 b1 = *(const bf16x8*)&oi[32 * LSP + lofs];
    acc[0][0] = mfma32(a0, b0, acc[0][0]);
    acc[0][1] = mfma32(a0, b1, acc[0][1]);
    acc[1][0] = mfma32(a1, b0, acc[1][0]);
    acc[1][1] = mfma32(a1, b1, acc[1][1]);
  }
  float* op = part + ((size_t)chunk * 16 + b) * 65536;
  #pragma unroll
  for (int mt = 0; mt < 2; ++mt)
    #pragma unroll
    for (int nt = 0; nt < 2; ++nt)
      #pragma unroll
      for (int r = 0; r < 16; ++r) {
        int row = j0 + mt * 32 + (r & 3) + 8 * (r >> 2) + 4 * (lane >> 5);
        int col = i0 + nt * 32 + (lane & 31);
        op[(size_t)row * 256 + col] = acc[mt][nt][r];
      }
}

// ---------------------------------------------------------------------------
// Reduce Gram partials (4 chunks) -> G2 bf16 [b][j][i]
// ---------------------------------------------------------------------------
__global__ __launch_bounds__(256) void greduce_kernel(
    const float* __restrict__ part, bf16* __restrict__ G2) {
  size_t e = ((size_t)blockIdx.x * 256 + threadIdx.x) * 8;  // grid 512
  float a[8];
  #pragma unroll
  for (int i = 0; i < 8; ++i) a[i] = 0.f;
  #pragma unroll
  for (int ch = 0; ch < 4; ++ch) {
    f32x4 p0 = *(const f32x4*)&part[ch * 1048576ull + e];
    f32x4 p1 = *(const f32x4*)&part[ch * 1048576ull + e + 4];
    #pragma unroll
    for (int i = 0; i < 4; ++i) { a[i] += p0[i]; a[4 + i] += p1[i]; }
  }
  bf16x8 o;
  #pragma unroll
  for (int i = 0; i < 8; ++i) o[i] = (bf16)a[i];
  *(bf16x8*)&G2[e] = o;
}

// ---------------------------------------------------------------------------
// Fold: per (b,h): M1[c][j] = sum_i Wq_h[c][i]*G2[j][i],
// S[c][d] = sum_j M1[c][j]*Wk_h[d][j], softmax rows -> P,
// UT[b][cin][h*32+c] = sum_d WvT[cin][h*32+d]*P[c][d].
// ---------------------------------------------------------------------------
__global__ __launch_bounds__(256) void fold2_kernel(
    const bf16* __restrict__ G2, const bf16* __restrict__ Wq,
    const bf16* __restrict__ Wk, const bf16* __restrict__ WvT,
    bf16* __restrict__ UT) {
  const int bh = blockIdx.x;
  const int b = bh >> 3, h = bh & 7;
  const int tid = threadIdx.x, lane = tid & 63, w = tid >> 6;
  __shared__ bf16 M1[32 * 256];
  __shared__ float Sp[4][1024];
  __shared__ float S[1024];
  __shared__ bf16 P[1024];

  const bf16* gq = Wq + (size_t)(h * 32) * 256;
  const bf16* g2b = G2 + (size_t)b * 65536;
  #pragma unroll
  for (int mt = 0; mt < 2; ++mt)
    #pragma unroll
    for (int nt = 0; nt < 4; ++nt) {
      f32x4 acc = {0.f, 0.f, 0.f, 0.f};
      #pragma unroll
      for (int ks = 0; ks < 8; ++ks) {
        bf16x8 a = *(const bf16x8*)&gq[(size_t)(mt * 16 + (lane & 15)) * 256 +
                                       ks * 32 + (lane >> 4) * 8];
        bf16x8 bb = *(const bf16x8*)&g2b[
            (size_t)(w * 64 + nt * 16 + (lane & 15)) * 256 + ks * 32 +
            (lane >> 4) * 8];
        acc = mfma16(a, bb, acc);
      }
      #pragma unroll
      for (int r = 0; r < 4; ++r)
        M1[(mt * 16 + (lane >> 4) * 4 + r) * 256 + w * 64 + nt * 16 +
           (lane & 15)] = (bf16)acc[r];
    }
  __syncthreads();

  const bf16* gk = Wk + (size_t)(h * 32) * 256;
  #pragma unroll
  for (int mt = 0; mt < 2; ++mt)
    #pragma unroll
    for (int dt = 0; dt < 2; ++dt) {
      f32x4 acc = {0.f, 0.f, 0.f, 0.f};
      #pragma unroll
      for (int kk = 0; kk < 2; ++kk) {
        bf16x8 a = *(const bf16x8*)&M1[(mt * 16 + (lane & 15)) * 256 + w * 64 +
                                       kk * 32 + (lane >> 4) * 8];
        bf16x8 bb = *(const bf16x8*)&gk[(size_t)(dt * 16 + (lane & 15)) * 256 +
                                        w * 64 + kk * 32 + (lane >> 4) * 8];
        acc = mfma16(a, bb, acc);
      }
      #pragma unroll
      for (int r = 0; r < 4; ++r)
        Sp[w][(mt * 16 + (lane >> 4) * 4 + r) * 32 + dt * 16 + (lane & 15)] =
            acc[r];
    }
  __syncthreads();
  #pragma unroll
  for (int i = 0; i < 4; ++i) {
    int e = tid + 256 * i;
    S[e] = (Sp[0][e] + Sp[1][e] + Sp[2][e] + Sp[3][e]) * 0.17677669529663687f;
  }
  __syncthreads();
  if (tid < 32) {
    float m = -1e30f;
    #pragma unroll
    for (int d = 0; d < 32; ++d) m = fmaxf(m, S[tid * 32 + d]);
    float sum = 0.f;
    float ex[32];
    #pragma unroll
    for (int d = 0; d < 32; ++d) {
      ex[d] = __expf(S[tid * 32 + d] - m);
      sum += ex[d];
    }
    float inv = 1.f / sum;
    #pragma unroll
    for (int d = 0; d < 32; ++d) P[tid * 32 + d] = (bf16)(ex[d] * inv);
  }
  __syncthreads();

  bf16x8 bfrag[2];
  #pragma unroll
  for (int ct = 0; ct < 2; ++ct)
    bfrag[ct] =
        *(const bf16x8*)&P[(ct * 16 + (lane & 15)) * 32 + (lane >> 4) * 8];
  bf16* outb = UT + (size_t)b * 65536 + h * 32;
  #pragma unroll
  for (int t = 0; t < 4; ++t) {
    int cin16 = w * 64 + t * 16;
    bf16x8 afrag = *(const bf16x8*)&WvT[(size_t)(cin16 + (lane & 15)) * 256 +
                                        h * 32 + (lane >> 4) * 8];
    #pragma unroll
    for (int ct = 0; ct < 2; ++ct) {
      f32x4 acc = {0.f, 0.f, 0.f, 0.f};
      acc = mfma16(afrag, bfrag[ct], acc);
      int c = ct * 16 + (lane & 15);
      int cinr = cin16 + (lane >> 4) * 4;
      #pragma unroll
      for (int r = 0; r < 4; ++r)
        outb[(size_t)(cinr + r) * 256 + c] = (bf16)acc[r];
    }
  }
}

// ---------------------------------------------------------------------------
// Small GEMM for Wfold: out bf16 [b][256][256] = Wo @ UT   (128x128 tiles)
// ---------------------------------------------------------------------------
__global__ __launch_bounds__(256) void wfold_kernel(
    const bf16* __restrict__ Aw, const bf16* __restrict__ Bx,
    bf16* __restrict__ outp) {
  const int tid = threadIdx.x;
  const int lane = tid & 63;
  const int wave = tid >> 6;
  const int wr = wave >> 1, wc = wave & 1;
  const int l0 = blockIdx.x * 128;
  const int m0 = blockIdx.y * 128;
  const int b  = blockIdx.z;
  constexpr int NB = 4096;
  __shared__ bf16 smem[4 * NB];
  bf16* As = smem;
  bf16* Bs = smem + 2 * NB;
  const bf16* Ag = Aw + (size_t)m0 * 256;
  const bf16* Bg = Bx + ((size_t)b * 256 + l0) * 256;
  auto stage = [&](int buf, int k0) {
    #pragma unroll
    for (int i = 0; i < 2; ++i) {
      int ch = i * 256 + tid;
      int r  = ch >> 2;
      int c8 = (ch & 3) * 8;
      gl2lds16(Ag + (size_t)r * 256 + k0 + c8, As + buf * NB + ch * 8);
      gl2lds16(Bg + (size_t)r * 256 + k0 + c8, Bs + buf * NB + ch * 8);
    }
  };
  f32x4 acc[4][4];
  #pragma unroll
  for (int mi = 0; mi < 4; ++mi)
    #pragma unroll
    for (int ni = 0; ni < 4; ++ni)
      #pragma unroll
      for (int r = 0; r < 4; ++r) acc[mi][ni][r] = 0.f;
  stage(0, 0);
  for (int kt = 0; kt < 8; ++kt) {
    __syncthreads();
    if (kt + 1 < 8) stage((kt + 1) & 1, (kt + 1) * 32);
    const bf16* Ab = As + (kt & 1) * NB;
    const bf16* Bb = Bs + (kt & 1) * NB;
    bf16x8 af[4], bfr[4];
    #pragma unroll
    for (int mi = 0; mi < 4; ++mi)
      af[mi] = *(const bf16x8*)&Ab[(wr * 64 + mi * 16 + (lane & 15)) * 32 +
                                   (lane >> 4) * 8];
    #pragma unroll
    for (int ni = 0; ni < 4; ++ni)
      bfr[ni] = *(const bf16x8*)&Bb[(wc * 64 + ni * 16 + (lane & 15)) * 32 +
                                    (lane >> 4) * 8];
    #pragma unroll
    for (int mi = 0; mi < 4; ++mi)
      #pragma unroll
      for (int ni = 0; ni < 4; ++ni)
        acc[mi][ni] = mfma16(af[mi], bfr[ni], acc[mi][ni]);
  }
  const int mq = m0 + wr * 64 + (lane >> 4) * 4;
  const int lq = l0 + wc * 64 + (lane & 15);
  #pragma unroll
  for (int mi = 0; mi < 4; ++mi)
    #pragma unroll
    for (int ni = 0; ni < 4; ++ni) {
      int l = lq + ni * 16, mb = mq + mi * 16;
      #pragma unroll
      for (int r = 0; r < 4; ++r)
        outp[((size_t)b * 256 + mb + r) * 256 + l] = (bf16)acc[mi][ni][r];
    }
}

// ---------------------------------------------------------------------------
// Fused x-GEMM + residual + FFN LayerNorm (M=256, N=64, K=256).
// ---------------------------------------------------------------------------
__global__ __launch_bounds__(256) void xgemm_ln_kernel(
    const bf16* __restrict__ Wfold, const bf16* __restrict__ sar_lc,
    const float* __restrict__ optical, const float* __restrict__ gff,
    const float* __restrict__ bff, float* __restrict__ xbuf,
    bf16* __restrict__ hn) {
  const int tid = threadIdx.x, lane = tid & 63, w = tid >> 6;
  const int l0 = blockIdx.x * 64;
  const int b  = blockIdx.y;
  __shared__ bf16 As[2][256 * 32];
  __shared__ bf16 Bs[2][64 * 32];
  __shared__ float red[2][4][64];

  const bf16* Ag = Wfold + (size_t)b * 65536;
  const bf16* Bg = sar_lc + ((size_t)b * LSP + l0) * CCH;

  auto stage = [&](int buf, int k0) {
    #pragma unroll
    for (int i = 0; i < 4; ++i) {
      int ch = i * 256 + tid;
      int r = ch >> 2, c8 = (ch & 3) * 8;
      gl2lds16(Ag + (size_t)r * 256 + k0 + c8, &As[buf][ch * 8]);
    }
    {
      int r = tid >> 2, c8 = (tid & 3) * 8;
      gl2lds16(Bg + (size_t)r * 256 + k0 + c8, &Bs[buf][tid * 8]);
    }
  };

  f32x4 acc[4][4];
  #pragma unroll
  for (int mi = 0; mi < 4; ++mi)
    #pragma unroll
    for (int ni = 0; ni < 4; ++ni)
      #pragma unroll
      for (int r = 0; r < 4; ++r) acc[mi][ni][r] = 0.f;

  stage(0, 0);
  for (int kt = 0; kt < 8; ++kt) {
    __syncthreads();
    if (kt < 7) stage((kt + 1) & 1, (kt + 1) * 32);
    const bf16* Ab = As[kt & 1];
    const bf16* Bb = Bs[kt & 1];
    bf16x8 af[4], bfr[4];
    #pragma unroll
    for (int mi = 0; mi < 4; ++mi)
      af[mi] = *(const bf16x8*)&Ab[(w * 64 + mi * 16 + (lane & 15)) * 32 +
                                   (lane >> 4) * 8];
    #pragma unroll
    for (int ni = 0; ni < 4; ++ni)
      bfr[ni] = *(const bf16x8*)&Bs[kt & 1][(ni * 16 + (lane & 15)) * 32 +
                                            (lane >> 4) * 8];
    #pragma unroll
    for (int mi = 0; mi < 4; ++mi)
      #pragma unroll
      for (int ni = 0; ni < 4; ++ni)
        acc[mi][ni] = mfma16(af[mi], bfr[ni], acc[mi][ni]);
    (void)Bb;
  }

  const int cb = w * 64 + (lane >> 4) * 4;
  const int lb = l0 + (lane & 15);
  float s[4], q[4];
  #pragma unroll
  for (int ni = 0; ni < 4; ++ni) { s[ni] = 0.f; q[ni] = 0.f; }
  #pragma unroll
  for (int mi = 0; mi < 4; ++mi)
    #pragma unroll
    for (int ni = 0; ni < 4; ++ni) {
      int c = cb + mi * 16, l = lb + ni * 16;
      #pragma unroll
      for (int r = 0; r < 4; ++r) {
        float v = acc[mi][ni][r] + optical[((size_t)b * CCH + c + r) * LSP + l];
        acc[mi][ni][r] = v;
        s[ni] += v; q[ni] += v * v;
      }
    }
  #pragma unroll
  for (int ni = 0; ni < 4; ++ni) {
    s[ni] += __shfl_xor(s[ni], 16);
    s[ni] += __shfl_xor(s[ni], 32);
    q[ni] += __shfl_xor(q[ni], 16);
    q[ni] += __shfl_xor(q[ni], 32);
  }
  if ((lane >> 4) == 0) {
    #pragma unroll
    for (int ni = 0; ni < 4; ++ni) {
      red[0][w][ni * 16 + (lane & 15)] = s[ni];
      red[1][w][ni * 16 + (lane & 15)] = q[ni];
    }
  }
  __syncthreads();
  float mu[4], rsg[4];
  #pragma unroll
  for (int ni = 0; ni < 4; ++ni) {
    int ll = ni * 16 + (lane & 15);
    float S4 = red[0][0][ll] + red[0][1][ll] + red[0][2][ll] + red[0][3][ll];
    float Q4 = red[1][0][ll] + red[1][1][ll] + red[1][2][ll] + red[1][3][ll];
    float m = S4 * (1.f / 256.f);
    mu[ni] = m;
    rsg[ni] = rsqrtf(Q4 * (1.f / 256.f) - m * m + 1e-5f);
  }
  #pragma unroll
  for (int mi = 0; mi < 4; ++mi) {
    int c = cb + mi * 16;
    f32x4 g4 = *(const f32x4*)&gff[c];
    f32x4 b4 = *(const f32x4*)&bff[c];
    #pragma unroll
    for (int ni = 0; ni < 4; ++ni) {
      int l = lb + ni * 16;
      f32x4 xv = acc[mi][ni];
      *(f32x4*)&xbuf[((size_t)b * LSP + l) * CCH + c] = xv;
      bf16x4 o;
      #pragma unroll
      for (int r = 0; r < 4; ++r)
        o[r] = (bf16)((xv[r] - mu[ni]) * rsg[ni] * g4[r] + b4[r]);
      *(bf16x4*)&hn[((size_t)b * LSP + l) * CCH + c] = o;
    }
  }
}

// ---------------------------------------------------------------------------
// 256x256-tile 8-phase GEMM (T2 swizzle + T3/T4 counted vmcnt + T5 setprio).
// MODE 0 (KEL=256): A = W1 interleaved -> SimpleGate, bf16 [b][l][512].
// MODE 1 (KEL=512): A = W2 -> + b2 + res, f32 d_out [b][c][l].
// ---------------------------------------------------------------------------
template <int KEL, int MODE>
__global__ __launch_bounds__(512, 2) void ffn_gemm_kernel(
    const bf16* __restrict__ Aw, const bf16* __restrict__ Bx,
    void* __restrict__ outp, const float* __restrict__ res,
    const float* __restrict__ bias) {
  constexpr int LDSB = (MODE == 1) ? 135168 : 131072;
  __shared__ __align__(16) char smem_raw[LDSB];
  const int tid = threadIdx.x;
  const int lane = tid & 63;
  const int wave = tid >> 6;
  const int wr = wave >> 2;        // 0..1  (m half: 128 rows)
  const int wc = wave & 3;         // 0..3  (n quarter: 64 cols)
  const int l0 = blockIdx.x * 256;
  const int m0 = blockIdx.y * 256;
  const int b  = blockIdx.z;

  char* ldsA0 = smem_raw;                  // A tile buf0: 256x64 bf16 = 32KB
  char* ldsB0 = smem_raw + 32768;
  char* ldsA1 = smem_raw + 65536;
  char* ldsB1 = smem_raw + 98304;

  const bf16* Ag = Aw + (size_t)m0 * KEL;
  const bf16* Bg = Bx + ((size_t)b * LSP + l0) * KEL;

  auto STAGE = [&](const bf16* gsrc, char* ldst, int par, int kt) {
    #pragma unroll
    for (int i = 0; i < 2; ++i) {
      int qi = i * 512 + tid;                       // 0..1023 chunk-in-half
      int r  = ((qi >> 7) << 5) + (par << 4) + ((qi >> 3) & 15);
      int cl = (qi & 7) ^ ((qi >> 3) & 7);          // pre-swizzled source col
      int p  = ((qi >> 7) << 8) + (par << 7) + (qi & 127);  // linear dest
      gl2lds16(gsrc + (size_t)r * KEL + kt * 64 + cl * 8,
               (bf16*)(ldst + p * 16));
    }
  };

  f32x4 acc[8][4];
  #pragma unroll
  for (int mi = 0; mi < 8; ++mi)
    #pragma unroll
    for (int ni = 0; ni < 4; ++ni)
      #pragma unroll
      for (int r = 0; r < 4; ++r) acc[mi][ni][r] = 0.f;

  bf16x8 af[4][2], bf[2][2];
  const int col0 = (((lane >> 4) << 4)) ^ ((lane & 7) << 4);
  const int col1 = col0 ^ 64;
  const int arow_off = (lane & 15) * 128;

#define LOAD_FRAGS(BUFA, BUFB, MP, NP)                                        \
  {                                                                           \
    const char* Ab_ = (BUFA);                                                 \
    const char* Bb_ = (BUFB);                                                 \
    _Pragma("unroll") for (int j = 0; j < 4; ++j) {                           \
      int rb = (wr * 128 + ((MP) + 2 * j) * 16) * 128 + arow_off;             \
      af[j][0] = *(const bf16x8*)(Ab_ + rb + col0);                           \
      af[j][1] = *(const bf16x8*)(Ab_ + rb + col1);                           \
    }                                                                         \
    _Pragma("unroll") for (int i = 0; i < 2; ++i) {                           \
      int rb = (wc * 64 + ((NP) + 2 * i) * 16) * 128 + arow_off;              \
      bf[i][0] = *(const bf16x8*)(Bb_ + rb + col0);                           \
      bf[i][1] = *(const bf16x8*)(Bb_ + rb + col1);                           \
    }                                                                         \
  }

#define DO_MFMA(MP, NP)                                                       \
  _Pragma("unroll") for (int j = 0; j < 4; ++j)                               \
  _Pragma("unroll") for (int i = 0; i < 2; ++i) {                             \
    acc[(MP) + 2 * j][(NP) + 2 * i] =                                         \
        mfma16(af[j][0], bf[i][0], acc[(MP) + 2 * j][(NP) + 2 * i]);          \
    acc[(MP) + 2 * j][(NP) + 2 * i] =                                         \
        mfma16(af[j][1], bf[i][1], acc[(MP) + 2 * j][(NP) + 2 * i]);          \
  }

#define PHASE(BUFA, BUFB, MP, NP, STG)                                        \
  asm volatile("s_waitcnt vmcnt(6)" ::: "memory");                            \
  __builtin_amdgcn_s_barrier();                                               \
  __builtin_amdgcn_sched_barrier(0);                                          \
  LOAD_FRAGS(BUFA, BUFB, MP, NP);                                             \
  STG;                                                                        \
  asm volatile("s_waitcnt lgkmcnt(0)" ::: "memory");                          \
  __builtin_amdgcn_sched_barrier(0);                                          \
  __builtin_amdgcn_s_setprio(1);                                              \
  DO_MFMA(MP, NP);                                                            \
  __builtin_amdgcn_s_setprio(0);

  STAGE(Ag, ldsA0, 0, 0);
  STAGE(Ag, ldsA0, 1, 0);
  STAGE(Bg, ldsB0, 0, 0);
  STAGE(Bg, ldsB0, 1, 0);
  STAGE(Ag, ldsA1, 0, 1);
  STAGE(Bg, ldsB1, 0, 1);

  constexpr int NITER = KEL / 128;
  for (int t = 0; t < NITER; ++t) {
    const int kt1 = 2 * t + 1;
    PHASE(ldsA0, ldsB0, 0, 0, STAGE(Ag, ldsA1, 1, kt1));      // ph1
    PHASE(ldsA0, ldsB0, 0, 1, STAGE(Bg, ldsB1, 1, kt1));      // ph2
    PHASE(ldsA0, ldsB0, 1, 0, STAGE(Ag, ldsA0, 0, kt1 + 1));  // ph3
    PHASE(ldsA0, ldsB0, 1, 1, STAGE(Bg, ldsB0, 0, kt1 + 1));  // ph4
    PHASE(ldsA1, ldsB1, 0, 0, STAGE(Ag, ldsA0, 1, kt1 + 1));  // ph5
    PHASE(ldsA1, ldsB1, 0, 1, STAGE(Bg, ldsB0, 1, kt1 + 1));  // ph6
    PHASE(ldsA1, ldsB1, 1, 0, STAGE(Ag, ldsA1, 0, kt1 + 2));  // ph7
    PHASE(ldsA1, ldsB1, 1, 1, STAGE(Bg, ldsB1, 0, kt1 + 2));  // ph8
  }
#undef PHASE
#undef DO_MFMA
#undef LOAD_FRAGS

  asm volatile("s_waitcnt vmcnt(0)" ::: "memory");
  __syncthreads();

  if constexpr (MODE == 0) {
    bf16* g_lds = (bf16*)smem_raw;           // [256 l][136 pad] bf16 = 68KB
    const int lq = wc * 64 + (lane & 15);
    const int qq = (lane >> 4);
    #pragma unroll
    for (int mi = 0; mi < 8; ++mi) {
      int a0 = wr * 64 + mi * 8 + qq * 2;    // local gate row (0..127)
      int ag = (m0 >> 1) + a0;               // global gate row (0..511)
      float b10 = bias[ag], b1h0 = bias[ag + 512];
      float b11 = bias[ag + 1], b1h1 = bias[ag + 1 + 512];
      #pragma unroll
      for (int ni = 0; ni < 4; ++ni) {
        int l = lq + ni * 16;
        float g0 = (acc[mi][ni][0] + b10) * (acc[mi][ni][1] + b1h0);
        float g1 = (acc[mi][ni][2] + b11) * (acc[mi][ni][3] + b1h1);
        bf16 gv0 = (bf16)g0, gv1 = (bf16)g1;
        unsigned u = ((unsigned)*(unsigned short*)&gv1 << 16) |
                     (unsigned)*(unsigned short*)&gv0;
        *(unsigned*)&g_lds[l * 136 + a0] = u;
      }
    }
    __syncthreads();
    bf16* out = (bf16*)outp;
    const int gy = blockIdx.y * 128;
    #pragma unroll
    for (int it = 0; it < 8; ++it) {
      int cid = it * 512 + tid;              // 4096 chunks of 16B
      int l = cid >> 4, ch = cid & 15;
      bf16x8 v = *(const bf16x8*)&g_lds[l * 136 + ch * 8];
      *(bf16x8*)&out[((size_t)b * LSP + l0 + l) * 512 + gy + ch * 8] = v;
    }
  } else {
    float* lds_f = (float*)smem_raw;         // [128 c][260 pad] f32 = 133KB
    float* out = (float*)outp;
    const int lq = wc * 64 + (lane & 15);
    const int qq = (lane >> 4);
    #pragma unroll
    for (int round = 0; round < 2; ++round) {
      if (wr == round) {
        #pragma unroll
        for (int mi = 0; mi < 8; ++mi) {
          int c0 = mi * 16 + qq * 4;         // local c (0..127)
          f32x4 b4 = *(const f32x4*)&bias[round * 128 + c0];
          #pragma unroll
          for (int ni = 0; ni < 4; ++ni) {
            int l = lq + ni * 16;
            f32x4 xr = *(const f32x4*)&res[((size_t)b * LSP + l0 + l) * CCH +
                                           round * 128 + c0];
            #pragma unroll
            for (int r = 0; r < 4; ++r)
              lds_f[(c0 + r) * 260 + l] = acc[mi][ni][r] + b4[r] + xr[r];
          }
        }
      }
      __syncthreads();
      #pragma unroll
      for (int it = 0; it < 16; ++it) {
        int cid = it * 512 + tid;            // 8192 chunks of 16B
        int c = cid >> 6, lch = cid & 63;
        f32x4 v = *(const f32x4*)&lds_f[c * 260 + lch * 4];
        *(f32x4*)&out[((size_t)b * CCH + round * 128 + c) * LSP + l0 +
                      lch * 4] = v;
      }
      __syncthreads();
    }
  }
}

// ---------------------------------------------------------------------------
extern "C" void kernel_launch(void* const* d_in, const int* in_sizes, int n_in,
                              void* d_out, int out_size, void* d_ws,
                              size_t ws_size, hipStream_t stream) {
  const float* optical = (const float*)d_in[0];
  const float* sar     = (const float*)d_in[1];
  const float* g_opt   = (const float*)d_in[2];
  const float* b_opt   = (const float*)d_in[3];
  const float* g_sar   = (const float*)d_in[4];
  const float* b_sar   = (const float*)d_in[5];
  const float* Wq      = (const float*)d_in[6];
  const float* Wk      = (const float*)d_in[7];
  const float* Wv      = (const float*)d_in[8];
  const float* Wo      = (const float*)d_in[9];
  const float* g_ffn   = (const float*)d_in[10];
  const float* b_ffn   = (const float*)d_in[11];
  const float* W1      = (const float*)d_in[12];
  const float* b1      = (const float*)d_in[13];
  const float* W2      = (const float*)d_in[14];
  const float* b2      = (const float*)d_in[15];

  char* ws = (char*)d_ws;
  bf16* wbf  = (bf16*)ws;
  bf16* Wqb  = wbf;
  bf16* Wkb  = wbf + 65536;
  bf16* WvTb = wbf + 131072;
  bf16* Wob  = wbf + 196608;
  bf16* W1b  = wbf + 262144;   // interleaved
  bf16* W2b  = wbf + 524288;

  size_t off = 2ull * 1024 * 1024;
  const size_t T16 = 16ull * LSP * CCH * 2;  // 33.5 MB bf16 tensor
  bf16* opt_ncl = (bf16*)(ws + off); off += T16;
  bf16* sar_ncl = (bf16*)(ws + off); off += T16;
  bf16* sar_nlc = (bf16*)(ws + off); off += T16;
  bf16* hn      = (bf16*)(ws + off); off += T16;
  float* xbuf   = (float*)(ws + off); off += 2 * T16;              // 67 MB
  float* Gpart  = (float*)(ws + off); off += 16ull * 1024 * 1024;  // 16 MB
  bf16* G2b     = (bf16*)(ws + off); off += 4ull * 1024 * 1024;
  bf16* UTb     = (bf16*)(ws + off); off += 2ull * 1024 * 1024;
  bf16* Wfoldb  = (bf16*)(ws + off); off += 2ull * 1024 * 1024;
  bf16* gbuf = opt_ncl;  // 67 MB overlay (opt_ncl+sar_ncl dead after gram)

  dim3 blk(256);
  cvt_w_kernel<<<2560, blk, 0, stream>>>(Wq, Wk, Wv, Wo, W1, W2, wbf);
  ln_tile_kernel<0><<<dim3(64, 16), blk, 0, stream>>>(optical, g_opt, b_opt,
                                                      opt_ncl, nullptr);
  ln_tile_kernel<1><<<dim3(64, 16), blk, 0, stream>>>(sar, g_sar, b_sar,
                                                      sar_ncl, sar_nlc);
  gram_kernel<<<dim3(4, 4, 16), blk, 0, stream>>>(sar_ncl, opt_ncl, Gpart);
  greduce_kernel<<<512, blk, 0, stream>>>(Gpart, G2b);
  fold2_kernel<<<128, blk, 0, stream>>>(G2b, Wqb, Wkb, WvTb, UTb);
  wfold_kernel<<<dim3(2, 2, 16), blk, 0, stream>>>(Wob, UTb, Wfoldb);
  xgemm_ln_kernel<<<dim3(64, 16), blk, 0, stream>>>(Wfoldb, sar_nlc, optical,
                                                    g_ffn, b_ffn, xbuf, hn);
  ffn_gemm_kernel<256, 0><<<dim3(16, 4, 16), dim3(512), 0, stream>>>(
      W1b, hn, gbuf, nullptr, b1);
  ffn_gemm_kernel<512, 1><<<dim3(16, 1, 16), dim3(512), 0, stream>>>(
      W2b, gbuf, (float*)d_out, xbuf, b2);
}

// Round 7
// 259.572 us; speedup vs baseline: 1.5481x; 1.0852x over previous
//
#include <hip/hip_runtime.h>
#include <hip/hip_bf16.h>

typedef __bf16 bf16;
typedef __attribute__((ext_vector_type(8))) __bf16 bf16x8;
typedef __attribute__((ext_vector_type(4))) __bf16 bf16x4;
typedef __attribute__((ext_vector_type(4))) float f32x4;
typedef __attribute__((ext_vector_type(16))) float f32x16;

#define LSP 4096   // H*W
#define CCH 256

__device__ __forceinline__ void gl2lds16(const bf16* g, bf16* l) {
  __builtin_amdgcn_global_load_lds(
      (const __attribute__((address_space(1))) unsigned int*)g,
      (__attribute__((address_space(3))) unsigned int*)l, 16, 0, 0);
}

__device__ __forceinline__ f32x4 mfma16(bf16x8 a, bf16x8 b, f32x4 c) {
  return __builtin_amdgcn_mfma_f32_16x16x32_bf16(a, b, c, 0, 0, 0);
}
__device__ __forceinline__ f32x16 mfma32(bf16x8 a, bf16x8 b, f32x16 c) {
  return __builtin_amdgcn_mfma_f32_32x32x16_bf16(a, b, c, 0, 0, 0);
}

// ---------------------------------------------------------------------------
// Weight f32 -> bf16. Wq,Wk direct; Wv TRANSPOSED (WvT[cin][och]); Wo direct;
// W1 INTERLEAVED and PRE-SCALED by g_ffn (row 2a = W1g[a], 2a+1 = W1g[a+512]);
// W2 direct.
// ---------------------------------------------------------------------------
__global__ __launch_bounds__(256) void cvt_w_kernel(
    const float* __restrict__ wq, const float* __restrict__ wk,
    const float* __restrict__ wv, const float* __restrict__ wo,
    const float* __restrict__ w1, const float* __restrict__ w2,
    const float* __restrict__ gff, bf16* __restrict__ out) {
  int e = blockIdx.x * 256 + threadIdx.x;   // grid 2560 -> 655360 exact
  if (e < 65536)        { out[e] = (bf16)wq[e]; }
  else if (e < 131072)  { out[e] = (bf16)wk[e - 65536]; }
  else if (e < 196608)  {
    int e2 = e - 131072;            // e2 = och*256 + cin
    int och = e2 >> 8, cin = e2 & 255;
    out[131072 + cin * 256 + och] = (bf16)wv[e2];   // WvT
  }
  else if (e < 262144)  { out[e] = (bf16)wo[e - 196608]; }
  else if (e < 524288)  {
    int e2 = e - 262144;            // m*256 + k, m in [0,1024)
    int m = e2 >> 8, k = e2 & 255;
    int mp = (m < 512) ? (2 * m) : (2 * (m - 512) + 1);
    out[262144 + mp * 256 + k] = (bf16)(w1[e2] * gff[k]);  // W1g interleaved
  }
  else                  { out[e] = (bf16)w2[e - 524288]; }
}

// ---------------------------------------------------------------------------
// Per-m FFN1 constants: cvec[0..511]=W1[m]@b_ffn+b1[m], [512..1023]=W1[m]@g_ffn,
// [1024..1535] / [1536..2047] = same for m+512. grid 4 x 256.
// ---------------------------------------------------------------------------
__global__ __launch_bounds__(256) void w1vec_kernel(
    const float* __restrict__ w1, const float* __restrict__ b1,
    const float* __restrict__ gff, const float* __restrict__ bff,
    float* __restrict__ cvec) {
  int m = blockIdx.x * 256 + threadIdx.x;   // 0..1023
  const float* row = w1 + (size_t)m * 256;
  float sb = 0.f, sg = 0.f;
  #pragma unroll 8
  for (int c = 0; c < 256; c += 4) {
    f32x4 w = *(const f32x4*)&row[c];
    f32x4 g = *(const f32x4*)&gff[c];
    f32x4 bb = *(const f32x4*)&bff[c];
    #pragma unroll
    for (int j = 0; j < 4; ++j) { sb += w[j] * bb[j]; sg += w[j] * g[j]; }
  }
  if (m < 512) {
    cvec[m] = sb + b1[m];
    cvec[512 + m] = sg;
  } else {
    cvec[512 + m] = sb + b1[m];       // 1024 + (m-512)
    cvec[1024 + m] = sg;              // 1536 + (m-512)
  }
}

// ---------------------------------------------------------------------------
// Tiled LayerNorm over channels. Input f32 [b][c][l]. Tile = 256c x 64l.
// ---------------------------------------------------------------------------
template <int DUAL>
__global__ __launch_bounds__(256) void ln_tile_kernel(
    const float* __restrict__ x, const float* __restrict__ gam,
    const float* __restrict__ bet, bf16* __restrict__ out_cl,
    bf16* __restrict__ out_lc) {
  const int l0 = blockIdx.x * 64;
  const int b  = blockIdx.y;
  const int tid = threadIdx.x;
  __shared__ bf16 Tt[256 * 64];          // 32 KB, swizzled
  __shared__ float red[2][16][64];       // 8 KB
  __shared__ float mu_s[64], rs_s[64];

  const float* px = x + (size_t)b * CCH * LSP + l0;
  const int colq = (tid & 15) * 4;
  f32x4 s = {0.f, 0.f, 0.f, 0.f}, q = {0.f, 0.f, 0.f, 0.f};
  #pragma unroll
  for (int it = 0; it < 16; ++it) {
    int c = it * 16 + (tid >> 4);
    f32x4 v = *(const f32x4*)&px[(size_t)c * LSP + colq];
    s += v;
    q += v * v;
    bf16x4 h;
    #pragma unroll
    for (int j = 0; j < 4; ++j) h[j] = (bf16)v[j];
    int colp = colq ^ (((c >> 3) & 7) << 3);
    *(bf16x4*)&Tt[c * 64 + colp] = h;
  }
  #pragma unroll
  for (int j = 0; j < 4; ++j) {
    red[0][tid >> 4][colq + j] = s[j];
    red[1][tid >> 4][colq + j] = q[j];
  }
  __syncthreads();
  if (tid < 64) {
    float S = 0.f, Q = 0.f;
    #pragma unroll
    for (int k = 0; k < 16; ++k) { S += red[0][k][tid]; Q += red[1][k][tid]; }
    float m = S * (1.f / 256.f);
    mu_s[tid] = m;
    rs_s[tid] = rsqrtf(Q * (1.f / 256.f) - m * m + 1e-5f);
  }
  __syncthreads();

  #pragma unroll
  for (int it = 0; it < 8; ++it) {
    int ch = it * 256 + tid;
    int c = ch >> 3, col8 = (ch & 7) * 8;
    int colp = col8 ^ (((c >> 3) & 7) << 3);
    bf16x8 h = *(const bf16x8*)&Tt[c * 64 + colp];
    f32x4 m0 = *(const f32x4*)&mu_s[col8];
    f32x4 m1 = *(const f32x4*)&mu_s[col8 + 4];
    f32x4 r0 = *(const f32x4*)&rs_s[col8];
    f32x4 r1 = *(const f32x4*)&rs_s[col8 + 4];
    float g = gam[c], be = bet[c];
    bf16x8 o;
    #pragma unroll
    for (int j = 0; j < 4; ++j) {
      o[j]     = (bf16)(((float)h[j] - m0[j]) * r0[j] * g + be);
      o[4 + j] = (bf16)(((float)h[4 + j] - m1[j]) * r1[j] * g + be);
    }
    *(bf16x8*)&out_cl[((size_t)b * CCH + c) * LSP + l0 + col8] = o;
  }

  if constexpr (DUAL) {
    #pragma unroll
    for (int it = 0; it < 8; ++it) {
      int ch = it * 256 + tid;
      int l = ch >> 5, cch = ch & 31;
      int c0 = cch * 8;
      int lp = l ^ ((cch & 7) << 3);
      float mu = mu_s[l], rs = rs_s[l];
      f32x4 g0 = *(const f32x4*)&gam[c0];
      f32x4 g1 = *(const f32x4*)&gam[c0 + 4];
      f32x4 b0 = *(const f32x4*)&bet[c0];
      f32x4 b1 = *(const f32x4*)&bet[c0 + 4];
      bf16x8 o;
      #pragma unroll
      for (int j = 0; j < 4; ++j) {
        float h0 = (float)Tt[(c0 + j) * 64 + lp];
        float h1 = (float)Tt[(c0 + 4 + j) * 64 + lp];
        o[j]     = (bf16)((h0 - mu) * rs * g0[j] + b0[j]);
        o[4 + j] = (bf16)((h1 - mu) * rs * g1[j] + b1[j]);
      }
      *(bf16x8*)&out_lc[((size_t)b * LSP + l0 + l) * CCH + c0] = o;
    }
  }
}

// ---------------------------------------------------------------------------
// Gram: G2part[chunk][b][j][i] = sum_{l in chunk} sar_cl[b][j][l]*opt_cl[b][i][l]
// ---------------------------------------------------------------------------
__global__ __launch_bounds__(256) void gram_kernel(
    const bf16* __restrict__ sar_cl, const bf16* __restrict__ opt_cl,
    float* __restrict__ part) {
  const int tile = blockIdx.x, chunk = blockIdx.y, b = blockIdx.z;
  const int tid = threadIdx.x, lane = tid & 63, w = tid >> 6;
  const int j0 = (tile >> 1) * 128 + (w >> 1) * 64;
  const int i0 = (tile & 1) * 128 + (w & 1) * 64;
  const int l0 = chunk * 1024;
  const bf16* sj = sar_cl + ((size_t)b * CCH + j0 + (lane & 31)) * LSP + l0;
  const bf16* oi = opt_cl + ((size_t)b * CCH + i0 + (lane & 31)) * LSP + l0;
  f32x16 acc[2][2];
  #pragma unroll
  for (int mt = 0; mt < 2; ++mt)
    #pragma unroll
    for (int nt = 0; nt < 2; ++nt)
      #pragma unroll
      for (int r = 0; r < 16; ++r) acc[mt][nt][r] = 0.f;
  #pragma unroll 4
  for (int ks = 0; ks < 64; ++ks) {
    int lofs = ks * 16 + (lane >> 5) * 8;
    bf16x8 a0 = *(const bf16x8*)&sj[lofs];
    bf16x8 a1 = *(const bf16x8*)&sj[32 * LSP + lofs];
    bf16x8 b0 = *(const bf16x8*)&oi[lofs];
    bf16x8 b1 = *(const bf16x8*)&oi[32 * LSP + lofs];
    acc[0][0] = mfma32(a0, b0, acc[0][0]);
    acc[0][1] = mfma32(a0, b1, acc[0][1]);
    acc[1][0] = mfma32(a1, b0, acc[1][0]);
    acc[1][1] = mfma32(a1, b1, acc[1][1]);
  }
  float* op = part + ((size_t)chunk * 16 + b) * 65536;
  #pragma unroll
  for (int mt = 0; mt < 2; ++mt)
    #pragma unroll
    for (int nt = 0; nt < 2; ++nt)
      #pragma unroll
      for (int r = 0; r < 16; ++r) {
        int row = j0 + mt * 32 + (r & 3) + 8 * (r >> 2) + 4 * (lane >> 5);
        int col = i0 + nt * 32 + (lane & 31);
        op[(size_t)row * 256 + col] = acc[mt][nt][r];
      }
}

// ---------------------------------------------------------------------------
// Reduce Gram partials (4 chunks) -> G2 bf16 [b][j][i]
// ---------------------------------------------------------------------------
__global__ __launch_bounds__(256) void greduce_kernel(
    const float* __restrict__ part, bf16* __restrict__ G2) {
  size_t e = ((size_t)blockIdx.x * 256 + threadIdx.x) * 8;  // grid 512
  float a[8];
  #pragma unroll
  for (int i = 0; i < 8; ++i) a[i] = 0.f;
  #pragma unroll
  for (int ch = 0; ch < 4; ++ch) {
    f32x4 p0 = *(const f32x4*)&part[ch * 1048576ull + e];
    f32x4 p1 = *(const f32x4*)&part[ch * 1048576ull + e + 4];
    #pragma unroll
    for (int i = 0; i < 4; ++i) { a[i] += p0[i]; a[4 + i] += p1[i]; }
  }
  bf16x8 o;
  #pragma unroll
  for (int i = 0; i < 8; ++i) o[i] = (bf16)a[i];
  *(bf16x8*)&G2[e] = o;
}

// ---------------------------------------------------------------------------
// Fold: per (b,h): M1[c][j] = sum_i Wq_h[c][i]*G2[j][i],
// S[c][d] = sum_j M1[c][j]*Wk_h[d][j], softmax rows -> P,
// UT[b][cin][h*32+c] = sum_d WvT[cin][h*32+d]*P[c][d].
// ---------------------------------------------------------------------------
__global__ __launch_bounds__(256) void fold2_kernel(
    const bf16* __restrict__ G2, const bf16* __restrict__ Wq,
    const bf16* __restrict__ Wk, const bf16* __restrict__ WvT,
    bf16* __restrict__ UT) {
  const int bh = blockIdx.x;
  const int b = bh >> 3, h = bh & 7;
  const int tid = threadIdx.x, lane = tid & 63, w = tid >> 6;
  __shared__ bf16 M1[32 * 256];
  __shared__ float Sp[4][1024];
  __shared__ float S[1024];
  __shared__ bf16 P[1024];

  const bf16* gq = Wq + (size_t)(h * 32) * 256;
  const bf16* g2b = G2 + (size_t)b * 65536;
  #pragma unroll
  for (int mt = 0; mt < 2; ++mt)
    #pragma unroll
    for (int nt = 0; nt < 4; ++nt) {
      f32x4 acc = {0.f, 0.f, 0.f, 0.f};
      #pragma unroll
      for (int ks = 0; ks < 8; ++ks) {
        bf16x8 a = *(const bf16x8*)&gq[(size_t)(mt * 16 + (lane & 15)) * 256 +
                                       ks * 32 + (lane >> 4) * 8];
        bf16x8 bb = *(const bf16x8*)&g2b[
            (size_t)(w * 64 + nt * 16 + (lane & 15)) * 256 + ks * 32 +
            (lane >> 4) * 8];
        acc = mfma16(a, bb, acc);
      }
      #pragma unroll
      for (int r = 0; r < 4; ++r)
        M1[(mt * 16 + (lane >> 4) * 4 + r) * 256 + w * 64 + nt * 16 +
           (lane & 15)] = (bf16)acc[r];
    }
  __syncthreads();

  const bf16* gk = Wk + (size_t)(h * 32) * 256;
  #pragma unroll
  for (int mt = 0; mt < 2; ++mt)
    #pragma unroll
    for (int dt = 0; dt < 2; ++dt) {
      f32x4 acc = {0.f, 0.f, 0.f, 0.f};
      #pragma unroll
      for (int kk = 0; kk < 2; ++kk) {
        bf16x8 a = *(const bf16x8*)&M1[(mt * 16 + (lane & 15)) * 256 + w * 64 +
                                       kk * 32 + (lane >> 4) * 8];
        bf16x8 bb = *(const bf16x8*)&gk[(size_t)(dt * 16 + (lane & 15)) * 256 +
                                        w * 64 + kk * 32 + (lane >> 4) * 8];
        acc = mfma16(a, bb, acc);
      }
      #pragma unroll
      for (int r = 0; r < 4; ++r)
        Sp[w][(mt * 16 + (lane >> 4) * 4 + r) * 32 + dt * 16 + (lane & 15)] =
            acc[r];
    }
  __syncthreads();
  #pragma unroll
  for (int i = 0; i < 4; ++i) {
    int e = tid + 256 * i;
    S[e] = (Sp[0][e] + Sp[1][e] + Sp[2][e] + Sp[3][e]) * 0.17677669529663687f;
  }
  __syncthreads();
  if (tid < 32) {
    float m = -1e30f;
    #pragma unroll
    for (int d = 0; d < 32; ++d) m = fmaxf(m, S[tid * 32 + d]);
    float sum = 0.f;
    float ex[32];
    #pragma unroll
    for (int d = 0; d < 32; ++d) {
      ex[d] = __expf(S[tid * 32 + d] - m);
      sum += ex[d];
    }
    float inv = 1.f / sum;
    #pragma unroll
    for (int d = 0; d < 32; ++d) P[tid * 32 + d] = (bf16)(ex[d] * inv);
  }
  __syncthreads();

  bf16x8 bfrag[2];
  #pragma unroll
  for (int ct = 0; ct < 2; ++ct)
    bfrag[ct] =
        *(const bf16x8*)&P[(ct * 16 + (lane & 15)) * 32 + (lane >> 4) * 8];
  bf16* outb = UT + (size_t)b * 65536 + h * 32;
  #pragma unroll
  for (int t = 0; t < 4; ++t) {
    int cin16 = w * 64 + t * 16;
    bf16x8 afrag = *(const bf16x8*)&WvT[(size_t)(cin16 + (lane & 15)) * 256 +
                                        h * 32 + (lane >> 4) * 8];
    #pragma unroll
    for (int ct = 0; ct < 2; ++ct) {
      f32x4 acc = {0.f, 0.f, 0.f, 0.f};
      acc = mfma16(afrag, bfrag[ct], acc);
      int c = ct * 16 + (lane & 15);
      int cinr = cin16 + (lane >> 4) * 4;
      #pragma unroll
      for (int r = 0; r < 4; ++r)
        outb[(size_t)(cinr + r) * 256 + c] = (bf16)acc[r];
    }
  }
}

// ---------------------------------------------------------------------------
// Small GEMM for Wfold: out bf16 [b][256][256] = Wo @ UT   (128x128 tiles)
// ---------------------------------------------------------------------------
__global__ __launch_bounds__(256) void wfold_kernel(
    const bf16* __restrict__ Aw, const bf16* __restrict__ Bx,
    bf16* __restrict__ outp) {
  const int tid = threadIdx.x;
  const int lane = tid & 63;
  const int wave = tid >> 6;
  const int wr = wave >> 1, wc = wave & 1;
  const int l0 = blockIdx.x * 128;
  const int m0 = blockIdx.y * 128;
  const int b  = blockIdx.z;
  constexpr int NB = 4096;
  __shared__ bf16 smem[4 * NB];
  bf16* As = smem;
  bf16* Bs = smem + 2 * NB;
  const bf16* Ag = Aw + (size_t)m0 * 256;
  const bf16* Bg = Bx + ((size_t)b * 256 + l0) * 256;
  auto stage = [&](int buf, int k0) {
    #pragma unroll
    for (int i = 0; i < 2; ++i) {
      int ch = i * 256 + tid;
      int r  = ch >> 2;
      int c8 = (ch & 3) * 8;
      gl2lds16(Ag + (size_t)r * 256 + k0 + c8, As + buf * NB + ch * 8);
      gl2lds16(Bg + (size_t)r * 256 + k0 + c8, Bs + buf * NB + ch * 8);
    }
  };
  f32x4 acc[4][4];
  #pragma unroll
  for (int mi = 0; mi < 4; ++mi)
    #pragma unroll
    for (int ni = 0; ni < 4; ++ni)
      #pragma unroll
      for (int r = 0; r < 4; ++r) acc[mi][ni][r] = 0.f;
  stage(0, 0);
  for (int kt = 0; kt < 8; ++kt) {
    __syncthreads();
    if (kt + 1 < 8) stage((kt + 1) & 1, (kt + 1) * 32);
    const bf16* Ab = As + (kt & 1) * NB;
    const bf16* Bb = Bs + (kt & 1) * NB;
    bf16x8 af[4], bfr[4];
    #pragma unroll
    for (int mi = 0; mi < 4; ++mi)
      af[mi] = *(const bf16x8*)&Ab[(wr * 64 + mi * 16 + (lane & 15)) * 32 +
                                   (lane >> 4) * 8];
    #pragma unroll
    for (int ni = 0; ni < 4; ++ni)
      bfr[ni] = *(const bf16x8*)&Bb[(wc * 64 + ni * 16 + (lane & 15)) * 32 +
                                    (lane >> 4) * 8];
    #pragma unroll
    for (int mi = 0; mi < 4; ++mi)
      #pragma unroll
      for (int ni = 0; ni < 4; ++ni)
        acc[mi][ni] = mfma16(af[mi], bfr[ni], acc[mi][ni]);
  }
  const int mq = m0 + wr * 64 + (lane >> 4) * 4;
  const int lq = l0 + wc * 64 + (lane & 15);
  #pragma unroll
  for (int mi = 0; mi < 4; ++mi)
    #pragma unroll
    for (int ni = 0; ni < 4; ++ni) {
      int l = lq + ni * 16, mb = mq + mi * 16;
      #pragma unroll
      for (int r = 0; r < 4; ++r)
        outp[((size_t)b * 256 + mb + r) * 256 + l] = (bf16)acc[mi][ni][r];
    }
}

// ---------------------------------------------------------------------------
// Fused x-GEMM + residual + LN-stats (M=256, N=64, K=256).
// x[c][l] = sum_k Wfold[b][c][k]*sar_lc[b][l][k] + optical[b][c][l]
// Writes x bf16 [b][l][c] (via LDS transpose, coalesced) and per-l
// stats[b][l] = {mu, rs} f32. The LN affine itself is folded into ffn1.
// ---------------------------------------------------------------------------
__global__ __launch_bounds__(256) void xgemm_stats_kernel(
    const bf16* __restrict__ Wfold, const bf16* __restrict__ sar_lc,
    const float* __restrict__ optical, bf16* __restrict__ xout,
    float* __restrict__ stats) {
  const int tid = threadIdx.x, lane = tid & 63, w = tid >> 6;
  const int l0 = blockIdx.x * 64;
  const int b  = blockIdx.y;
  __shared__ __align__(16) char smem[43520];
  // [0,32768): As[2][256*32]bf16 ; [32768,40960): Bs[2][64*32]bf16
  // [40960,43008): red[2][4][64] f32 ; epilogue overlay: X bf16 [64][260]
  bf16* X = (bf16*)smem;
  float* red = (float*)(smem + 40960);

  const bf16* Ag = Wfold + (size_t)b * 65536;
  const bf16* Bg = sar_lc + ((size_t)b * LSP + l0) * CCH;

  auto stage = [&](int buf, int k0) {
    bf16* As = (bf16*)(smem + buf * 16384);
    bf16* Bs = (bf16*)(smem + 32768 + buf * 4096);
    #pragma unroll
    for (int i = 0; i < 4; ++i) {
      int ch = i * 256 + tid;
      int r = ch >> 2, c8 = (ch & 3) * 8;
      gl2lds16(Ag + (size_t)r * 256 + k0 + c8, &As[ch * 8]);
    }
    {
      int r = tid >> 2, c8 = (tid & 3) * 8;
      gl2lds16(Bg + (size_t)r * 256 + k0 + c8, &Bs[tid * 8]);
    }
  };

  f32x4 acc[4][4];
  #pragma unroll
  for (int mi = 0; mi < 4; ++mi)
    #pragma unroll
    for (int ni = 0; ni < 4; ++ni)
      #pragma unroll
      for (int r = 0; r < 4; ++r) acc[mi][ni][r] = 0.f;

  stage(0, 0);
  for (int kt = 0; kt < 8; ++kt) {
    __syncthreads();
    if (kt < 7) stage((kt + 1) & 1, (kt + 1) * 32);
    const bf16* Ab = (const bf16*)(smem + (kt & 1) * 16384);
    const bf16* Bb = (const bf16*)(smem + 32768 + (kt & 1) * 4096);
    bf16x8 af[4], bfr[4];
    #pragma unroll
    for (int mi = 0; mi < 4; ++mi)
      af[mi] = *(const bf16x8*)&Ab[(w * 64 + mi * 16 + (lane & 15)) * 32 +
                                   (lane >> 4) * 8];
    #pragma unroll
    for (int ni = 0; ni < 4; ++ni)
      bfr[ni] = *(const bf16x8*)&Bb[(ni * 16 + (lane & 15)) * 32 +
                                    (lane >> 4) * 8];
    #pragma unroll
    for (int mi = 0; mi < 4; ++mi)
      #pragma unroll
      for (int ni = 0; ni < 4; ++ni)
        acc[mi][ni] = mfma16(af[mi], bfr[ni], acc[mi][ni]);
  }
  __syncthreads();   // all LDS frag reads done; As/Bs region reused as X

  // x = acc + optical; stash bf16 into X[l][c]; accumulate per-l sums
  const int cb = w * 64 + (lane >> 4) * 4;
  const int lb = lane & 15;
  float s[4], q[4];
  #pragma unroll
  for (int ni = 0; ni < 4; ++ni) { s[ni] = 0.f; q[ni] = 0.f; }
  #pragma unroll
  for (int mi = 0; mi < 4; ++mi)
    #pragma unroll
    for (int ni = 0; ni < 4; ++ni) {
      int c = cb + mi * 16, ll = lb + ni * 16;
      bf16x4 hx;
      #pragma unroll
      for (int r = 0; r < 4; ++r) {
        float v = acc[mi][ni][r] +
                  optical[((size_t)b * CCH + c + r) * LSP + l0 + ll];
        s[ni] += v; q[ni] += v * v;
        hx[r] = (bf16)v;
      }
      *(bf16x4*)&X[ll * 260 + c] = hx;
    }
  #pragma unroll
  for (int ni = 0; ni < 4; ++ni) {
    s[ni] += __shfl_xor(s[ni], 16);
    s[ni] += __shfl_xor(s[ni], 32);
    q[ni] += __shfl_xor(q[ni], 16);
    q[ni] += __shfl_xor(q[ni], 32);
  }
  if ((lane >> 4) == 0) {
    #pragma unroll
    for (int ni = 0; ni < 4; ++ni) {
      red[(0 * 4 + w) * 64 + ni * 16 + lb] = s[ni];
      red[(4 + w) * 64 + ni * 16 + lb] = q[ni];
    }
  }
  __syncthreads();
  if (tid < 64) {
    float S4 = red[0 * 64 + tid] + red[1 * 64 + tid] + red[2 * 64 + tid] +
               red[3 * 64 + tid];
    float Q4 = red[4 * 64 + tid] + red[5 * 64 + tid] + red[6 * 64 + tid] +
               red[7 * 64 + tid];
    float m = S4 * (1.f / 256.f);
    float rs = rsqrtf(Q4 * (1.f / 256.f) - m * m + 1e-5f);
    float* st = stats + ((size_t)b * LSP + l0 + tid) * 2;
    st[0] = m;
    st[1] = rs;
  }
  __syncthreads();
  // coalesced x write: [b][l][c] bf16
  #pragma unroll
  for (int it = 0; it < 8; ++it) {
    int cid = it * 256 + tid;            // 2048 chunks of 16B
    int l = cid >> 5, c0 = (cid & 31) * 8;
    bf16x8 v = *(const bf16x8*)&X[l * 260 + c0];
    *(bf16x8*)&xout[((size_t)b * LSP + l0 + l) * CCH + c0] = v;
  }
}

// ---------------------------------------------------------------------------
// 256x256-tile 8-phase GEMM (T2 swizzle + T3/T4 counted vmcnt + T5 setprio).
// MODE 0 (KEL=256): A = W1g interleaved, B = x bf16; epilogue applies the
//   folded LN affine (stats + cvec) then SimpleGate, bf16 [b][l][512].
// MODE 1 (KEL=512): A = W2 -> + b2 + res(bf16 x), f32 d_out [b][c][l].
// ---------------------------------------------------------------------------
template <int KEL, int MODE>
__global__ __launch_bounds__(512, 2) void ffn_gemm_kernel(
    const bf16* __restrict__ Aw, const bf16* __restrict__ Bx,
    void* __restrict__ outp, const bf16* __restrict__ resb,
    const float* __restrict__ bias, const float* __restrict__ stats) {
  constexpr int LDSB = (MODE == 1) ? 135168 : 131072;
  __shared__ __align__(16) char smem_raw[LDSB];
  const int tid = threadIdx.x;
  const int lane = tid & 63;
  const int wave = tid >> 6;
  const int wr = wave >> 2;        // 0..1  (m half: 128 rows)
  const int wc = wave & 3;         // 0..3  (n quarter: 64 cols)
  const int l0 = blockIdx.x * 256;
  const int m0 = blockIdx.y * 256;
  const int b  = blockIdx.z;

  char* ldsA0 = smem_raw;                  // A tile buf0: 256x64 bf16 = 32KB
  char* ldsB0 = smem_raw + 32768;
  char* ldsA1 = smem_raw + 65536;
  char* ldsB1 = smem_raw + 98304;

  const bf16* Ag = Aw + (size_t)m0 * KEL;
  const bf16* Bg = Bx + ((size_t)b * LSP + l0) * KEL;

  auto STAGE = [&](const bf16* gsrc, char* ldst, int par, int kt) {
    #pragma unroll
    for (int i = 0; i < 2; ++i) {
      int qi = i * 512 + tid;                       // 0..1023 chunk-in-half
      int r  = ((qi >> 7) << 5) + (par << 4) + ((qi >> 3) & 15);
      int cl = (qi & 7) ^ ((qi >> 3) & 7);          // pre-swizzled source col
      int p  = ((qi >> 7) << 8) + (par << 7) + (qi & 127);  // linear dest
      gl2lds16(gsrc + (size_t)r * KEL + kt * 64 + cl * 8,
               (bf16*)(ldst + p * 16));
    }
  };

  f32x4 acc[8][4];
  #pragma unroll
  for (int mi = 0; mi < 8; ++mi)
    #pragma unroll
    for (int ni = 0; ni < 4; ++ni)
      #pragma unroll
      for (int r = 0; r < 4; ++r) acc[mi][ni][r] = 0.f;

  bf16x8 af[4][2], bf[2][2];
  const int col0 = (((lane >> 4) << 4)) ^ ((lane & 7) << 4);
  const int col1 = col0 ^ 64;
  const int arow_off = (lane & 15) * 128;

#define LOAD_FRAGS(BUFA, BUFB, MP, NP)                                        \
  {                                                                           \
    const char* Ab_ = (BUFA);                                                 \
    const char* Bb_ = (BUFB);                                                 \
    _Pragma("unroll") for (int j = 0; j < 4; ++j) {                           \
      int rb = (wr * 128 + ((MP) + 2 * j) * 16) * 128 + arow_off;             \
      af[j][0] = *(const bf16x8*)(Ab_ + rb + col0);                           \
      af[j][1] = *(const bf16x8*)(Ab_ + rb + col1);                           \
    }                                                                         \
    _Pragma("unroll") for (int i = 0; i < 2; ++i) {                           \
      int rb = (wc * 64 + ((NP) + 2 * i) * 16) * 128 + arow_off;              \
      bf[i][0] = *(const bf16x8*)(Bb_ + rb + col0);                           \
      bf[i][1] = *(const bf16x8*)(Bb_ + rb + col1);                           \
    }                                                                         \
  }

#define DO_MFMA(MP, NP)                                                       \
  _Pragma("unroll") for (int j = 0; j < 4; ++j)                               \
  _Pragma("unroll") for (int i = 0; i < 2; ++i) {                             \
    acc[(MP) + 2 * j][(NP) + 2 * i] =                                         \
        mfma16(af[j][0], bf[i][0], acc[(MP) + 2 * j][(NP) + 2 * i]);          \
    acc[(MP) + 2 * j][(NP) + 2 * i] =                                         \
        mfma16(af[j][1], bf[i][1], acc[(MP) + 2 * j][(NP) + 2 * i]);          \
  }

#define PHASE(BUFA, BUFB, MP, NP, STG)                                        \
  asm volatile("s_waitcnt vmcnt(6)" ::: "memory");                            \
  __builtin_amdgcn_s_barrier();                                               \
  __builtin_amdgcn_sched_barrier(0);                                          \
  LOAD_FRAGS(BUFA, BUFB, MP, NP);                                             \
  STG;                                                                        \
  asm volatile("s_waitcnt lgkmcnt(0)" ::: "memory");                          \
  __builtin_amdgcn_sched_barrier(0);                                          \
  __builtin_amdgcn_s_setprio(1);                                              \
  DO_MFMA(MP, NP);                                                            \
  __builtin_amdgcn_s_setprio(0);

  STAGE(Ag, ldsA0, 0, 0);
  STAGE(Ag, ldsA0, 1, 0);
  STAGE(Bg, ldsB0, 0, 0);
  STAGE(Bg, ldsB0, 1, 0);
  STAGE(Ag, ldsA1, 0, 1);
  STAGE(Bg, ldsB1, 0, 1);

  constexpr int NITER = KEL / 128;
  for (int t = 0; t < NITER; ++t) {
    const int kt1 = 2 * t + 1;
    PHASE(ldsA0, ldsB0, 0, 0, STAGE(Ag, ldsA1, 1, kt1));      // ph1
    PHASE(ldsA0, ldsB0, 0, 1, STAGE(Bg, ldsB1, 1, kt1));      // ph2
    PHASE(ldsA0, ldsB0, 1, 0, STAGE(Ag, ldsA0, 0, kt1 + 1));  // ph3
    PHASE(ldsA0, ldsB0, 1, 1, STAGE(Bg, ldsB0, 0, kt1 + 1));  // ph4
    PHASE(ldsA1, ldsB1, 0, 0, STAGE(Ag, ldsA0, 1, kt1 + 1));  // ph5
    PHASE(ldsA1, ldsB1, 0, 1, STAGE(Bg, ldsB0, 1, kt1 + 1));  // ph6
    PHASE(ldsA1, ldsB1, 1, 0, STAGE(Ag, ldsA1, 0, kt1 + 2));  // ph7
    PHASE(ldsA1, ldsB1, 1, 1, STAGE(Bg, ldsB1, 0, kt1 + 2));  // ph8
  }
#undef PHASE
#undef DO_MFMA
#undef LOAD_FRAGS

  asm volatile("s_waitcnt vmcnt(0)" ::: "memory");
  __syncthreads();

  if constexpr (MODE == 0) {
    // folded-LN + SimpleGate epilogue
    bf16* g_lds = (bf16*)smem_raw;           // [256 l][136 pad] bf16 = 68KB
    const int lq = wc * 64 + (lane & 15);
    const int qq = (lane >> 4);
    const float* stb = stats + ((size_t)b * LSP + l0) * 2;
    float muv[4], rsv[4];
    #pragma unroll
    for (int ni = 0; ni < 4; ++ni) {
      int l = lq + ni * 16;
      muv[ni] = stb[l * 2];
      rsv[ni] = stb[l * 2 + 1];
    }
    #pragma unroll
    for (int mi = 0; mi < 8; ++mi) {
      int a0 = wr * 64 + mi * 8 + qq * 2;    // local gate row (0..127)
      int ag = (m0 >> 1) + a0;               // global gate row (0..511)
      float be1a = bias[ag],        ga1a = bias[512 + ag];
      float be2a = bias[1024 + ag], ga2a = bias[1536 + ag];
      float be1b = bias[ag + 1],        ga1b = bias[512 + ag + 1];
      float be2b = bias[1024 + ag + 1], ga2b = bias[1536 + ag + 1];
      #pragma unroll
      for (int ni = 0; ni < 4; ++ni) {
        int l = lq + ni * 16;
        float mrs = muv[ni] * rsv[ni];
        float h1a = rsv[ni] * acc[mi][ni][0] + be1a - mrs * ga1a;
        float h2a = rsv[ni] * acc[mi][ni][1] + be2a - mrs * ga2a;
        float h1b = rsv[ni] * acc[mi][ni][2] + be1b - mrs * ga1b;
        float h2b = rsv[ni] * acc[mi][ni][3] + be2b - mrs * ga2b;
        bf16 gv0 = (bf16)(h1a * h2a), gv1 = (bf16)(h1b * h2b);
        unsigned u = ((unsigned)*(unsigned short*)&gv1 << 16) |
                     (unsigned)*(unsigned short*)&gv0;
        *(unsigned*)&g_lds[l * 136 + a0] = u;
      }
    }
    __syncthreads();
    bf16* out = (bf16*)outp;
    const int gy = blockIdx.y * 128;
    #pragma unroll
    for (int it = 0; it < 8; ++it) {
      int cid = it * 512 + tid;              // 4096 chunks of 16B
      int l = cid >> 4, ch = cid & 15;
      bf16x8 v = *(const bf16x8*)&g_lds[l * 136 + ch * 8];
      *(bf16x8*)&out[((size_t)b * LSP + l0 + l) * 512 + gy + ch * 8] = v;
    }
  } else {
    float* lds_f = (float*)smem_raw;         // [128 c][260 pad] f32 = 133KB
    float* out = (float*)outp;
    const int lq = wc * 64 + (lane & 15);
    const int qq = (lane >> 4);
    #pragma unroll
    for (int round = 0; round < 2; ++round) {
      if (wr == round) {
        #pragma unroll
        for (int mi = 0; mi < 8; ++mi) {
          int c0 = mi * 16 + qq * 4;         // local c (0..127)
          f32x4 b4 = *(const f32x4*)&bias[round * 128 + c0];
          #pragma unroll
          for (int ni = 0; ni < 4; ++ni) {
            int l = lq + ni * 16;
            bf16x4 xr4 = *(const bf16x4*)&resb[((size_t)b * LSP + l0 + l) *
                                                   CCH + round * 128 + c0];
            #pragma unroll
            for (int r = 0; r < 4; ++r)
              lds_f[(c0 + r) * 260 + l] =
                  acc[mi][ni][r] + b4[r] + (float)xr4[r];
          }
        }
      }
      __syncthreads();
      #pragma unroll
      for (int it = 0; it < 16; ++it) {
        int cid = it * 512 + tid;            // 8192 chunks of 16B
        int c = cid >> 6, lch = cid & 63;
        f32x4 v = *(const f32x4*)&lds_f[c * 260 + lch * 4];
        *(f32x4*)&out[((size_t)b * CCH + round * 128 + c) * LSP + l0 +
                      lch * 4] = v;
      }
      __syncthreads();
    }
  }
}

// ---------------------------------------------------------------------------
extern "C" void kernel_launch(void* const* d_in, const int* in_sizes, int n_in,
                              void* d_out, int out_size, void* d_ws,
                              size_t ws_size, hipStream_t stream) {
  const float* optical = (const float*)d_in[0];
  const float* sar     = (const float*)d_in[1];
  const float* g_opt   = (const float*)d_in[2];
  const float* b_opt   = (const float*)d_in[3];
  const float* g_sar   = (const float*)d_in[4];
  const float* b_sar   = (const float*)d_in[5];
  const float* Wq      = (const float*)d_in[6];
  const float* Wk      = (const float*)d_in[7];
  const float* Wv      = (const float*)d_in[8];
  const float* Wo      = (const float*)d_in[9];
  const float* g_ffn   = (const float*)d_in[10];
  const float* b_ffn   = (const float*)d_in[11];
  const float* W1      = (const float*)d_in[12];
  const float* b1      = (const float*)d_in[13];
  const float* W2      = (const float*)d_in[14];
  const float* b2      = (const float*)d_in[15];

  char* ws = (char*)d_ws;
  bf16* wbf  = (bf16*)ws;
  bf16* Wqb  = wbf;
  bf16* Wkb  = wbf + 65536;
  bf16* WvTb = wbf + 131072;
  bf16* Wob  = wbf + 196608;
  bf16* W1b  = wbf + 262144;   // interleaved, pre-scaled by g_ffn
  bf16* W2b  = wbf + 524288;

  size_t off = 2ull * 1024 * 1024;
  const size_t T16 = 16ull * LSP * CCH * 2;  // 33.5 MB bf16 tensor
  bf16* opt_ncl = (bf16*)(ws + off); off += T16;
  bf16* sar_ncl = (bf16*)(ws + off); off += T16;
  bf16* sar_nlc = (bf16*)(ws + off); off += T16;
  bf16* xb      = (bf16*)(ws + off); off += T16;                   // x bf16
  float* stats  = (float*)(ws + off); off += 1ull * 1024 * 1024;   // 512KB+
  float* cvec   = (float*)(ws + off); off += 64 * 1024;            // 8KB
  float* Gpart  = (float*)(ws + off); off += 16ull * 1024 * 1024;  // 16 MB
  bf16* G2b     = (bf16*)(ws + off); off += 4ull * 1024 * 1024;
  bf16* UTb     = (bf16*)(ws + off); off += 2ull * 1024 * 1024;
  bf16* Wfoldb  = (bf16*)(ws + off); off += 2ull * 1024 * 1024;
  bf16* gbuf = opt_ncl;  // 67 MB overlay (opt_ncl+sar_ncl dead after gram)

  dim3 blk(256);
  cvt_w_kernel<<<2560, blk, 0, stream>>>(Wq, Wk, Wv, Wo, W1, W2, g_ffn, wbf);
  w1vec_kernel<<<4, blk, 0, stream>>>(W1, b1, g_ffn, b_ffn, cvec);
  ln_tile_kernel<0><<<dim3(64, 16), blk, 0, stream>>>(optical, g_opt, b_opt,
                                                      opt_ncl, nullptr);
  ln_tile_kernel<1><<<dim3(64, 16), blk, 0, stream>>>(sar, g_sar, b_sar,
                                                      sar_ncl, sar_nlc);
  gram_kernel<<<dim3(4, 4, 16), blk, 0, stream>>>(sar_ncl, opt_ncl, Gpart);
  greduce_kernel<<<512, blk, 0, stream>>>(Gpart, G2b);
  fold2_kernel<<<128, blk, 0, stream>>>(G2b, Wqb, Wkb, WvTb, UTb);
  wfold_kernel<<<dim3(2, 2, 16), blk, 0, stream>>>(Wob, UTb, Wfoldb);
  xgemm_stats_kernel<<<dim3(64, 16), blk, 0, stream>>>(Wfoldb, sar_nlc,
                                                       optical, xb, stats);
  ffn_gemm_kernel<256, 0><<<dim3(16, 4, 16), dim3(512), 0, stream>>>(
      W1b, xb, gbuf, nullptr, cvec, stats);
  ffn_gemm_kernel<512, 1><<<dim3(16, 1, 16), dim3(512), 0, stream>>>(
      W2b, gbuf, (float*)d_out, xb, b2, nullptr);
}

// Round 8
// 254.990 us; speedup vs baseline: 1.5759x; 1.0180x over previous
//
#include <hip/hip_runtime.h>
#include <hip/hip_bf16.h>

typedef __bf16 bf16;
typedef __attribute__((ext_vector_type(8))) __bf16 bf16x8;
typedef __attribute__((ext_vector_type(4))) __bf16 bf16x4;
typedef __attribute__((ext_vector_type(4))) float f32x4;
typedef __attribute__((ext_vector_type(16))) float f32x16;

#define LSP 4096   // H*W
#define CCH 256

__device__ __forceinline__ void gl2lds16(const bf16* g, bf16* l) {
  __builtin_amdgcn_global_load_lds(
      (const __attribute__((address_space(1))) unsigned int*)g,
      (__attribute__((address_space(3))) unsigned int*)l, 16, 0, 0);
}

__device__ __forceinline__ f32x4 mfma16(bf16x8 a, bf16x8 b, f32x4 c) {
  return __builtin_amdgcn_mfma_f32_16x16x32_bf16(a, b, c, 0, 0, 0);
}
__device__ __forceinline__ f32x16 mfma32(bf16x8 a, bf16x8 b, f32x16 c) {
  return __builtin_amdgcn_mfma_f32_32x32x16_bf16(a, b, c, 0, 0, 0);
}

// ---------------------------------------------------------------------------
// Weight f32 -> bf16. Wq,Wk direct; Wv TRANSPOSED (WvT[cin][och]); Wo direct;
// W1 INTERLEAVED and PRE-SCALED by g_ffn (row 2a = W1g[a], 2a+1 = W1g[a+512]);
// W2 direct.
// ---------------------------------------------------------------------------
__global__ __launch_bounds__(256) void cvt_w_kernel(
    const float* __restrict__ wq, const float* __restrict__ wk,
    const float* __restrict__ wv, const float* __restrict__ wo,
    const float* __restrict__ w1, const float* __restrict__ w2,
    const float* __restrict__ gff, bf16* __restrict__ out) {
  int e = blockIdx.x * 256 + threadIdx.x;   // grid 2560 -> 655360 exact
  if (e < 65536)        { out[e] = (bf16)wq[e]; }
  else if (e < 131072)  { out[e] = (bf16)wk[e - 65536]; }
  else if (e < 196608)  {
    int e2 = e - 131072;            // e2 = och*256 + cin
    int och = e2 >> 8, cin = e2 & 255;
    out[131072 + cin * 256 + och] = (bf16)wv[e2];   // WvT
  }
  else if (e < 262144)  { out[e] = (bf16)wo[e - 196608]; }
  else if (e < 524288)  {
    int e2 = e - 262144;            // m*256 + k, m in [0,1024)
    int m = e2 >> 8, k = e2 & 255;
    int mp = (m < 512) ? (2 * m) : (2 * (m - 512) + 1);
    out[262144 + mp * 256 + k] = (bf16)(w1[e2] * gff[k]);  // W1g interleaved
  }
  else                  { out[e] = (bf16)w2[e - 524288]; }
}

// ---------------------------------------------------------------------------
// Per-m FFN1 constants: cvec[0..511]=W1[m]@b_ffn+b1[m], [512..1023]=W1[m]@g_ffn,
// [1024..1535] / [1536..2047] = same for m+512. grid 4 x 256.
// ---------------------------------------------------------------------------
__global__ __launch_bounds__(256) void w1vec_kernel(
    const float* __restrict__ w1, const float* __restrict__ b1,
    const float* __restrict__ gff, const float* __restrict__ bff,
    float* __restrict__ cvec) {
  int m = blockIdx.x * 256 + threadIdx.x;   // 0..1023
  const float* row = w1 + (size_t)m * 256;
  float sb = 0.f, sg = 0.f;
  #pragma unroll 8
  for (int c = 0; c < 256; c += 4) {
    f32x4 w = *(const f32x4*)&row[c];
    f32x4 g = *(const f32x4*)&gff[c];
    f32x4 bb = *(const f32x4*)&bff[c];
    #pragma unroll
    for (int j = 0; j < 4; ++j) { sb += w[j] * bb[j]; sg += w[j] * g[j]; }
  }
  if (m < 512) {
    cvec[m] = sb + b1[m];
    cvec[512 + m] = sg;
  } else {
    cvec[512 + m] = sb + b1[m];       // 1024 + (m-512)
    cvec[1024 + m] = sg;              // 1536 + (m-512)
  }
}

// ---------------------------------------------------------------------------
// Tiled LayerNorm over channels. Input f32 [b][c][l]. Tile = 256c x 64l.
// ---------------------------------------------------------------------------
template <int DUAL>
__global__ __launch_bounds__(256) void ln_tile_kernel(
    const float* __restrict__ x, const float* __restrict__ gam,
    const float* __restrict__ bet, bf16* __restrict__ out_cl,
    bf16* __restrict__ out_lc) {
  const int l0 = blockIdx.x * 64;
  const int b  = blockIdx.y;
  const int tid = threadIdx.x;
  __shared__ bf16 Tt[256 * 64];          // 32 KB, swizzled
  __shared__ float red[2][16][64];       // 8 KB
  __shared__ float mu_s[64], rs_s[64];

  const float* px = x + (size_t)b * CCH * LSP + l0;
  const int colq = (tid & 15) * 4;
  f32x4 s = {0.f, 0.f, 0.f, 0.f}, q = {0.f, 0.f, 0.f, 0.f};
  #pragma unroll
  for (int it = 0; it < 16; ++it) {
    int c = it * 16 + (tid >> 4);
    f32x4 v = *(const f32x4*)&px[(size_t)c * LSP + colq];
    s += v;
    q += v * v;
    bf16x4 h;
    #pragma unroll
    for (int j = 0; j < 4; ++j) h[j] = (bf16)v[j];
    int colp = colq ^ (((c >> 3) & 7) << 3);
    *(bf16x4*)&Tt[c * 64 + colp] = h;
  }
  #pragma unroll
  for (int j = 0; j < 4; ++j) {
    red[0][tid >> 4][colq + j] = s[j];
    red[1][tid >> 4][colq + j] = q[j];
  }
  __syncthreads();
  if (tid < 64) {
    float S = 0.f, Q = 0.f;
    #pragma unroll
    for (int k = 0; k < 16; ++k) { S += red[0][k][tid]; Q += red[1][k][tid]; }
    float m = S * (1.f / 256.f);
    mu_s[tid] = m;
    rs_s[tid] = rsqrtf(Q * (1.f / 256.f) - m * m + 1e-5f);
  }
  __syncthreads();

  #pragma unroll
  for (int it = 0; it < 8; ++it) {
    int ch = it * 256 + tid;
    int c = ch >> 3, col8 = (ch & 7) * 8;
    int colp = col8 ^ (((c >> 3) & 7) << 3);
    bf16x8 h = *(const bf16x8*)&Tt[c * 64 + colp];
    f32x4 m0 = *(const f32x4*)&mu_s[col8];
    f32x4 m1 = *(const f32x4*)&mu_s[col8 + 4];
    f32x4 r0 = *(const f32x4*)&rs_s[col8];
    f32x4 r1 = *(const f32x4*)&rs_s[col8 + 4];
    float g = gam[c], be = bet[c];
    bf16x8 o;
    #pragma unroll
    for (int j = 0; j < 4; ++j) {
      o[j]     = (bf16)(((float)h[j] - m0[j]) * r0[j] * g + be);
      o[4 + j] = (bf16)(((float)h[4 + j] - m1[j]) * r1[j] * g + be);
    }
    *(bf16x8*)&out_cl[((size_t)b * CCH + c) * LSP + l0 + col8] = o;
  }

  if constexpr (DUAL) {
    #pragma unroll
    for (int it = 0; it < 8; ++it) {
      int ch = it * 256 + tid;
      int l = ch >> 5, cch = ch & 31;
      int c0 = cch * 8;
      int lp = l ^ ((cch & 7) << 3);
      float mu = mu_s[l], rs = rs_s[l];
      f32x4 g0 = *(const f32x4*)&gam[c0];
      f32x4 g1 = *(const f32x4*)&gam[c0 + 4];
      f32x4 b0 = *(const f32x4*)&bet[c0];
      f32x4 b1 = *(const f32x4*)&bet[c0 + 4];
      bf16x8 o;
      #pragma unroll
      for (int j = 0; j < 4; ++j) {
        float h0 = (float)Tt[(c0 + j) * 64 + lp];
        float h1 = (float)Tt[(c0 + 4 + j) * 64 + lp];
        o[j]     = (bf16)((h0 - mu) * rs * g0[j] + b0[j]);
        o[4 + j] = (bf16)((h1 - mu) * rs * g1[j] + b1[j]);
      }
      *(bf16x8*)&out_lc[((size_t)b * LSP + l0 + l) * CCH + c0] = o;
    }
  }
}

// ---------------------------------------------------------------------------
// Gram: G2part[chunk][b][j][i] = sum_{l in chunk} sar_cl[b][j][l]*opt_cl[b][i][l]
// ---------------------------------------------------------------------------
__global__ __launch_bounds__(256) void gram_kernel(
    const bf16* __restrict__ sar_cl, const bf16* __restrict__ opt_cl,
    float* __restrict__ part) {
  const int tile = blockIdx.x, chunk = blockIdx.y, b = blockIdx.z;
  const int tid = threadIdx.x, lane = tid & 63, w = tid >> 6;
  const int j0 = (tile >> 1) * 128 + (w >> 1) * 64;
  const int i0 = (tile & 1) * 128 + (w & 1) * 64;
  const int l0 = chunk * 1024;
  const bf16* sj = sar_cl + ((size_t)b * CCH + j0 + (lane & 31)) * LSP + l0;
  const bf16* oi = opt_cl + ((size_t)b * CCH + i0 + (lane & 31)) * LSP + l0;
  f32x16 acc[2][2];
  #pragma unroll
  for (int mt = 0; mt < 2; ++mt)
    #pragma unroll
    for (int nt = 0; nt < 2; ++nt)
      #pragma unroll
      for (int r = 0; r < 16; ++r) acc[mt][nt][r] = 0.f;
  #pragma unroll 4
  for (int ks = 0; ks < 64; ++ks) {
    int lofs = ks * 16 + (lane >> 5) * 8;
    bf16x8 a0 = *(const bf16x8*)&sj[lofs];
    bf16x8 a1 = *(const bf16x8*)&sj[32 * LSP + lofs];
    bf16x8 b0 = *(const bf16x8*)&oi[lofs];
    bf16x8 b1 = *(const bf16x8*)&oi[32 * LSP + lofs];
    acc[0][0] = mfma32(a0, b0, acc[0][0]);
    acc[0][1] = mfma32(a0, b1, acc[0][1]);
    acc[1][0] = mfma32(a1, b0, acc[1][0]);
    acc[1][1] = mfma32(a1, b1, acc[1][1]);
  }
  float* op = part + ((size_t)chunk * 16 + b) * 65536;
  #pragma unroll
  for (int mt = 0; mt < 2; ++mt)
    #pragma unroll
    for (int nt = 0; nt < 2; ++nt)
      #pragma unroll
      for (int r = 0; r < 16; ++r) {
        int row = j0 + mt * 32 + (r & 3) + 8 * (r >> 2) + 4 * (lane >> 5);
        int col = i0 + nt * 32 + (lane & 31);
        op[(size_t)row * 256 + col] = acc[mt][nt][r];
      }
}

// ---------------------------------------------------------------------------
// Reduce Gram partials (4 chunks) -> G2 bf16 [b][j][i]
// ---------------------------------------------------------------------------
__global__ __launch_bounds__(256) void greduce_kernel(
    const float* __restrict__ part, bf16* __restrict__ G2) {
  size_t e = ((size_t)blockIdx.x * 256 + threadIdx.x) * 8;  // grid 512
  float a[8];
  #pragma unroll
  for (int i = 0; i < 8; ++i) a[i] = 0.f;
  #pragma unroll
  for (int ch = 0; ch < 4; ++ch) {
    f32x4 p0 = *(const f32x4*)&part[ch * 1048576ull + e];
    f32x4 p1 = *(const f32x4*)&part[ch * 1048576ull + e + 4];
    #pragma unroll
    for (int i = 0; i < 4; ++i) { a[i] += p0[i]; a[4 + i] += p1[i]; }
  }
  bf16x8 o;
  #pragma unroll
  for (int i = 0; i < 8; ++i) o[i] = (bf16)a[i];
  *(bf16x8*)&G2[e] = o;
}

// ---------------------------------------------------------------------------
// Fold: per (b,h): M1[c][j] = sum_i Wq_h[c][i]*G2[j][i],
// S[c][d] = sum_j M1[c][j]*Wk_h[d][j], softmax rows -> P,
// UT[b][cin][h*32+c] = sum_d WvT[cin][h*32+d]*P[c][d].
// ---------------------------------------------------------------------------
__global__ __launch_bounds__(256) void fold2_kernel(
    const bf16* __restrict__ G2, const bf16* __restrict__ Wq,
    const bf16* __restrict__ Wk, const bf16* __restrict__ WvT,
    bf16* __restrict__ UT) {
  const int bh = blockIdx.x;
  const int b = bh >> 3, h = bh & 7;
  const int tid = threadIdx.x, lane = tid & 63, w = tid >> 6;
  __shared__ bf16 M1[32 * 256];
  __shared__ float Sp[4][1024];
  __shared__ float S[1024];
  __shared__ bf16 P[1024];

  const bf16* gq = Wq + (size_t)(h * 32) * 256;
  const bf16* g2b = G2 + (size_t)b * 65536;
  #pragma unroll
  for (int mt = 0; mt < 2; ++mt)
    #pragma unroll
    for (int nt = 0; nt < 4; ++nt) {
      f32x4 acc = {0.f, 0.f, 0.f, 0.f};
      #pragma unroll
      for (int ks = 0; ks < 8; ++ks) {
        bf16x8 a = *(const bf16x8*)&gq[(size_t)(mt * 16 + (lane & 15)) * 256 +
                                       ks * 32 + (lane >> 4) * 8];
        bf16x8 bb = *(const bf16x8*)&g2b[
            (size_t)(w * 64 + nt * 16 + (lane & 15)) * 256 + ks * 32 +
            (lane >> 4) * 8];
        acc = mfma16(a, bb, acc);
      }
      #pragma unroll
      for (int r = 0; r < 4; ++r)
        M1[(mt * 16 + (lane >> 4) * 4 + r) * 256 + w * 64 + nt * 16 +
           (lane & 15)] = (bf16)acc[r];
    }
  __syncthreads();

  const bf16* gk = Wk + (size_t)(h * 32) * 256;
  #pragma unroll
  for (int mt = 0; mt < 2; ++mt)
    #pragma unroll
    for (int dt = 0; dt < 2; ++dt) {
      f32x4 acc = {0.f, 0.f, 0.f, 0.f};
      #pragma unroll
      for (int kk = 0; kk < 2; ++kk) {
        bf16x8 a = *(const bf16x8*)&M1[(mt * 16 + (lane & 15)) * 256 + w * 64 +
                                       kk * 32 + (lane >> 4) * 8];
        bf16x8 bb = *(const bf16x8*)&gk[(size_t)(dt * 16 + (lane & 15)) * 256 +
                                        w * 64 + kk * 32 + (lane >> 4) * 8];
        acc = mfma16(a, bb, acc);
      }
      #pragma unroll
      for (int r = 0; r < 4; ++r)
        Sp[w][(mt * 16 + (lane >> 4) * 4 + r) * 32 + dt * 16 + (lane & 15)] =
            acc[r];
    }
  __syncthreads();
  #pragma unroll
  for (int i = 0; i < 4; ++i) {
    int e = tid + 256 * i;
    S[e] = (Sp[0][e] + Sp[1][e] + Sp[2][e] + Sp[3][e]) * 0.17677669529663687f;
  }
  __syncthreads();
  if (tid < 32) {
    float m = -1e30f;
    #pragma unroll
    for (int d = 0; d < 32; ++d) m = fmaxf(m, S[tid * 32 + d]);
    float sum = 0.f;
    float ex[32];
    #pragma unroll
    for (int d = 0; d < 32; ++d) {
      ex[d] = __expf(S[tid * 32 + d] - m);
      sum += ex[d];
    }
    float inv = 1.f / sum;
    #pragma unroll
    for (int d = 0; d < 32; ++d) P[tid * 32 + d] = (bf16)(ex[d] * inv);
  }
  __syncthreads();

  bf16x8 bfrag[2];
  #pragma unroll
  for (int ct = 0; ct < 2; ++ct)
    bfrag[ct] =
        *(const bf16x8*)&P[(ct * 16 + (lane & 15)) * 32 + (lane >> 4) * 8];
  bf16* outb = UT + (size_t)b * 65536 + h * 32;
  #pragma unroll
  for (int t = 0; t < 4; ++t) {
    int cin16 = w * 64 + t * 16;
    bf16x8 afrag = *(const bf16x8*)&WvT[(size_t)(cin16 + (lane & 15)) * 256 +
                                        h * 32 + (lane >> 4) * 8];
    #pragma unroll
    for (int ct = 0; ct < 2; ++ct) {
      f32x4 acc = {0.f, 0.f, 0.f, 0.f};
      acc = mfma16(afrag, bfrag[ct], acc);
      int c = ct * 16 + (lane & 15);
      int cinr = cin16 + (lane >> 4) * 4;
      #pragma unroll
      for (int r = 0; r < 4; ++r)
        outb[(size_t)(cinr + r) * 256 + c] = (bf16)acc[r];
    }
  }
}

// ---------------------------------------------------------------------------
// Small GEMM for Wfold: out bf16 [b][256][256] = Wo @ UT   (128x128 tiles)
// ---------------------------------------------------------------------------
__global__ __launch_bounds__(256) void wfold_kernel(
    const bf16* __restrict__ Aw, const bf16* __restrict__ Bx,
    bf16* __restrict__ outp) {
  const int tid = threadIdx.x;
  const int lane = tid & 63;
  const int wave = tid >> 6;
  const int wr = wave >> 1, wc = wave & 1;
  const int l0 = blockIdx.x * 128;
  const int m0 = blockIdx.y * 128;
  const int b  = blockIdx.z;
  constexpr int NB = 4096;
  __shared__ bf16 smem[4 * NB];
  bf16* As = smem;
  bf16* Bs = smem + 2 * NB;
  const bf16* Ag = Aw + (size_t)m0 * 256;
  const bf16* Bg = Bx + ((size_t)b * 256 + l0) * 256;
  auto stage = [&](int buf, int k0) {
    #pragma unroll
    for (int i = 0; i < 2; ++i) {
      int ch = i * 256 + tid;
      int r  = ch >> 2;
      int c8 = (ch & 3) * 8;
      gl2lds16(Ag + (size_t)r * 256 + k0 + c8, As + buf * NB + ch * 8);
      gl2lds16(Bg + (size_t)r * 256 + k0 + c8, Bs + buf * NB + ch * 8);
    }
  };
  f32x4 acc[4][4];
  #pragma unroll
  for (int mi = 0; mi < 4; ++mi)
    #pragma unroll
    for (int ni = 0; ni < 4; ++ni)
      #pragma unroll
      for (int r = 0; r < 4; ++r) acc[mi][ni][r] = 0.f;
  stage(0, 0);
  for (int kt = 0; kt < 8; ++kt) {
    __syncthreads();
    if (kt + 1 < 8) stage((kt + 1) & 1, (kt + 1) * 32);
    const bf16* Ab = As + (kt & 1) * NB;
    const bf16* Bb = Bs + (kt & 1) * NB;
    bf16x8 af[4], bfr[4];
    #pragma unroll
    for (int mi = 0; mi < 4; ++mi)
      af[mi] = *(const bf16x8*)&Ab[(wr * 64 + mi * 16 + (lane & 15)) * 32 +
                                   (lane >> 4) * 8];
    #pragma unroll
    for (int ni = 0; ni < 4; ++ni)
      bfr[ni] = *(const bf16x8*)&Bb[(wc * 64 + ni * 16 + (lane & 15)) * 32 +
                                    (lane >> 4) * 8];
    #pragma unroll
    for (int mi = 0; mi < 4; ++mi)
      #pragma unroll
      for (int ni = 0; ni < 4; ++ni)
        acc[mi][ni] = mfma16(af[mi], bfr[ni], acc[mi][ni]);
  }
  const int mq = m0 + wr * 64 + (lane >> 4) * 4;
  const int lq = l0 + wc * 64 + (lane & 15);
  #pragma unroll
  for (int mi = 0; mi < 4; ++mi)
    #pragma unroll
    for (int ni = 0; ni < 4; ++ni) {
      int l = lq + ni * 16, mb = mq + mi * 16;
      #pragma unroll
      for (int r = 0; r < 4; ++r)
        outp[((size_t)b * 256 + mb + r) * 256 + l] = (bf16)acc[mi][ni][r];
    }
}

// ---------------------------------------------------------------------------
// Fused x-GEMM + residual + LN-stats (M=256, N=64, K=256).
// ---------------------------------------------------------------------------
__global__ __launch_bounds__(256) void xgemm_stats_kernel(
    const bf16* __restrict__ Wfold, const bf16* __restrict__ sar_lc,
    const float* __restrict__ optical, bf16* __restrict__ xout,
    float* __restrict__ stats) {
  const int tid = threadIdx.x, lane = tid & 63, w = tid >> 6;
  const int l0 = blockIdx.x * 64;
  const int b  = blockIdx.y;
  __shared__ __align__(16) char smem[43520];
  bf16* X = (bf16*)smem;
  float* red = (float*)(smem + 40960);

  const bf16* Ag = Wfold + (size_t)b * 65536;
  const bf16* Bg = sar_lc + ((size_t)b * LSP + l0) * CCH;

  auto stage = [&](int buf, int k0) {
    bf16* As = (bf16*)(smem + buf * 16384);
    bf16* Bs = (bf16*)(smem + 32768 + buf * 4096);
    #pragma unroll
    for (int i = 0; i < 4; ++i) {
      int ch = i * 256 + tid;
      int r = ch >> 2, c8 = (ch & 3) * 8;
      gl2lds16(Ag + (size_t)r * 256 + k0 + c8, &As[ch * 8]);
    }
    {
      int r = tid >> 2, c8 = (tid & 3) * 8;
      gl2lds16(Bg + (size_t)r * 256 + k0 + c8, &Bs[tid * 8]);
    }
  };

  f32x4 acc[4][4];
  #pragma unroll
  for (int mi = 0; mi < 4; ++mi)
    #pragma unroll
    for (int ni = 0; ni < 4; ++ni)
      #pragma unroll
      for (int r = 0; r < 4; ++r) acc[mi][ni][r] = 0.f;

  stage(0, 0);
  for (int kt = 0; kt < 8; ++kt) {
    __syncthreads();
    if (kt < 7) stage((kt + 1) & 1, (kt + 1) * 32);
    const bf16* Ab = (const bf16*)(smem + (kt & 1) * 16384);
    const bf16* Bb = (const bf16*)(smem + 32768 + (kt & 1) * 4096);
    bf16x8 af[4], bfr[4];
    #pragma unroll
    for (int mi = 0; mi < 4; ++mi)
      af[mi] = *(const bf16x8*)&Ab[(w * 64 + mi * 16 + (lane & 15)) * 32 +
                                   (lane >> 4) * 8];
    #pragma unroll
    for (int ni = 0; ni < 4; ++ni)
      bfr[ni] = *(const bf16x8*)&Bb[(ni * 16 + (lane & 15)) * 32 +
                                    (lane >> 4) * 8];
    #pragma unroll
    for (int mi = 0; mi < 4; ++mi)
      #pragma unroll
      for (int ni = 0; ni < 4; ++ni)
        acc[mi][ni] = mfma16(af[mi], bfr[ni], acc[mi][ni]);
  }
  __syncthreads();   // all LDS frag reads done; As/Bs region reused as X

  const int cb = w * 64 + (lane >> 4) * 4;
  const int lb = lane & 15;
  float s[4], q[4];
  #pragma unroll
  for (int ni = 0; ni < 4; ++ni) { s[ni] = 0.f; q[ni] = 0.f; }
  #pragma unroll
  for (int mi = 0; mi < 4; ++mi)
    #pragma unroll
    for (int ni = 0; ni < 4; ++ni) {
      int c = cb + mi * 16, ll = lb + ni * 16;
      bf16x4 hx;
      #pragma unroll
      for (int r = 0; r < 4; ++r) {
        float v = acc[mi][ni][r] +
                  optical[((size_t)b * CCH + c + r) * LSP + l0 + ll];
        s[ni] += v; q[ni] += v * v;
        hx[r] = (bf16)v;
      }
      *(bf16x4*)&X[ll * 260 + c] = hx;
    }
  #pragma unroll
  for (int ni = 0; ni < 4; ++ni) {
    s[ni] += __shfl_xor(s[ni], 16);
    s[ni] += __shfl_xor(s[ni], 32);
    q[ni] += __shfl_xor(q[ni], 16);
    q[ni] += __shfl_xor(q[ni], 32);
  }
  if ((lane >> 4) == 0) {
    #pragma unroll
    for (int ni = 0; ni < 4; ++ni) {
      red[(0 * 4 + w) * 64 + ni * 16 + lb] = s[ni];
      red[(4 + w) * 64 + ni * 16 + lb] = q[ni];
    }
  }
  __syncthreads();
  if (tid < 64) {
    float S4 = red[0 * 64 + tid] + red[1 * 64 + tid] + red[2 * 64 + tid] +
               red[3 * 64 + tid];
    float Q4 = red[4 * 64 + tid] + red[5 * 64 + tid] + red[6 * 64 + tid] +
               red[7 * 64 + tid];
    float m = S4 * (1.f / 256.f);
    float rs = rsqrtf(Q4 * (1.f / 256.f) - m * m + 1e-5f);
    float* st = stats + ((size_t)b * LSP + l0 + tid) * 2;
    st[0] = m;
    st[1] = rs;
  }
  __syncthreads();
  #pragma unroll
  for (int it = 0; it < 8; ++it) {
    int cid = it * 256 + tid;            // 2048 chunks of 16B
    int l = cid >> 5, c0 = (cid & 31) * 8;
    bf16x8 v = *(const bf16x8*)&X[l * 260 + c0];
    *(bf16x8*)&xout[((size_t)b * LSP + l0 + l) * CCH + c0] = v;
  }
}

// ---------------------------------------------------------------------------
// 256x256-tile 8-phase GEMM, gray-code quadrant order (0,0)->(0,1)->(1,1)->
// (1,0) with B register-cached per buffer: per-iter ds_reads 96 -> 48.
// Stage ring (re-derived ledger, vmcnt(6), loads/phase {4,0,2,2,2,2,2,2}):
//   ph1: B1p0(2t+1) then A1p1(2t+1); ph3: A0p0'; ph4: B0p1'; ph5: B0p0';
//   ph6: A0p1'; ph7: A1p0''; ph8: B1p1''.  kt clamped in final iter (stages
//   overwrite only free slots; keeps vmcnt counts uniform).
// MODE 0 (KEL=256): A = W1g interleaved -> folded-LN + SimpleGate, bf16
//   [b][l][512]. MODE 1 (KEL=512): A = W2 -> + b2 + res(bf16 x), f32 d_out.
// ---------------------------------------------------------------------------
template <int KEL, int MODE>
__global__ __launch_bounds__(512, 2) void ffn_gemm_kernel(
    const bf16* __restrict__ Aw, const bf16* __restrict__ Bx,
    void* __restrict__ outp, const bf16* __restrict__ resb,
    const float* __restrict__ bias, const float* __restrict__ stats) {
  constexpr int LDSB = (MODE == 1) ? 135168 : 131072;
  __shared__ __align__(16) char smem_raw[LDSB];
  const int tid = threadIdx.x;
  const int lane = tid & 63;
  const int wave = tid >> 6;
  const int wr = wave >> 2;        // 0..1  (m half: 128 rows)
  const int wc = wave & 3;         // 0..3  (n quarter: 64 cols)
  const int l0 = blockIdx.x * 256;
  const int m0 = blockIdx.y * 256;
  const int b  = blockIdx.z;

  char* ldsA0 = smem_raw;                  // A tile buf0: 256x64 bf16 = 32KB
  char* ldsB0 = smem_raw + 32768;
  char* ldsA1 = smem_raw + 65536;
  char* ldsB1 = smem_raw + 98304;

  const bf16* Ag = Aw + (size_t)m0 * KEL;
  const bf16* Bg = Bx + ((size_t)b * LSP + l0) * KEL;

  auto STAGE = [&](const bf16* gsrc, char* ldst, int par, int kt) {
    #pragma unroll
    for (int i = 0; i < 2; ++i) {
      int qi = i * 512 + tid;                       // 0..1023 chunk-in-half
      int r  = ((qi >> 7) << 5) + (par << 4) + ((qi >> 3) & 15);
      int cl = (qi & 7) ^ ((qi >> 3) & 7);          // pre-swizzled source col
      int p  = ((qi >> 7) << 8) + (par << 7) + (qi & 127);  // linear dest
      gl2lds16(gsrc + (size_t)r * KEL + kt * 64 + cl * 8,
               (bf16*)(ldst + p * 16));
    }
  };

  f32x4 acc[8][4];
  #pragma unroll
  for (int mi = 0; mi < 8; ++mi)
    #pragma unroll
    for (int ni = 0; ni < 4; ++ni)
      #pragma unroll
      for (int r = 0; r < 4; ++r) acc[mi][ni][r] = 0.f;

  bf16x8 af[4][2], bn0[2][2], bn1[2][2];
  const int col0 = (((lane >> 4) << 4)) ^ ((lane & 7) << 4);
  const int col1 = col0 ^ 64;
  const int arow_off = (lane & 15) * 128;

#define LOAD_A(BUFA, MP)                                                      \
  {                                                                           \
    const char* Ab_ = (BUFA);                                                 \
    _Pragma("unroll") for (int j = 0; j < 4; ++j) {                           \
      int rb = (wr * 128 + ((MP) + 2 * j) * 16) * 128 + arow_off;             \
      af[j][0] = *(const bf16x8*)(Ab_ + rb + col0);                           \
      af[j][1] = *(const bf16x8*)(Ab_ + rb + col1);                           \
    }                                                                         \
  }

#define LOAD_B(BUFB, NP, DST)                                                 \
  {                                                                           \
    const char* Bb_ = (BUFB);                                                 \
    _Pragma("unroll") for (int i = 0; i < 2; ++i) {                           \
      int rb = (wc * 64 + ((NP) + 2 * i) * 16) * 128 + arow_off;              \
      DST[i][0] = *(const bf16x8*)(Bb_ + rb + col0);                          \
      DST[i][1] = *(const bf16x8*)(Bb_ + rb + col1);                          \
    }                                                                         \
  }

#define DO_MFMA(MP, NP, BS)                                                   \
  _Pragma("unroll") for (int j = 0; j < 4; ++j)                               \
  _Pragma("unroll") for (int i = 0; i < 2; ++i) {                             \
    acc[(MP) + 2 * j][(NP) + 2 * i] =                                         \
        mfma16(af[j][0], BS[i][0], acc[(MP) + 2 * j][(NP) + 2 * i]);          \
    acc[(MP) + 2 * j][(NP) + 2 * i] =                                         \
        mfma16(af[j][1], BS[i][1], acc[(MP) + 2 * j][(NP) + 2 * i]);          \
  }

#define PH_HEAD                                                               \
  asm volatile("s_waitcnt vmcnt(6)" ::: "memory");                            \
  __builtin_amdgcn_s_barrier();                                               \
  __builtin_amdgcn_sched_barrier(0);

#define PH_TAIL(MP, NP, BS)                                                   \
  asm volatile("s_waitcnt lgkmcnt(0)" ::: "memory");                          \
  __builtin_amdgcn_sched_barrier(0);                                         \
  __builtin_amdgcn_s_setprio(1);                                              \
  DO_MFMA(MP, NP, BS);                                                        \
  __builtin_amdgcn_s_setprio(0);

  // Prologue: A0p0,B0p0 first (ph1 deps), then B0p1, A0p1, A1p0, B1p1.
  STAGE(Ag, ldsA0, 0, 0);
  STAGE(Bg, ldsB0, 0, 0);
  STAGE(Bg, ldsB0, 1, 0);
  STAGE(Ag, ldsA0, 1, 0);
  STAGE(Ag, ldsA1, 0, 1);
  STAGE(Bg, ldsB1, 1, 1);

  constexpr int NITER = KEL / 128;
  constexpr int KMAX = KEL / 64 - 1;
  for (int t = 0; t < NITER; ++t) {
    const int k1 = 2 * t + 1;
    const int k2 = (2 * t + 2 > KMAX) ? KMAX : 2 * t + 2;
    const int k3 = (2 * t + 3 > KMAX) ? KMAX : 2 * t + 3;
    // ph1 (0,0) buf0
    PH_HEAD; LOAD_A(ldsA0, 0); LOAD_B(ldsB0, 0, bn0);
    STAGE(Bg, ldsB1, 0, k1); STAGE(Ag, ldsA1, 1, k1);
    PH_TAIL(0, 0, bn0);
    // ph2 (0,1)
    PH_HEAD; LOAD_B(ldsB0, 1, bn1);
    PH_TAIL(0, 1, bn1);
    // ph3 (1,1)
    PH_HEAD; LOAD_A(ldsA0, 1); STAGE(Ag, ldsA0, 0, k2);
    PH_TAIL(1, 1, bn1);
    // ph4 (1,0)
    PH_HEAD; STAGE(Bg, ldsB0, 1, k2);
    PH_TAIL(1, 0, bn0);
    // ph5 (0,0) buf1
    PH_HEAD; LOAD_A(ldsA1, 0); LOAD_B(ldsB1, 0, bn0);
    STAGE(Bg, ldsB0, 0, k2);
    PH_TAIL(0, 0, bn0);
    // ph6 (0,1)
    PH_HEAD; LOAD_B(ldsB1, 1, bn1); STAGE(Ag, ldsA0, 1, k2);
    PH_TAIL(0, 1, bn1);
    // ph7 (1,1)
    PH_HEAD; LOAD_A(ldsA1, 1); STAGE(Ag, ldsA1, 0, k3);
    PH_TAIL(1, 1, bn1);
    // ph8 (1,0)
    PH_HEAD; STAGE(Bg, ldsB1, 1, k3);
    PH_TAIL(1, 0, bn0);
  }
#undef PH_HEAD
#undef PH_TAIL
#undef DO_MFMA
#undef LOAD_A
#undef LOAD_B

  asm volatile("s_waitcnt vmcnt(0)" ::: "memory");
  __syncthreads();

  if constexpr (MODE == 0) {
    // folded-LN + SimpleGate epilogue
    bf16* g_lds = (bf16*)smem_raw;           // [256 l][136 pad] bf16 = 68KB
    const int lq = wc * 64 + (lane & 15);
    const int qq = (lane >> 4);
    const float* stb = stats + ((size_t)b * LSP + l0) * 2;
    float muv[4], rsv[4];
    #pragma unroll
    for (int ni = 0; ni < 4; ++ni) {
      int l = lq + ni * 16;
      muv[ni] = stb[l * 2];
      rsv[ni] = stb[l * 2 + 1];
    }
    #pragma unroll
    for (int mi = 0; mi < 8; ++mi) {
      int a0 = wr * 64 + mi * 8 + qq * 2;    // local gate row (0..127)
      int ag = (m0 >> 1) + a0;               // global gate row (0..511)
      float be1a = bias[ag],        ga1a = bias[512 + ag];
      float be2a = bias[1024 + ag], ga2a = bias[1536 + ag];
      float be1b = bias[ag + 1],        ga1b = bias[512 + ag + 1];
      float be2b = bias[1024 + ag + 1], ga2b = bias[1536 + ag + 1];
      #pragma unroll
      for (int ni = 0; ni < 4; ++ni) {
        int l = lq + ni * 16;
        float mrs = muv[ni] * rsv[ni];
        float h1a = rsv[ni] * acc[mi][ni][0] + be1a - mrs * ga1a;
        float h2a = rsv[ni] * acc[mi][ni][1] + be2a - mrs * ga2a;
        float h1b = rsv[ni] * acc[mi][ni][2] + be1b - mrs * ga1b;
        float h2b = rsv[ni] * acc[mi][ni][3] + be2b - mrs * ga2b;
        bf16 gv0 = (bf16)(h1a * h2a), gv1 = (bf16)(h1b * h2b);
        unsigned u = ((unsigned)*(unsigned short*)&gv1 << 16) |
                     (unsigned)*(unsigned short*)&gv0;
        *(unsigned*)&g_lds[l * 136 + a0] = u;
      }
    }
    __syncthreads();
    bf16* out = (bf16*)outp;
    const int gy = blockIdx.y * 128;
    #pragma unroll
    for (int it = 0; it < 8; ++it) {
      int cid = it * 512 + tid;              // 4096 chunks of 16B
      int l = cid >> 4, ch = cid & 15;
      bf16x8 v = *(const bf16x8*)&g_lds[l * 136 + ch * 8];
      *(bf16x8*)&out[((size_t)b * LSP + l0 + l) * 512 + gy + ch * 8] = v;
    }
  } else {
    float* lds_f = (float*)smem_raw;         // [128 c][260 pad] f32 = 133KB
    float* out = (float*)outp;
    const int lq = wc * 64 + (lane & 15);
    const int qq = (lane >> 4);
    #pragma unroll
    for (int round = 0; round < 2; ++round) {
      if (wr == round) {
        #pragma unroll
        for (int mi = 0; mi < 8; ++mi) {
          int c0 = mi * 16 + qq * 4;         // local c (0..127)
          f32x4 b4 = *(const f32x4*)&bias[round * 128 + c0];
          #pragma unroll
          for (int ni = 0; ni < 4; ++ni) {
            int l = lq + ni * 16;
            bf16x4 xr4 = *(const bf16x4*)&resb[((size_t)b * LSP + l0 + l) *
                                                   CCH + round * 128 + c0];
            #pragma unroll
            for (int r = 0; r < 4; ++r)
              lds_f[(c0 + r) * 260 + l] =
                  acc[mi][ni][r] + b4[r] + (float)xr4[r];
          }
        }
      }
      __syncthreads();
      #pragma unroll
      for (int it = 0; it < 16; ++it) {
        int cid = it * 512 + tid;            // 8192 chunks of 16B
        int c = cid >> 6, lch = cid & 63;
        f32x4 v = *(const f32x4*)&lds_f[c * 260 + lch * 4];
        *(f32x4*)&out[((size_t)b * CCH + round * 128 + c) * LSP + l0 +
                      lch * 4] = v;
      }
      __syncthreads();
    }
  }
}

// ---------------------------------------------------------------------------
extern "C" void kernel_launch(void* const* d_in, const int* in_sizes, int n_in,
                              void* d_out, int out_size, void* d_ws,
                              size_t ws_size, hipStream_t stream) {
  const float* optical = (const float*)d_in[0];
  const float* sar     = (const float*)d_in[1];
  const float* g_opt   = (const float*)d_in[2];
  const float* b_opt   = (const float*)d_in[3];
  const float* g_sar   = (const float*)d_in[4];
  const float* b_sar   = (const float*)d_in[5];
  const float* Wq      = (const float*)d_in[6];
  const float* Wk      = (const float*)d_in[7];
  const float* Wv      = (const float*)d_in[8];
  const float* Wo      = (const float*)d_in[9];
  const float* g_ffn   = (const float*)d_in[10];
  const float* b_ffn   = (const float*)d_in[11];
  const float* W1      = (const float*)d_in[12];
  const float* b1      = (const float*)d_in[13];
  const float* W2      = (const float*)d_in[14];
  const float* b2      = (const float*)d_in[15];

  char* ws = (char*)d_ws;
  bf16* wbf  = (bf16*)ws;
  bf16* Wqb  = wbf;
  bf16* Wkb  = wbf + 65536;
  bf16* WvTb = wbf + 131072;
  bf16* Wob  = wbf + 196608;
  bf16* W1b  = wbf + 262144;   // interleaved, pre-scaled by g_ffn
  bf16* W2b  = wbf + 524288;

  size_t off = 2ull * 1024 * 1024;
  const size_t T16 = 16ull * LSP * CCH * 2;  // 33.5 MB bf16 tensor
  bf16* opt_ncl = (bf16*)(ws + off); off += T16;
  bf16* sar_ncl = (bf16*)(ws + off); off += T16;
  bf16* sar_nlc = (bf16*)(ws + off); off += T16;
  bf16* xb      = (bf16*)(ws + off); off += T16;                   // x bf16
  float* stats  = (float*)(ws + off); off += 1ull * 1024 * 1024;   // 512KB+
  float* cvec   = (float*)(ws + off); off += 64 * 1024;            // 8KB
  float* Gpart  = (float*)(ws + off); off += 16ull * 1024 * 1024;  // 16 MB
  bf16* G2b     = (bf16*)(ws + off); off += 4ull * 1024 * 1024;
  bf16* UTb     = (bf16*)(ws + off); off += 2ull * 1024 * 1024;
  bf16* Wfoldb  = (bf16*)(ws + off); off += 2ull * 1024 * 1024;
  bf16* gbuf = opt_ncl;  // 67 MB overlay (opt_ncl+sar_ncl dead after gram)

  dim3 blk(256);
  cvt_w_kernel<<<2560, blk, 0, stream>>>(Wq, Wk, Wv, Wo, W1, W2, g_ffn, wbf);
  w1vec_kernel<<<4, blk, 0, stream>>>(W1, b1, g_ffn, b_ffn, cvec);
  ln_tile_kernel<0><<<dim3(64, 16), blk, 0, stream>>>(optical, g_opt, b_opt,
                                                      opt_ncl, nullptr);
  ln_tile_kernel<1><<<dim3(64, 16), blk, 0, stream>>>(sar, g_sar, b_sar,
                                                      sar_ncl, sar_nlc);
  gram_kernel<<<dim3(4, 4, 16), blk, 0, stream>>>(sar_ncl, opt_ncl, Gpart);
  greduce_kernel<<<512, blk, 0, stream>>>(Gpart, G2b);
  fold2_kernel<<<128, blk, 0, stream>>>(G2b, Wqb, Wkb, WvTb, UTb);
  wfold_kernel<<<dim3(2, 2, 16), blk, 0, stream>>>(Wob, UTb, Wfoldb);
  xgemm_stats_kernel<<<dim3(64, 16), blk, 0, stream>>>(Wfoldb, sar_nlc,
                                                       optical, xb, stats);
  ffn_gemm_kernel<256, 0><<<dim3(16, 4, 16), dim3(512), 0, stream>>>(
      W1b, xb, gbuf, nullptr, cvec, stats);
  ffn_gemm_kernel<512, 1><<<dim3(16, 1, 16), dim3(512), 0, stream>>>(
      W2b, gbuf, (float*)d_out, xb, b2, nullptr);
}